// Round 6
// baseline (833.586 us; speedup 1.0000x reference)
//
#include <hip/hip_runtime.h>

#define HW 112
#define PP 12544
#define BB 4
#define RR 49
#define RS 256
#define GW 114          // padded grid width (zero ring)
#define GP (GW*GW)      // 12996
#define CK 160          // padded channels for conv0

typedef __bf16 bf16;
typedef __bf16 bf16x8 __attribute__((ext_vector_type(8)));
typedef __bf16 bf16x4 __attribute__((ext_vector_type(4)));
typedef float f32x4 __attribute__((ext_vector_type(4)));

// XOR-swizzled byte offset in a row-major bf16 tile; rowbytes ∈ {128,256,512}
__device__ __forceinline__ int swzg(int row, int halfcol, int rowbytes) {
  int byte = halfcol * 2;
  return row * rowbytes + (byte & ~127) + ((((byte >> 4) ^ row) & 7) * 16) + (byte & 15);
}
__device__ __forceinline__ int swz128(int row, int halfcol) { return swzg(row, halfcol, 128); }

__device__ __forceinline__ float gelu_exact(float x) {
  return 0.5f * x * (1.f + erff(x * 0.70710678118654752f));
}

// ---------------- prep: downsample+concat -> xcat_t bf16 [n][grid 114x114][160], mask ----------------
__global__ __launch_bounds__(256) void k_prep2(const float* __restrict__ ex0, const float* __restrict__ ex,
    const float* __restrict__ img, const float* __restrict__ pre,
    bf16* __restrict__ xct, float* __restrict__ maskr) {
  __shared__ bf16 sT2[64 * 168];   // [pixel][168 ch] rows 336B (16B aligned)
  int n = blockIdx.y;
  int p0 = blockIdx.x * 64;
  int tid = threadIdx.x;
  uint4 zz = {0, 0, 0, 0};
  for (int i2 = tid; i2 < 1344; i2 += 256) ((uint4*)sT2)[i2] = zz;
  __syncthreads();
  int l = tid & 63, g = tid >> 6;
  int p = p0 + l;
  int h = p / HW, w = p % HW;
  for (int c = g; c < 131; c += 4) {
    float val;
    if (c < 64) {
      const float* s = ex0 + (((size_t)(n * 64 + c)) * 224 + 2 * h) * 224 + 2 * w;
      val = 0.5f * (0.5f * (s[0] + s[224]) + 0.5f * (s[1] + s[225]));
    } else if (c < 128) {
      val = ex[((size_t)(n * 64 + (c - 64))) * PP + p];
    } else {
      const float* s = img + (((size_t)(n * 3 + (c - 128))) * 224 + 2 * h) * 224 + 2 * w;
      val = 0.5f * (0.5f * (s[0] + s[224]) + 0.5f * (s[1] + s[225]));
    }
    sT2[l * 168 + c] = (bf16)val;
  }
  if (tid < 64) {
    const float* s = pre + ((size_t)n * 224 + 2 * h) * 224 + 2 * w;
    float v = 0.5f * (0.5f * (s[0] + s[224]) + 0.5f * (s[1] + s[225]));
    int r = (h >> 4) * 7 + (w >> 4); int sIdx = (h & 15) * 16 + (w & 15);
    maskr[(n * RR + r) * RS + sIdx] = (v > 0.0f) ? 0.0f : -100.0f;
  }
  __syncthreads();
  for (int i2 = tid; i2 < 1280; i2 += 256) {
    int row = i2 / 20, ch = i2 % 20;
    int pr = p0 + row;
    int hh = pr / HW, ww = pr % HW;
    uint4 d = *(const uint4*)(sT2 + row * 168 + ch * 8);
    *(uint4*)(xct + ((size_t)n * GP + (hh + 1) * GW + ww + 1) * CK + ch * 8) = d;
  }
}

// ---------------- conv0 weights -> wTb bf16 [9tap][5ks][64o][32c] ----------------
__global__ __launch_bounds__(256) void k_wt2(const float* __restrict__ w, bf16* __restrict__ wTb) {
  int t = blockIdx.x * 256 + threadIdx.x;
  if (t >= 9 * 5 * 64 * 32) return;
  int cc = t & 31; int o = (t >> 5) & 63; int ks = (t >> 11) % 5; int k = t / 10240;
  int c = ks * 32 + cc;
  wTb[t] = (bf16)((c < 131) ? w[((size_t)(o * 131) + c) * 9 + k] : 0.f);
}

// ---------------- conv0 as MFMA implicit GEMM: 9 shifted taps x 5 K-slices ----------------
__global__ __launch_bounds__(256) void k_conv0m(const bf16* __restrict__ xct, const bf16* __restrict__ wTb,
    const float* __restrict__ bias, float* __restrict__ out_t) {
  __shared__ bf16 sA[128 * 32];
  __shared__ bf16 sB[64 * 32];
  int n = blockIdx.y;
  int p0 = blockIdx.x * 128;
  int tid = threadIdx.x, lane = tid & 63, wv = tid >> 6;
  int lo = lane & 15, hi = lane >> 4;
  size_t gofsA[2];
  #pragma unroll
  for (int it = 0; it < 2; it++) {
    int idx = tid + it * 256;
    int row = idx >> 2, ch = idx & 3;
    int p = p0 + row;
    int hh = p / HW, ww = p % HW;
    gofsA[it] = ((size_t)(hh + 1) * GW + ww + 1) * (CK * 2) + ch * 16;
  }
  const char* xbase = (const char*)(xct + (size_t)n * GP * CK);
  f32x4 acc[2][4];
  #pragma unroll
  for (int mi = 0; mi < 2; mi++)
    #pragma unroll
    for (int ni = 0; ni < 4; ni++) acc[mi][ni] = (f32x4){0.f, 0.f, 0.f, 0.f};
  for (int tap = 0; tap < 9; tap++) {
    long shift = (long)((tap / 3 - 1) * GW + (tap % 3 - 1)) * (CK * 2);
    for (int ks = 0; ks < 5; ks++) {
      uint4 a0 = *(const uint4*)(xbase + gofsA[0] + shift + ks * 64);
      uint4 a1 = *(const uint4*)(xbase + gofsA[1] + shift + ks * 64);
      uint4 b0 = *(const uint4*)((const char*)wTb + ((size_t)(tap * 5 + ks) * 2048 + tid * 8) * 2);
      __syncthreads();
      *(uint4*)((char*)sA + tid * 16) = a0;
      *(uint4*)((char*)sA + (tid + 256) * 16) = a1;
      *(uint4*)((char*)sB + tid * 16) = b0;
      __syncthreads();
      bf16x8 aF[2], bF[4];
      #pragma unroll
      for (int mi = 0; mi < 2; mi++)
        aF[mi] = *(const bf16x8*)((const char*)sA + (wv * 32 + mi * 16 + lo) * 64 + hi * 16);
      #pragma unroll
      for (int ni = 0; ni < 4; ni++)
        bF[ni] = *(const bf16x8*)((const char*)sB + (ni * 16 + lo) * 64 + hi * 16);
      #pragma unroll
      for (int mi = 0; mi < 2; mi++)
        #pragma unroll
        for (int ni = 0; ni < 4; ni++)
          acc[mi][ni] = __builtin_amdgcn_mfma_f32_16x16x32_bf16(aF[mi], bF[ni], acc[mi][ni], 0, 0, 0);
    }
  }
  #pragma unroll
  for (int ni = 0; ni < 4; ni++) {
    float bv = bias[ni * 16 + lo];
    #pragma unroll
    for (int mi = 0; mi < 2; mi++) {
      #pragma unroll
      for (int r2 = 0; r2 < 4; r2++) {
        int p = p0 + wv * 32 + mi * 16 + hi * 4 + r2;
        out_t[((size_t)n * PP + p) * 64 + ni * 16 + lo] = acc[mi][ni][r2] + bv;
      }
    }
  }
}

// ---------------- qkv with fused LN1 ----------------
__global__ __launch_bounds__(256) void k_qkv(const float* __restrict__ xin, const float* __restrict__ lng,
    const float* __restrict__ lnb, const float* __restrict__ w, const float* __restrict__ bias,
    bf16* __restrict__ qRo, bf16* __restrict__ kRo, bf16* __restrict__ vto) {
  __shared__ bf16 sA[128 * 64];
  __shared__ bf16 sB[64 * 64];
  int n = blockIdx.y;
  int p0 = blockIdx.x * 128;
  int tid = threadIdx.x, lane = tid & 63, wv = tid >> 6;
  int lo = lane & 15, hi = lane >> 4;
  { // fused LN staging: 2 threads per row, 32 channels each
    int row = tid >> 1, part = tid & 1;
    const float* xp = xin + ((size_t)n * PP + p0 + row) * 64 + part * 32;
    float v[32]; float s = 0.f, sq = 0.f;
    #pragma unroll
    for (int i = 0; i < 8; i++) {
      float4 d = *(const float4*)&xp[i * 4];
      v[i*4]=d.x; v[i*4+1]=d.y; v[i*4+2]=d.z; v[i*4+3]=d.w;
      s += d.x+d.y+d.z+d.w;
      sq += d.x*d.x+d.y*d.y+d.z*d.z+d.w*d.w;
    }
    s += __shfl_xor(s, 1, 64); sq += __shfl_xor(sq, 1, 64);
    float mu = s * (1.f/64.f);
    float rstd = rsqrtf(fmaxf(sq * (1.f/64.f) - mu*mu, 0.f) + 1e-5f);
    #pragma unroll
    for (int j2 = 0; j2 < 4; j2++) {
      bf16x8 o8;
      #pragma unroll
      for (int e = 0; e < 8; e++) {
        int c = part*32 + j2*8 + e;
        o8[e] = (bf16)((v[j2*8+e] - mu) * rstd * lng[c] + lnb[c]);
      }
      *(bf16x8*)((char*)sA + swz128(row, part*32 + j2*8)) = o8;
    }
  }
  for (int ob = 0; ob < 3; ob++) {
    #pragma unroll
    for (int it = 0; it < 4; it++) {
      int idx = tid + it * 256;
      int oo = idx >> 4, q = idx & 15;
      float4 wv4 = *(const float4*)&w[(size_t)(ob * 64 + oo) * 64 + q * 4];
      bf16x4 b4; b4[0] = (bf16)wv4.x; b4[1] = (bf16)wv4.y; b4[2] = (bf16)wv4.z; b4[3] = (bf16)wv4.w;
      *(bf16x4*)((char*)sB + swz128(oo, q * 4)) = b4;
    }
    __syncthreads();
    f32x4 acc[2][4];
    #pragma unroll
    for (int mi = 0; mi < 2; mi++)
      #pragma unroll
      for (int ni = 0; ni < 4; ni++) acc[mi][ni] = (f32x4){0.f, 0.f, 0.f, 0.f};
    #pragma unroll
    for (int kk = 0; kk < 2; kk++) {
      bf16x8 aF[2], bF[4];
      #pragma unroll
      for (int mi = 0; mi < 2; mi++)
        aF[mi] = *(const bf16x8*)((const char*)sA + swz128(wv * 32 + mi * 16 + lo, kk * 32 + hi * 8));
      #pragma unroll
      for (int ni = 0; ni < 4; ni++)
        bF[ni] = *(const bf16x8*)((const char*)sB + swz128(ni * 16 + lo, kk * 32 + hi * 8));
      #pragma unroll
      for (int mi = 0; mi < 2; mi++)
        #pragma unroll
        for (int ni = 0; ni < 4; ni++)
          acc[mi][ni] = __builtin_amdgcn_mfma_f32_16x16x32_bf16(aF[mi], bF[ni], acc[mi][ni], 0, 0, 0);
    }
    #pragma unroll
    for (int ni = 0; ni < 4; ni++) {
      float bv = bias[ob * 64 + ni * 16 + lo];
      #pragma unroll
      for (int mi = 0; mi < 2; mi++) {
        #pragma unroll
        for (int r2 = 0; r2 < 4; r2++) {
          float rv = acc[mi][ni][r2] + bv;
          int p = p0 + wv * 32 + mi * 16 + hi * 4 + r2;
          int hh = p / HW, ww = p % HW;
          int rg = (hh >> 4) * 7 + (ww >> 4), s2 = (hh & 15) * 16 + (ww & 15);
          int o = ni * 16 + lo;
          if (ob == 0)      qRo[(((size_t)(n * RR + rg)) * RS + s2) * 64 + o] = (bf16)(rv * 0.125f);
          else if (ob == 1) kRo[(((size_t)(n * RR + rg)) * RS + s2) * 64 + o] = (bf16)rv;
          else              vto[((size_t)n * PP + p) * 64 + o] = (bf16)rv;
        }
      }
    }
    __syncthreads();
  }
}

// ---------------- per-region: vT transpose + qd/kd means ----------------
__global__ __launch_bounds__(256) void k_vpost(const bf16* __restrict__ qR, const bf16* __restrict__ kR,
    const bf16* __restrict__ v_t, float* __restrict__ qd, float* __restrict__ kd, bf16* __restrict__ vT) {
  __shared__ bf16 sT[64 * 264];
  __shared__ float rq[4][64], rk[4][64];
  int r = blockIdx.x, n = blockIdx.y;
  int nr = n * RR + r;
  int tid = threadIdx.x;
  int rh = (r / 7) * 16, rw = (r % 7) * 16;
  {
    int ph = rh + (tid >> 4), pw = rw + (tid & 15);
    const bf16* src = v_t + ((size_t)n * PP + ph * HW + pw) * 64;
    #pragma unroll
    for (int c8 = 0; c8 < 8; c8++) {
      bf16x8 d = *(const bf16x8*)(src + c8 * 8);
      #pragma unroll
      for (int j = 0; j < 8; j++) sT[(c8 * 8 + j) * 264 + tid] = d[j];
    }
  }
  {
    int c = tid & 63, sq = tid >> 6;
    const bf16* qb = qR + (size_t)nr * RS * 64;
    const bf16* kb = kR + (size_t)nr * RS * 64;
    float aq = 0.f, ak = 0.f;
    for (int s = sq * 64; s < sq * 64 + 64; s++) {
      aq += (float)qb[s * 64 + c];
      ak += (float)kb[s * 64 + c];
    }
    rq[sq][c] = aq; rk[sq][c] = ak;
  }
  __syncthreads();
  #pragma unroll
  for (int it = 0; it < 8; it++) {
    int idx = tid + it * 256;
    int row = idx >> 5, ch = idx & 31;
    uint4 d = *(const uint4*)(sT + row * 264 + ch * 8);
    *(uint4*)(vT + ((size_t)nr * 64 + row) * 256 + ch * 8) = d;
  }
  if (tid < 64) {
    int c = tid;
    qd[(n * 64 + c) * RR + r] = ((rq[0][c] + rq[1][c]) + (rq[2][c] + rq[3][c])) * (1.f / 256.f);
    kd[(n * 64 + c) * RR + r] = ((rk[0][c] + rk[1][c]) + (rk[2][c] + rk[3][c])) * (1.f / 256.f);
  }
}

// ---------------- top-4 routing: one wave per query region ----------------
__global__ __launch_bounds__(64) void k_topk(const float* __restrict__ qd, const float* __restrict__ kd,
    int* __restrict__ gidx) {
  int pq = blockIdx.x, n = blockIdx.y;
  int j = threadIdx.x;
  float a = -3e38f;
  if (j < RR) {
    a = 0.f;
    for (int c = 0; c < 64; c++)
      a += qd[(n * 64 + c) * RR + pq] * kd[(n * 64 + c) * RR + j];
  }
  for (int t = 0; t < 4; t++) {
    float bv = a; int bj = j;
    #pragma unroll
    for (int d = 32; d >= 1; d >>= 1) {
      float ov = __shfl_xor(bv, d, 64);
      int oj = __shfl_xor(bj, d, 64);
      if (ov > bv || (ov == bv && oj < bj)) { bv = ov; bj = oj; }
    }
    if (j == 0) gidx[(n * RR + pq) * 4 + t] = bj;
    if (j == bj) a = -3e38f;
  }
}

// ---------------- gathered-region flash attention v3: KVBLK=128, coalesced epilogue ----------------
// grid = BB*RR*4 (XCD-swizzled); block = 4 waves; wave owns 16 Q rows
__global__ __launch_bounds__(256) void k_attn(const bf16* __restrict__ qR, const bf16* __restrict__ kR,
    const bf16* __restrict__ vT, const float* __restrict__ maskr, const int* __restrict__ gidx,
    bf16* __restrict__ attnRb) {
  __shared__ bf16 sK[128 * 64];     // [kv 128][ch 64] swz128   16KB
  __shared__ bf16 sV[64 * 128];     // [d 64][kv 128] swz256    16KB
  __shared__ bf16 sP[4][16 * 128];  // per-wave P [16 q][128 kv] swz256  16KB
  __shared__ float sMask[128];
  int bid = blockIdx.x;
  int newid = (bid & 7) * 98 + (bid >> 3);   // 784 = 8*98: bijective XCD chunking
  int n = newid / (RR * 4); int rem = newid % (RR * 4); int r = rem >> 2, qs = rem & 3;
  int tid = threadIdx.x, lane = tid & 63, wv = tid >> 6;
  int lo = lane & 15, hi = lane >> 4;
  int m0 = qs * 64 + wv * 16;
  const bf16* qbase = qR + ((size_t)(n * RR + r)) * RS * 64;
  bf16x8 qF[2];
  #pragma unroll
  for (int kk = 0; kk < 2; kk++)
    qF[kk] = *(const bf16x8*)(qbase + (m0 + lo) * 64 + kk * 32 + hi * 8);

  // staging geometry: K: 1024 uint4 (row=idx>>3 0..127, c4=idx&7); V: row=idx>>4 0..63, c8=idx&15
  int rowK[4], c4K[4], wK[4], rowV[4], c8V[4], wV[4];
  #pragma unroll
  for (int it = 0; it < 4; it++) {
    int idx = tid + it * 256;
    rowK[it] = idx >> 3; c4K[it] = idx & 7;
    wK[it] = rowK[it] * 128 + (((c4K[it] ^ rowK[it]) & 7) << 4);
    rowV[it] = idx >> 4; c8V[it] = idx & 15;
    wV[it] = rowV[it] * 256 + ((c8V[it] & 8) << 4) + (((c8V[it] ^ rowV[it]) & 7) << 4);
  }

  f32x4 zero4 = {0.f, 0.f, 0.f, 0.f};
  f32x4 Oacc[4];
  #pragma unroll
  for (int di = 0; di < 4; di++) Oacc[di] = zero4;
  float mrun[4], lrun[4];
  #pragma unroll
  for (int s = 0; s < 4; s++) { mrun[s] = -3e38f; lrun[s] = 0.f; }

  const int* gptr = gidx + (n * RR + r) * 4;
  int j0 = gptr[0];
  const bf16* kbase = kR + ((size_t)(n * RR + j0)) * RS * 64;
  const bf16* vbase = vT + ((size_t)(n * RR + j0)) * 64 * RS;
  const float* mbase = maskr + (n * RR + j0) * RS;
  uint4 regK[4], regV[4]; float regM;
  // preload ts=0 (t=0, hb=0)
  #pragma unroll
  for (int it = 0; it < 4; it++) {
    regK[it] = *(const uint4*)(kbase + rowK[it] * 64 + c4K[it] * 8);
    regV[it] = *(const uint4*)(vbase + rowV[it] * 256 + c8V[it] * 8);
  }
  regM = (tid < 128) ? mbase[tid] : 0.f;

  for (int ts = 0; ts < 8; ts++) {
    __syncthreads();   // all waves done reading LDS from previous iteration
    #pragma unroll
    for (int it = 0; it < 4; it++) {
      *(uint4*)((char*)sK + wK[it]) = regK[it];
      *(uint4*)((char*)sV + wV[it]) = regV[it];
    }
    if (tid < 128) sMask[tid] = regM;
    __syncthreads();
    // prefetch next half-tile while computing this one
    if (ts < 7) {
      int nts = ts + 1, nhb = nts & 1;
      if (nhb == 0) {
        int j = gptr[nts >> 1];
        kbase = kR + ((size_t)(n * RR + j)) * RS * 64;
        vbase = vT + ((size_t)(n * RR + j)) * 64 * RS;
        mbase = maskr + (n * RR + j) * RS;
      }
      #pragma unroll
      for (int it = 0; it < 4; it++) {
        regK[it] = *(const uint4*)(kbase + (nhb * 128 + rowK[it]) * 64 + c4K[it] * 8);
        regV[it] = *(const uint4*)(vbase + rowV[it] * 256 + nhb * 128 + c8V[it] * 8);
      }
      regM = (tid < 128) ? mbase[nhb * 128 + tid] : 0.f;
    }
    // ---- QK^T over 128 kv ----
    f32x4 Sacc[8];
    #pragma unroll
    for (int ni = 0; ni < 8; ni++) Sacc[ni] = zero4;
    #pragma unroll
    for (int kk = 0; kk < 2; kk++) {
      #pragma unroll
      for (int ni = 0; ni < 8; ni++) {
        bf16x8 bF = *(const bf16x8*)((const char*)sK + swz128(ni * 16 + lo, kk * 32 + hi * 8));
        Sacc[ni] = __builtin_amdgcn_mfma_f32_16x16x32_bf16(qF[kk], bF, Sacc[ni], 0, 0, 0);
      }
    }
    // ---- online softmax ----
    float mv[8];
    #pragma unroll
    for (int ni = 0; ni < 8; ni++) mv[ni] = sMask[ni * 16 + lo];
    bf16* sPw = sP[wv];
    #pragma unroll
    for (int jj = 0; jj < 4; jj++) {
      float s0 = fmaxf(fmaxf(Sacc[0][jj] + mv[0], Sacc[1][jj] + mv[1]),
                       fmaxf(Sacc[2][jj] + mv[2], Sacc[3][jj] + mv[3]));
      float s1 = fmaxf(fmaxf(Sacc[4][jj] + mv[4], Sacc[5][jj] + mv[5]),
                       fmaxf(Sacc[6][jj] + mv[6], Sacc[7][jj] + mv[7]));
      float cm = fmaxf(s0, s1);
      #pragma unroll
      for (int d2 = 1; d2 < 16; d2 <<= 1) cm = fmaxf(cm, __shfl_xor(cm, d2, 64));
      float nm = fmaxf(mrun[jj], cm);
      float sc = __expf(mrun[jj] - nm);
      float rsum = 0.f; float pv[8];
      #pragma unroll
      for (int ni = 0; ni < 8; ni++) { pv[ni] = __expf(Sacc[ni][jj] + mv[ni] - nm); rsum += pv[ni]; }
      #pragma unroll
      for (int d2 = 1; d2 < 16; d2 <<= 1) rsum += __shfl_xor(rsum, d2, 64);
      mrun[jj] = nm; lrun[jj] = lrun[jj] * sc + rsum;
      #pragma unroll
      for (int di = 0; di < 4; di++) Oacc[di][jj] *= sc;
      int prow = hi * 4 + jj;
      #pragma unroll
      for (int ni = 0; ni < 8; ni++)
        *(bf16*)((char*)sPw + swzg(prow, ni * 16 + lo, 256)) = (bf16)pv[ni];
    }
    // ---- PV over 128 kv ----
    #pragma unroll
    for (int kk2 = 0; kk2 < 4; kk2++) {
      bf16x8 pF = *(const bf16x8*)((const char*)sPw + swzg(lo, kk2 * 32 + hi * 8, 256));
      #pragma unroll
      for (int di = 0; di < 4; di++) {
        bf16x8 vF = *(const bf16x8*)((const char*)sV + swzg(di * 16 + lo, kk2 * 32 + hi * 8, 256));
        Oacc[di] = __builtin_amdgcn_mfma_f32_16x16x32_bf16(pF, vF, Oacc[di], 0, 0, 0);
      }
    }
  }
  // ---- coalesced epilogue: normalize -> LDS repack -> contiguous uint4 stores ----
  __syncthreads();                 // all waves finished reading sK
  bf16* sOut = sK;                 // reuse 8KB of sK
  #pragma unroll
  for (int jj = 0; jj < 4; jj++) {
    float inv = 1.f / lrun[jj];
    int row = wv * 16 + hi * 4 + jj;
    #pragma unroll
    for (int di = 0; di < 4; di++)
      sOut[row * 64 + di * 16 + lo] = (bf16)(Oacc[di][jj] * inv);
  }
  __syncthreads();
  bf16* dst = attnRb + (((size_t)(n * RR + r)) * RS + qs * 64) * 64;
  #pragma unroll
  for (int it = 0; it < 2; it++) {
    int idx = tid + it * 256;
    *(uint4*)(dst + idx * 8) = *(const uint4*)(sOut + idx * 8);
  }
}

// ---------------- lepe 5x5 dw + from_regions (attnR bf16) ----------------
__global__ __launch_bounds__(256) void k_lepe2(const bf16* __restrict__ v_t, const bf16* __restrict__ attnRb,
    const float* __restrict__ lw, const float* __restrict__ lb, bf16* __restrict__ z_t) {
  __shared__ bf16 sH[400 * 72];
  __shared__ float sW[25][64];
  int r = blockIdx.x, n = blockIdx.y;
  int rh = (r / 7) * 16, rw = (r % 7) * 16;
  int tid = threadIdx.x;
  for (int i = tid; i < 1600; i += 256) { int c = i / 25, k = i % 25; sW[k][c] = lw[c * 25 + k]; }
  for (int g = tid; g < 3200; g += 256) {
    int pix = g >> 3, c4 = g & 7;
    int yy = pix / 20, xx = pix % 20;
    int hh = rh + yy - 2, ww = rw + xx - 2;
    uint4 d = {0, 0, 0, 0};
    if ((unsigned)hh < HW && (unsigned)ww < HW)
      d = *(const uint4*)(v_t + ((size_t)n * PP + hh * HW + ww) * 64 + c4 * 8);
    *(uint4*)((char*)sH + pix * 144 + c4 * 16) = d;
  }
  __syncthreads();
  int y = tid >> 4, x = tid & 15;
  float acc[64];
  const bf16* ar = attnRb + (((size_t)(n * RR + r)) * RS + tid) * 64;
  #pragma unroll
  for (int c8 = 0; c8 < 8; c8++) {
    bf16x8 av = *(const bf16x8*)(ar + c8 * 8);
    #pragma unroll
    for (int j = 0; j < 8; j++) acc[c8 * 8 + j] = lb[c8 * 8 + j] + (float)av[j];
  }
  for (int t25 = 0; t25 < 25; t25++) {
    int dh = t25 / 5, dw = t25 % 5;
    int pix = (y + dh) * 20 + (x + dw);
    #pragma unroll
    for (int c8 = 0; c8 < 8; c8++) {
      bf16x8 hv = *(const bf16x8*)((const char*)sH + pix * 144 + c8 * 16);
      #pragma unroll
      for (int j = 0; j < 8; j++) acc[c8 * 8 + j] += (float)hv[j] * sW[t25][c8 * 8 + j];
    }
  }
  bf16* zp = z_t + ((size_t)n * PP + (rh + y) * HW + rw + x) * 64;
  #pragma unroll
  for (int c8 = 0; c8 < 8; c8++) {
    bf16x8 o8;
    #pragma unroll
    for (int j = 0; j < 8; j++) o8[j] = (bf16)acc[c8 * 8 + j];
    *(bf16x8*)(zp + c8 * 8) = o8;
  }
}

// ---------------- proj GEMM: z_t -> x_t += ----------------
__global__ __launch_bounds__(256) void k_proj(const bf16* __restrict__ A, const float* __restrict__ w,
    const float* __restrict__ bias, float* __restrict__ xo) {
  __shared__ bf16 sA[128 * 64];
  __shared__ bf16 sB[64 * 64];
  int n = blockIdx.y;
  int p0 = blockIdx.x * 128;
  int tid = threadIdx.x, lane = tid & 63, wv = tid >> 6;
  int lo = lane & 15, hi = lane >> 4;
  const bf16* Abase = A + (size_t)n * PP * 64;
  #pragma unroll
  for (int it = 0; it < 4; it++) {
    int idx = tid + it * 256;
    int row = idx >> 3, c4 = idx & 7;
    uint4 d = *(const uint4*)(Abase + (size_t)(p0 + row) * 64 + c4 * 8);
    *(uint4*)((char*)sA + row * 128 + (((c4 ^ row) & 7) * 16)) = d;
  }
  #pragma unroll
  for (int it = 0; it < 4; it++) {
    int idx = tid + it * 256;
    int oo = idx >> 4, q = idx & 15;
    float4 wv4 = *(const float4*)&w[(size_t)oo * 64 + q * 4];
    bf16x4 b4; b4[0] = (bf16)wv4.x; b4[1] = (bf16)wv4.y; b4[2] = (bf16)wv4.z; b4[3] = (bf16)wv4.w;
    *(bf16x4*)((char*)sB + swz128(oo, q * 4)) = b4;
  }
  __syncthreads();
  f32x4 acc[2][4];
  #pragma unroll
  for (int mi = 0; mi < 2; mi++)
    #pragma unroll
    for (int ni = 0; ni < 4; ni++) acc[mi][ni] = (f32x4){0.f, 0.f, 0.f, 0.f};
  #pragma unroll
  for (int kk = 0; kk < 2; kk++) {
    bf16x8 aF[2], bF[4];
    #pragma unroll
    for (int mi = 0; mi < 2; mi++)
      aF[mi] = *(const bf16x8*)((const char*)sA + swz128(wv * 32 + mi * 16 + lo, kk * 32 + hi * 8));
    #pragma unroll
    for (int ni = 0; ni < 4; ni++)
      bF[ni] = *(const bf16x8*)((const char*)sB + swz128(ni * 16 + lo, kk * 32 + hi * 8));
    #pragma unroll
    for (int mi = 0; mi < 2; mi++)
      #pragma unroll
      for (int ni = 0; ni < 4; ni++)
        acc[mi][ni] = __builtin_amdgcn_mfma_f32_16x16x32_bf16(aF[mi], bF[ni], acc[mi][ni], 0, 0, 0);
  }
  #pragma unroll
  for (int ni = 0; ni < 4; ni++) {
    float bv = bias[ni * 16 + lo];
    #pragma unroll
    for (int mi = 0; mi < 2; mi++) {
      #pragma unroll
      for (int r2 = 0; r2 < 4; r2++) {
        int p = p0 + wv * 32 + mi * 16 + hi * 4 + r2;
        xo[((size_t)n * PP + p) * 64 + ni * 16 + lo] += acc[mi][ni][r2] + bv;
      }
    }
  }
}

// ---------------- fused MLP: LN2 + fc1 + gelu + fc2 + residual ----------------
__global__ __launch_bounds__(256) void k_mlp(const float* __restrict__ xin, const float* __restrict__ lng,
    const float* __restrict__ lnb, const float* __restrict__ w1, const float* __restrict__ b1,
    const float* __restrict__ w2, const float* __restrict__ b2, float* __restrict__ xo) {
  __shared__ bf16 sA[64 * 64];
  __shared__ bf16 sW1[128 * 64];
  __shared__ bf16 sHh[64 * 128];
  __shared__ bf16 sW2[64 * 128];
  int n = blockIdx.y;
  int p0 = blockIdx.x * 64;
  int tid = threadIdx.x, lane = tid & 63, wv = tid >> 6;
  int lo = lane & 15, hi = lane >> 4;
  { // fused LN staging: 4 threads per row, 16 channels each
    int row = tid >> 2, part = tid & 3;
    const float* xp = xin + ((size_t)n * PP + p0 + row) * 64 + part * 16;
    float v[16]; float s = 0.f, sq = 0.f;
    #pragma unroll
    for (int i = 0; i < 4; i++) {
      float4 d = *(const float4*)&xp[i * 4];
      v[i*4]=d.x; v[i*4+1]=d.y; v[i*4+2]=d.z; v[i*4+3]=d.w;
      s += d.x+d.y+d.z+d.w;
      sq += d.x*d.x+d.y*d.y+d.z*d.z+d.w*d.w;
    }
    s += __shfl_xor(s, 1, 64); sq += __shfl_xor(sq, 1, 64);
    s += __shfl_xor(s, 2, 64); sq += __shfl_xor(sq, 2, 64);
    float mu = s * (1.f/64.f);
    float rstd = rsqrtf(fmaxf(sq * (1.f/64.f) - mu*mu, 0.f) + 1e-5f);
    #pragma unroll
    for (int j2 = 0; j2 < 2; j2++) {
      bf16x8 o8;
      #pragma unroll
      for (int e = 0; e < 8; e++) {
        int c = part*16 + j2*8 + e;
        o8[e] = (bf16)((v[j2*8+e] - mu) * rstd * lng[c] + lnb[c]);
      }
      *(bf16x8*)((char*)sA + swz128(row, part*16 + j2*8)) = o8;
    }
  }
  f32x4 oacc[4];
  #pragma unroll
  for (int ni = 0; ni < 4; ni++) oacc[ni] = (f32x4){0.f, 0.f, 0.f, 0.f};
  for (int half = 0; half < 2; half++) {
    #pragma unroll
    for (int it = 0; it < 8; it++) {
      int idx = tid + it * 256;
      int oo = idx >> 4, q = idx & 15;
      float4 wv4 = *(const float4*)&w1[(size_t)(half * 128 + oo) * 64 + q * 4];
      bf16x4 b4; b4[0] = (bf16)wv4.x; b4[1] = (bf16)wv4.y; b4[2] = (bf16)wv4.z; b4[3] = (bf16)wv4.w;
      *(bf16x4*)((char*)sW1 + swz128(oo, q * 4)) = b4;
    }
    __syncthreads();
    f32x4 hacc[8];
    #pragma unroll
    for (int ni = 0; ni < 8; ni++) hacc[ni] = (f32x4){0.f, 0.f, 0.f, 0.f};
    #pragma unroll
    for (int kk = 0; kk < 2; kk++) {
      bf16x8 aF = *(const bf16x8*)((const char*)sA + swz128(wv * 16 + lo, kk * 32 + hi * 8));
      #pragma unroll
      for (int ni = 0; ni < 8; ni++) {
        bf16x8 bF = *(const bf16x8*)((const char*)sW1 + swz128(ni * 16 + lo, kk * 32 + hi * 8));
        hacc[ni] = __builtin_amdgcn_mfma_f32_16x16x32_bf16(aF, bF, hacc[ni], 0, 0, 0);
      }
    }
    #pragma unroll
    for (int ni = 0; ni < 8; ni++) {
      float bv = b1[half * 128 + ni * 16 + lo];
      #pragma unroll
      for (int r2 = 0; r2 < 4; r2++) {
        float hval = gelu_exact(hacc[ni][r2] + bv);
        *(bf16*)((char*)sHh + swzg(wv * 16 + hi * 4 + r2, ni * 16 + lo, 256)) = (bf16)hval;
      }
    }
    #pragma unroll
    for (int it = 0; it < 8; it++) {
      int idx = tid + it * 256;
      int oo = idx >> 5, q = idx & 31;
      float4 wv4 = *(const float4*)&w2[(size_t)oo * 256 + half * 128 + q * 4];
      bf16x4 b4; b4[0] = (bf16)wv4.x; b4[1] = (bf16)wv4.y; b4[2] = (bf16)wv4.z; b4[3] = (bf16)wv4.w;
      *(bf16x4*)((char*)sW2 + swzg(oo, q * 4, 256)) = b4;
    }
    __syncthreads();
    #pragma unroll
    for (int kk = 0; kk < 4; kk++) {
      bf16x8 aH = *(const bf16x8*)((const char*)sHh + swzg(wv * 16 + lo, kk * 32 + hi * 8, 256));
      #pragma unroll
      for (int ni = 0; ni < 4; ni++) {
        bf16x8 bF = *(const bf16x8*)((const char*)sW2 + swzg(ni * 16 + lo, kk * 32 + hi * 8, 256));
        oacc[ni] = __builtin_amdgcn_mfma_f32_16x16x32_bf16(aH, bF, oacc[ni], 0, 0, 0);
      }
    }
    __syncthreads();
  }
  #pragma unroll
  for (int ni = 0; ni < 4; ni++) {
    float bv = b2[ni * 16 + lo];
    #pragma unroll
    for (int r2 = 0; r2 < 4; r2++) {
      int p = p0 + wv * 16 + hi * 4 + r2;
      xo[((size_t)n * PP + p) * 64 + ni * 16 + lo] += oacc[ni][r2] + bv;
    }
  }
}

// ---------------- final untranspose: x_t[p][c] -> out[c][p] ----------------
__global__ __launch_bounds__(256) void k_untr(const float* __restrict__ x_t, float* __restrict__ out) {
  __shared__ float tile[64][68];
  int n = blockIdx.y; int p0 = blockIdx.x * 64;
  int tid = threadIdx.x;
  #pragma unroll
  for (int it = 0; it < 4; it++) {
    int g = tid + it * 256;
    int row = g >> 4, q = g & 15;
    float4 d = *(const float4*)&x_t[((size_t)n * PP + p0 + row) * 64 + q * 4];
    *(float4*)&tile[row][q * 4] = d;
  }
  __syncthreads();
  #pragma unroll
  for (int it = 0; it < 4; it++) {
    int g = tid + it * 256;
    int c = g >> 4, q = g & 15;
    float4 v;
    v.x = tile[q * 4 + 0][c]; v.y = tile[q * 4 + 1][c];
    v.z = tile[q * 4 + 2][c]; v.w = tile[q * 4 + 3][c];
    *(float4*)&out[((size_t)(n * 64 + c)) * PP + p0 + q * 4] = v;
  }
}

extern "C" void kernel_launch(void* const* d_in, const int* in_sizes, int n_in,
                              void* d_out, int out_size, void* d_ws, size_t ws_size,
                              hipStream_t stream) {
  const float* ex0 = (const float*)d_in[0];
  const float* ex  = (const float*)d_in[1];
  const float* img = (const float*)d_in[2];
  const float* pre = (const float*)d_in[3];
  const float* c0w = (const float*)d_in[4];
  const float* c0b = (const float*)d_in[5];
  const float* ln1g = (const float*)d_in[6];
  const float* ln1b = (const float*)d_in[7];
  const float* ln2g = (const float*)d_in[8];
  const float* ln2b = (const float*)d_in[9];
  const float* qkvw = (const float*)d_in[10];
  const float* qkvb = (const float*)d_in[11];
  const float* lw = (const float*)d_in[12];
  const float* lb = (const float*)d_in[13];
  const float* pw = (const float*)d_in[14];
  const float* pb = (const float*)d_in[15];
  const float* f1w = (const float*)d_in[16];
  const float* f1b = (const float*)d_in[17];
  const float* f2w = (const float*)d_in[18];
  const float* f2b = (const float*)d_in[19];

  float* W = (float*)d_ws;
  size_t o = 0;
  bf16* xct = (bf16*)(W + o);  o += (size_t)BB * GP * CK / 2;
  float* x_t  = W + o;         o += 3211264;
  bf16* attnRb = (bf16*)(W + o); o += 1605632;
  bf16* v_t  = (bf16*)(W + o); o += 1605632;
  bf16* z_t  = (bf16*)(W + o); o += 1605632;
  bf16* qR   = (bf16*)(W + o); o += 1605632;
  bf16* kR   = (bf16*)(W + o); o += 1605632;
  bf16* vT   = (bf16*)(W + o); o += 1605632;
  float* qd = W + o;           o += 12544;
  float* kd = W + o;           o += 12544;
  float* maskr = W + o;        o += 50176;
  bf16* wTb = (bf16*)(W + o);  o += 46080;
  int* gidx = (int*)(W + o);   o += 784;

  hipMemsetAsync(xct, 0, (size_t)BB * GP * CK * 2, stream);
  k_prep2<<<dim3(196, BB), dim3(256), 0, stream>>>(ex0, ex, img, pre, xct, maskr);
  k_wt2<<<dim3(360), dim3(256), 0, stream>>>(c0w, wTb);
  k_conv0m<<<dim3(98, BB), dim3(256), 0, stream>>>(xct, wTb, c0b, x_t);
  for (int i = 0; i < 4; i++) {
    k_qkv<<<dim3(98, BB), dim3(256), 0, stream>>>(x_t, ln1g + i * 64, ln1b + i * 64,
        qkvw + (size_t)i * 192 * 64, qkvb + i * 192, qR, kR, v_t);
    k_vpost<<<dim3(RR, BB), dim3(256), 0, stream>>>(qR, kR, v_t, qd, kd, vT);
    k_topk<<<dim3(RR, BB), dim3(64), 0, stream>>>(qd, kd, gidx);
    k_attn<<<dim3(BB * RR * 4), dim3(256), 0, stream>>>(qR, kR, vT, maskr, gidx, attnRb);
    k_lepe2<<<dim3(RR, BB), dim3(256), 0, stream>>>(v_t, attnRb, lw + (size_t)i * 64 * 25, lb + i * 64, z_t);
    k_proj<<<dim3(98, BB), dim3(256), 0, stream>>>(z_t, pw + (size_t)i * 64 * 64, pb + i * 64, x_t);
    k_mlp<<<dim3(196, BB), dim3(256), 0, stream>>>(x_t, ln2g + i * 64, ln2b + i * 64,
        f1w + (size_t)i * 256 * 64, f1b + i * 256, f2w + (size_t)i * 64 * 256, f2b + i * 64, x_t);
  }
  k_untr<<<dim3(196, BB), dim3(256), 0, stream>>>(x_t, (float*)d_out);
}

// Round 7
// 790.672 us; speedup vs baseline: 1.0543x; 1.0543x over previous
//
#include <hip/hip_runtime.h>

#define HW 112
#define PP 12544
#define BB 4
#define RR 49
#define RS 256
#define GW 114          // padded grid width (zero ring)
#define GP (GW*GW)      // 12996
#define CK 160          // padded channels for conv0

typedef __bf16 bf16;
typedef __bf16 bf16x8 __attribute__((ext_vector_type(8)));
typedef __bf16 bf16x4 __attribute__((ext_vector_type(4)));
typedef float f32x4 __attribute__((ext_vector_type(4)));

// XOR-swizzled byte offset in a row-major bf16 tile; rowbytes ∈ {128,256,512}
__device__ __forceinline__ int swzg(int row, int halfcol, int rowbytes) {
  int byte = halfcol * 2;
  return row * rowbytes + (byte & ~127) + ((((byte >> 4) ^ row) & 7) * 16) + (byte & 15);
}
__device__ __forceinline__ int swz128(int row, int halfcol) { return swzg(row, halfcol, 128); }

__device__ __forceinline__ float gelu_exact(float x) {
  return 0.5f * x * (1.f + erff(x * 0.70710678118654752f));
}

// ---------------- prep: downsample+concat -> xcat_t bf16 [n][grid 114x114][160], mask ----------------
__global__ __launch_bounds__(256) void k_prep2(const float* __restrict__ ex0, const float* __restrict__ ex,
    const float* __restrict__ img, const float* __restrict__ pre,
    bf16* __restrict__ xct, float* __restrict__ maskr) {
  __shared__ bf16 sT2[64 * 168];   // [pixel][168 ch] rows 336B (16B aligned)
  int n = blockIdx.y;
  int p0 = blockIdx.x * 64;
  int tid = threadIdx.x;
  uint4 zz = {0, 0, 0, 0};
  for (int i2 = tid; i2 < 1344; i2 += 256) ((uint4*)sT2)[i2] = zz;
  __syncthreads();
  int l = tid & 63, g = tid >> 6;
  int p = p0 + l;
  int h = p / HW, w = p % HW;
  for (int c = g; c < 131; c += 4) {
    float val;
    if (c < 64) {
      const float* s = ex0 + (((size_t)(n * 64 + c)) * 224 + 2 * h) * 224 + 2 * w;
      val = 0.5f * (0.5f * (s[0] + s[224]) + 0.5f * (s[1] + s[225]));
    } else if (c < 128) {
      val = ex[((size_t)(n * 64 + (c - 64))) * PP + p];
    } else {
      const float* s = img + (((size_t)(n * 3 + (c - 128))) * 224 + 2 * h) * 224 + 2 * w;
      val = 0.5f * (0.5f * (s[0] + s[224]) + 0.5f * (s[1] + s[225]));
    }
    sT2[l * 168 + c] = (bf16)val;
  }
  if (tid < 64) {
    const float* s = pre + ((size_t)n * 224 + 2 * h) * 224 + 2 * w;
    float v = 0.5f * (0.5f * (s[0] + s[224]) + 0.5f * (s[1] + s[225]));
    int r = (h >> 4) * 7 + (w >> 4); int sIdx = (h & 15) * 16 + (w & 15);
    maskr[(n * RR + r) * RS + sIdx] = (v > 0.0f) ? 0.0f : -100.0f;
  }
  __syncthreads();
  for (int i2 = tid; i2 < 1280; i2 += 256) {
    int row = i2 / 20, ch = i2 % 20;
    int pr = p0 + row;
    int hh = pr / HW, ww = pr % HW;
    uint4 d = *(const uint4*)(sT2 + row * 168 + ch * 8);
    *(uint4*)(xct + ((size_t)n * GP + (hh + 1) * GW + ww + 1) * CK + ch * 8) = d;
  }
}

// ---------------- conv0 weights -> wTb bf16 [9tap][5ks][64o][32c] ----------------
__global__ __launch_bounds__(256) void k_wt2(const float* __restrict__ w, bf16* __restrict__ wTb) {
  int t = blockIdx.x * 256 + threadIdx.x;
  if (t >= 9 * 5 * 64 * 32) return;
  int cc = t & 31; int o = (t >> 5) & 63; int ks = (t >> 11) % 5; int k = t / 10240;
  int c = ks * 32 + cc;
  wTb[t] = (bf16)((c < 131) ? w[((size_t)(o * 131) + c) * 9 + k] : 0.f);
}

// ---------------- conv0 as MFMA implicit GEMM: 9 shifted taps x 5 K-slices ----------------
__global__ __launch_bounds__(256) void k_conv0m(const bf16* __restrict__ xct, const bf16* __restrict__ wTb,
    const float* __restrict__ bias, float* __restrict__ out_t) {
  __shared__ bf16 sA[128 * 32];
  __shared__ bf16 sB[64 * 32];
  int n = blockIdx.y;
  int p0 = blockIdx.x * 128;
  int tid = threadIdx.x, lane = tid & 63, wv = tid >> 6;
  int lo = lane & 15, hi = lane >> 4;
  size_t gofsA[2];
  #pragma unroll
  for (int it = 0; it < 2; it++) {
    int idx = tid + it * 256;
    int row = idx >> 2, ch = idx & 3;
    int p = p0 + row;
    int hh = p / HW, ww = p % HW;
    gofsA[it] = ((size_t)(hh + 1) * GW + ww + 1) * (CK * 2) + ch * 16;
  }
  const char* xbase = (const char*)(xct + (size_t)n * GP * CK);
  f32x4 acc[2][4];
  #pragma unroll
  for (int mi = 0; mi < 2; mi++)
    #pragma unroll
    for (int ni = 0; ni < 4; ni++) acc[mi][ni] = (f32x4){0.f, 0.f, 0.f, 0.f};
  for (int tap = 0; tap < 9; tap++) {
    long shift = (long)((tap / 3 - 1) * GW + (tap % 3 - 1)) * (CK * 2);
    for (int ks = 0; ks < 5; ks++) {
      uint4 a0 = *(const uint4*)(xbase + gofsA[0] + shift + ks * 64);
      uint4 a1 = *(const uint4*)(xbase + gofsA[1] + shift + ks * 64);
      uint4 b0 = *(const uint4*)((const char*)wTb + ((size_t)(tap * 5 + ks) * 2048 + tid * 8) * 2);
      __syncthreads();
      *(uint4*)((char*)sA + tid * 16) = a0;
      *(uint4*)((char*)sA + (tid + 256) * 16) = a1;
      *(uint4*)((char*)sB + tid * 16) = b0;
      __syncthreads();
      bf16x8 aF[2], bF[4];
      #pragma unroll
      for (int mi = 0; mi < 2; mi++)
        aF[mi] = *(const bf16x8*)((const char*)sA + (wv * 32 + mi * 16 + lo) * 64 + hi * 16);
      #pragma unroll
      for (int ni = 0; ni < 4; ni++)
        bF[ni] = *(const bf16x8*)((const char*)sB + (ni * 16 + lo) * 64 + hi * 16);
      #pragma unroll
      for (int mi = 0; mi < 2; mi++)
        #pragma unroll
        for (int ni = 0; ni < 4; ni++)
          acc[mi][ni] = __builtin_amdgcn_mfma_f32_16x16x32_bf16(aF[mi], bF[ni], acc[mi][ni], 0, 0, 0);
    }
  }
  #pragma unroll
  for (int ni = 0; ni < 4; ni++) {
    float bv = bias[ni * 16 + lo];
    #pragma unroll
    for (int mi = 0; mi < 2; mi++) {
      #pragma unroll
      for (int r2 = 0; r2 < 4; r2++) {
        int p = p0 + wv * 32 + mi * 16 + hi * 4 + r2;
        out_t[((size_t)n * PP + p) * 64 + ni * 16 + lo] = acc[mi][ni][r2] + bv;
      }
    }
  }
}

// ---------------- qkv with fused LN1 ----------------
__global__ __launch_bounds__(256) void k_qkv(const float* __restrict__ xin, const float* __restrict__ lng,
    const float* __restrict__ lnb, const float* __restrict__ w, const float* __restrict__ bias,
    bf16* __restrict__ qRo, bf16* __restrict__ kRo, bf16* __restrict__ vto) {
  __shared__ bf16 sA[128 * 64];
  __shared__ bf16 sB[64 * 64];
  int n = blockIdx.y;
  int p0 = blockIdx.x * 128;
  int tid = threadIdx.x, lane = tid & 63, wv = tid >> 6;
  int lo = lane & 15, hi = lane >> 4;
  { // fused LN staging: 2 threads per row, 32 channels each
    int row = tid >> 1, part = tid & 1;
    const float* xp = xin + ((size_t)n * PP + p0 + row) * 64 + part * 32;
    float v[32]; float s = 0.f, sq = 0.f;
    #pragma unroll
    for (int i = 0; i < 8; i++) {
      float4 d = *(const float4*)&xp[i * 4];
      v[i*4]=d.x; v[i*4+1]=d.y; v[i*4+2]=d.z; v[i*4+3]=d.w;
      s += d.x+d.y+d.z+d.w;
      sq += d.x*d.x+d.y*d.y+d.z*d.z+d.w*d.w;
    }
    s += __shfl_xor(s, 1, 64); sq += __shfl_xor(sq, 1, 64);
    float mu = s * (1.f/64.f);
    float rstd = rsqrtf(fmaxf(sq * (1.f/64.f) - mu*mu, 0.f) + 1e-5f);
    #pragma unroll
    for (int j2 = 0; j2 < 4; j2++) {
      bf16x8 o8;
      #pragma unroll
      for (int e = 0; e < 8; e++) {
        int c = part*32 + j2*8 + e;
        o8[e] = (bf16)((v[j2*8+e] - mu) * rstd * lng[c] + lnb[c]);
      }
      *(bf16x8*)((char*)sA + swz128(row, part*32 + j2*8)) = o8;
    }
  }
  for (int ob = 0; ob < 3; ob++) {
    #pragma unroll
    for (int it = 0; it < 4; it++) {
      int idx = tid + it * 256;
      int oo = idx >> 4, q = idx & 15;
      float4 wv4 = *(const float4*)&w[(size_t)(ob * 64 + oo) * 64 + q * 4];
      bf16x4 b4; b4[0] = (bf16)wv4.x; b4[1] = (bf16)wv4.y; b4[2] = (bf16)wv4.z; b4[3] = (bf16)wv4.w;
      *(bf16x4*)((char*)sB + swz128(oo, q * 4)) = b4;
    }
    __syncthreads();
    f32x4 acc[2][4];
    #pragma unroll
    for (int mi = 0; mi < 2; mi++)
      #pragma unroll
      for (int ni = 0; ni < 4; ni++) acc[mi][ni] = (f32x4){0.f, 0.f, 0.f, 0.f};
    #pragma unroll
    for (int kk = 0; kk < 2; kk++) {
      bf16x8 aF[2], bF[4];
      #pragma unroll
      for (int mi = 0; mi < 2; mi++)
        aF[mi] = *(const bf16x8*)((const char*)sA + swz128(wv * 32 + mi * 16 + lo, kk * 32 + hi * 8));
      #pragma unroll
      for (int ni = 0; ni < 4; ni++)
        bF[ni] = *(const bf16x8*)((const char*)sB + swz128(ni * 16 + lo, kk * 32 + hi * 8));
      #pragma unroll
      for (int mi = 0; mi < 2; mi++)
        #pragma unroll
        for (int ni = 0; ni < 4; ni++)
          acc[mi][ni] = __builtin_amdgcn_mfma_f32_16x16x32_bf16(aF[mi], bF[ni], acc[mi][ni], 0, 0, 0);
    }
    #pragma unroll
    for (int ni = 0; ni < 4; ni++) {
      float bv = bias[ob * 64 + ni * 16 + lo];
      #pragma unroll
      for (int mi = 0; mi < 2; mi++) {
        #pragma unroll
        for (int r2 = 0; r2 < 4; r2++) {
          float rv = acc[mi][ni][r2] + bv;
          int p = p0 + wv * 32 + mi * 16 + hi * 4 + r2;
          int hh = p / HW, ww = p % HW;
          int rg = (hh >> 4) * 7 + (ww >> 4), s2 = (hh & 15) * 16 + (ww & 15);
          int o = ni * 16 + lo;
          if (ob == 0)      qRo[(((size_t)(n * RR + rg)) * RS + s2) * 64 + o] = (bf16)(rv * 0.125f);
          else if (ob == 1) kRo[(((size_t)(n * RR + rg)) * RS + s2) * 64 + o] = (bf16)rv;
          else              vto[((size_t)n * PP + p) * 64 + o] = (bf16)rv;
        }
      }
    }
    __syncthreads();
  }
}

// ---------------- per-region: vT transpose + qd/kd means ----------------
__global__ __launch_bounds__(256) void k_vpost(const bf16* __restrict__ qR, const bf16* __restrict__ kR,
    const bf16* __restrict__ v_t, float* __restrict__ qd, float* __restrict__ kd, bf16* __restrict__ vT) {
  __shared__ bf16 sT[64 * 264];
  __shared__ float rq[4][64], rk[4][64];
  int r = blockIdx.x, n = blockIdx.y;
  int nr = n * RR + r;
  int tid = threadIdx.x;
  int rh = (r / 7) * 16, rw = (r % 7) * 16;
  {
    int ph = rh + (tid >> 4), pw = rw + (tid & 15);
    const bf16* src = v_t + ((size_t)n * PP + ph * HW + pw) * 64;
    #pragma unroll
    for (int c8 = 0; c8 < 8; c8++) {
      bf16x8 d = *(const bf16x8*)(src + c8 * 8);
      #pragma unroll
      for (int j = 0; j < 8; j++) sT[(c8 * 8 + j) * 264 + tid] = d[j];
    }
  }
  {
    int c = tid & 63, sq = tid >> 6;
    const bf16* qb = qR + (size_t)nr * RS * 64;
    const bf16* kb = kR + (size_t)nr * RS * 64;
    float aq = 0.f, ak = 0.f;
    for (int s = sq * 64; s < sq * 64 + 64; s++) {
      aq += (float)qb[s * 64 + c];
      ak += (float)kb[s * 64 + c];
    }
    rq[sq][c] = aq; rk[sq][c] = ak;
  }
  __syncthreads();
  #pragma unroll
  for (int it = 0; it < 8; it++) {
    int idx = tid + it * 256;
    int row = idx >> 5, ch = idx & 31;
    uint4 d = *(const uint4*)(sT + row * 264 + ch * 8);
    *(uint4*)(vT + ((size_t)nr * 64 + row) * 256 + ch * 8) = d;
  }
  if (tid < 64) {
    int c = tid;
    qd[(n * 64 + c) * RR + r] = ((rq[0][c] + rq[1][c]) + (rq[2][c] + rq[3][c])) * (1.f / 256.f);
    kd[(n * 64 + c) * RR + r] = ((rk[0][c] + rk[1][c]) + (rk[2][c] + rk[3][c])) * (1.f / 256.f);
  }
}

// ---------------- top-4 routing: one wave per query region ----------------
__global__ __launch_bounds__(64) void k_topk(const float* __restrict__ qd, const float* __restrict__ kd,
    int* __restrict__ gidx) {
  int pq = blockIdx.x, n = blockIdx.y;
  int j = threadIdx.x;
  float a = -3e38f;
  if (j < RR) {
    a = 0.f;
    for (int c = 0; c < 64; c++)
      a += qd[(n * 64 + c) * RR + pq] * kd[(n * 64 + c) * RR + j];
  }
  for (int t = 0; t < 4; t++) {
    float bv = a; int bj = j;
    #pragma unroll
    for (int d = 32; d >= 1; d >>= 1) {
      float ov = __shfl_xor(bv, d, 64);
      int oj = __shfl_xor(bj, d, 64);
      if (ov > bv || (ov == bv && oj < bj)) { bv = ov; bj = oj; }
    }
    if (j == 0) gidx[(n * RR + pq) * 4 + t] = bj;
    if (j == bj) a = -3e38f;
  }
}

// ---------------- gathered-region flash attention: R5 structure + coalesced epilogue ----------------
// grid = BB*RR*4 (XCD-swizzled); block = 4 waves; wave owns 16 Q rows; KVBLK=64
__global__ __launch_bounds__(256) void k_attn(const bf16* __restrict__ qR, const bf16* __restrict__ kR,
    const bf16* __restrict__ vT, const float* __restrict__ maskr, const int* __restrict__ gidx,
    bf16* __restrict__ attnRb) {
  __shared__ bf16 sK[64 * 64];
  __shared__ bf16 sV[64 * 64];
  __shared__ bf16 sP[4][16 * 64];
  __shared__ float sMask[256];
  int bid = blockIdx.x;
  int newid = (bid & 7) * 98 + (bid >> 3);   // 784 = 8*98: bijective XCD chunking
  int n = newid / (RR * 4); int rem = newid % (RR * 4); int r = rem >> 2, qs = rem & 3;
  int tid = threadIdx.x, lane = tid & 63, wv = tid >> 6;
  int lo = lane & 15, hi = lane >> 4;
  int m0 = qs * 64 + wv * 16;
  const bf16* qbase = qR + ((size_t)(n * RR + r)) * RS * 64;
  bf16x8 qF[2];
  #pragma unroll
  for (int kk = 0; kk < 2; kk++)
    qF[kk] = *(const bf16x8*)(qbase + (m0 + lo) * 64 + kk * 32 + hi * 8);

  // LDS write offsets (swizzled) for the 2×uint4 staging per array
  int wofs[2];
  #pragma unroll
  for (int it = 0; it < 2; it++) {
    int idx = tid + it * 256;
    int row = idx >> 3, c4 = idx & 7;
    wofs[it] = row * 128 + (((c4 ^ row) & 7) * 16);
  }
  int srcK[2], srcV[2];   // element offsets within tile (sub-independent parts)
  #pragma unroll
  for (int it = 0; it < 2; it++) {
    int idx = tid + it * 256;
    int row = idx >> 3, c4 = idx & 7;
    srcK[it] = row * 64 + c4 * 8;      // + sub*64*64 row shift handled via sub*4096
    srcV[it] = row * 256 + c4 * 8;     // + sub*64 col shift
  }

  f32x4 zero4 = {0.f, 0.f, 0.f, 0.f};
  f32x4 Oacc[4];
  #pragma unroll
  for (int di = 0; di < 4; di++) Oacc[di] = zero4;
  float mrun[4], lrun[4];
  #pragma unroll
  for (int s = 0; s < 4; s++) { mrun[s] = -3e38f; lrun[s] = 0.f; }

  const int* gptr = gidx + (n * RR + r) * 4;
  int j0 = gptr[0];
  const bf16* kbase = kR + ((size_t)(n * RR + j0)) * RS * 64;
  const bf16* vbase = vT + ((size_t)(n * RR + j0)) * 64 * RS;
  const float* mbase = maskr + (n * RR + j0) * RS;
  uint4 regK[2], regV[2]; float regM;
  // preload ts=0 (t=0, sub=0)
  #pragma unroll
  for (int it = 0; it < 2; it++) {
    regK[it] = *(const uint4*)(kbase + srcK[it]);
    regV[it] = *(const uint4*)(vbase + srcV[it]);
  }
  regM = mbase[tid];

  for (int ts = 0; ts < 16; ts++) {
    int sub = ts & 3;
    __syncthreads();   // all waves done reading LDS from previous iteration
    #pragma unroll
    for (int it = 0; it < 2; it++) {
      *(uint4*)((char*)sK + wofs[it]) = regK[it];
      *(uint4*)((char*)sV + wofs[it]) = regV[it];
    }
    if (sub == 0) sMask[tid] = regM;
    __syncthreads();
    // prefetch next sub while computing this one
    if (ts < 15) {
      int nts = ts + 1, nsub = nts & 3;
      if (nsub == 0) {
        int j = gptr[nts >> 2];
        kbase = kR + ((size_t)(n * RR + j)) * RS * 64;
        vbase = vT + ((size_t)(n * RR + j)) * 64 * RS;
        mbase = maskr + (n * RR + j) * RS;
        regM = mbase[tid];
      }
      #pragma unroll
      for (int it = 0; it < 2; it++) {
        regK[it] = *(const uint4*)(kbase + nsub * 4096 + srcK[it]);
        regV[it] = *(const uint4*)(vbase + nsub * 64 + srcV[it]);
      }
    }
    // ---- compute sub ----
    f32x4 Sacc[4];
    #pragma unroll
    for (int ni = 0; ni < 4; ni++) Sacc[ni] = zero4;
    #pragma unroll
    for (int kk = 0; kk < 2; kk++) {
      #pragma unroll
      for (int ni = 0; ni < 4; ni++) {
        bf16x8 bF = *(const bf16x8*)((const char*)sK + swz128(ni * 16 + lo, kk * 32 + hi * 8));
        Sacc[ni] = __builtin_amdgcn_mfma_f32_16x16x32_bf16(qF[kk], bF, Sacc[ni], 0, 0, 0);
      }
    }
    float mv[4];
    #pragma unroll
    for (int ni = 0; ni < 4; ni++) mv[ni] = sMask[sub * 64 + ni * 16 + lo];
    bf16* sPw = sP[wv];
    #pragma unroll
    for (int jj = 0; jj < 4; jj++) {
      float cm = fmaxf(fmaxf(Sacc[0][jj] + mv[0], Sacc[1][jj] + mv[1]),
                       fmaxf(Sacc[2][jj] + mv[2], Sacc[3][jj] + mv[3]));
      #pragma unroll
      for (int d2 = 1; d2 < 16; d2 <<= 1) cm = fmaxf(cm, __shfl_xor(cm, d2, 64));
      float nm = fmaxf(mrun[jj], cm);
      float sc = __expf(mrun[jj] - nm);
      float rsum = 0.f; float pv[4];
      #pragma unroll
      for (int ni = 0; ni < 4; ni++) { pv[ni] = __expf(Sacc[ni][jj] + mv[ni] - nm); rsum += pv[ni]; }
      #pragma unroll
      for (int d2 = 1; d2 < 16; d2 <<= 1) rsum += __shfl_xor(rsum, d2, 64);
      mrun[jj] = nm; lrun[jj] = lrun[jj] * sc + rsum;
      #pragma unroll
      for (int di = 0; di < 4; di++) Oacc[di][jj] *= sc;
      int prow = hi * 4 + jj;
      #pragma unroll
      for (int ni = 0; ni < 4; ni++)
        *(bf16*)((char*)sPw + swz128(prow, ni * 16 + lo)) = (bf16)pv[ni];
    }
    #pragma unroll
    for (int kk = 0; kk < 2; kk++) {
      bf16x8 pF = *(const bf16x8*)((const char*)sPw + swz128(lo, kk * 32 + hi * 8));
      #pragma unroll
      for (int di = 0; di < 4; di++) {
        bf16x8 vF = *(const bf16x8*)((const char*)sV + swz128(di * 16 + lo, kk * 32 + hi * 8));
        Oacc[di] = __builtin_amdgcn_mfma_f32_16x16x32_bf16(pF, vF, Oacc[di], 0, 0, 0);
      }
    }
  }
  // ---- coalesced epilogue: normalize -> LDS repack (reuse sK) -> contiguous uint4 stores ----
  __syncthreads();                 // all waves finished reading sK/sV
  bf16* sOut = sK;                 // 8KB = 64 rows x 64 ch
  #pragma unroll
  for (int jj = 0; jj < 4; jj++) {
    float inv = 1.f / lrun[jj];
    int row = wv * 16 + hi * 4 + jj;
    #pragma unroll
    for (int di = 0; di < 4; di++)
      sOut[row * 64 + di * 16 + lo] = (bf16)(Oacc[di][jj] * inv);
  }
  __syncthreads();
  bf16* dst = attnRb + (((size_t)(n * RR + r)) * RS + qs * 64) * 64;
  #pragma unroll
  for (int it = 0; it < 2; it++) {
    int idx = tid + it * 256;
    *(uint4*)(dst + idx * 8) = *(const uint4*)(sOut + idx * 8);
  }
}

// ---------------- lepe 5x5 dw + from_regions (attnR bf16) ----------------
__global__ __launch_bounds__(256) void k_lepe2(const bf16* __restrict__ v_t, const bf16* __restrict__ attnRb,
    const float* __restrict__ lw, const float* __restrict__ lb, bf16* __restrict__ z_t) {
  __shared__ bf16 sH[400 * 72];
  __shared__ float sW[25][64];
  int r = blockIdx.x, n = blockIdx.y;
  int rh = (r / 7) * 16, rw = (r % 7) * 16;
  int tid = threadIdx.x;
  for (int i = tid; i < 1600; i += 256) { int c = i / 25, k = i % 25; sW[k][c] = lw[c * 25 + k]; }
  for (int g = tid; g < 3200; g += 256) {
    int pix = g >> 3, c4 = g & 7;
    int yy = pix / 20, xx = pix % 20;
    int hh = rh + yy - 2, ww = rw + xx - 2;
    uint4 d = {0, 0, 0, 0};
    if ((unsigned)hh < HW && (unsigned)ww < HW)
      d = *(const uint4*)(v_t + ((size_t)n * PP + hh * HW + ww) * 64 + c4 * 8);
    *(uint4*)((char*)sH + pix * 144 + c4 * 16) = d;
  }
  __syncthreads();
  int y = tid >> 4, x = tid & 15;
  float acc[64];
  const bf16* ar = attnRb + (((size_t)(n * RR + r)) * RS + tid) * 64;
  #pragma unroll
  for (int c8 = 0; c8 < 8; c8++) {
    bf16x8 av = *(const bf16x8*)(ar + c8 * 8);
    #pragma unroll
    for (int j = 0; j < 8; j++) acc[c8 * 8 + j] = lb[c8 * 8 + j] + (float)av[j];
  }
  for (int t25 = 0; t25 < 25; t25++) {
    int dh = t25 / 5, dw = t25 % 5;
    int pix = (y + dh) * 20 + (x + dw);
    #pragma unroll
    for (int c8 = 0; c8 < 8; c8++) {
      bf16x8 hv = *(const bf16x8*)((const char*)sH + pix * 144 + c8 * 16);
      #pragma unroll
      for (int j = 0; j < 8; j++) acc[c8 * 8 + j] += (float)hv[j] * sW[t25][c8 * 8 + j];
    }
  }
  bf16* zp = z_t + ((size_t)n * PP + (rh + y) * HW + rw + x) * 64;
  #pragma unroll
  for (int c8 = 0; c8 < 8; c8++) {
    bf16x8 o8;
    #pragma unroll
    for (int j = 0; j < 8; j++) o8[j] = (bf16)acc[c8 * 8 + j];
    *(bf16x8*)(zp + c8 * 8) = o8;
  }
}

// ---------------- proj GEMM: z_t -> x_t += ----------------
__global__ __launch_bounds__(256) void k_proj(const bf16* __restrict__ A, const float* __restrict__ w,
    const float* __restrict__ bias, float* __restrict__ xo) {
  __shared__ bf16 sA[128 * 64];
  __shared__ bf16 sB[64 * 64];
  int n = blockIdx.y;
  int p0 = blockIdx.x * 128;
  int tid = threadIdx.x, lane = tid & 63, wv = tid >> 6;
  int lo = lane & 15, hi = lane >> 4;
  const bf16* Abase = A + (size_t)n * PP * 64;
  #pragma unroll
  for (int it = 0; it < 4; it++) {
    int idx = tid + it * 256;
    int row = idx >> 3, c4 = idx & 7;
    uint4 d = *(const uint4*)(Abase + (size_t)(p0 + row) * 64 + c4 * 8);
    *(uint4*)((char*)sA + row * 128 + (((c4 ^ row) & 7) * 16)) = d;
  }
  #pragma unroll
  for (int it = 0; it < 4; it++) {
    int idx = tid + it * 256;
    int oo = idx >> 4, q = idx & 15;
    float4 wv4 = *(const float4*)&w[(size_t)oo * 64 + q * 4];
    bf16x4 b4; b4[0] = (bf16)wv4.x; b4[1] = (bf16)wv4.y; b4[2] = (bf16)wv4.z; b4[3] = (bf16)wv4.w;
    *(bf16x4*)((char*)sB + swz128(oo, q * 4)) = b4;
  }
  __syncthreads();
  f32x4 acc[2][4];
  #pragma unroll
  for (int mi = 0; mi < 2; mi++)
    #pragma unroll
    for (int ni = 0; ni < 4; ni++) acc[mi][ni] = (f32x4){0.f, 0.f, 0.f, 0.f};
  #pragma unroll
  for (int kk = 0; kk < 2; kk++) {
    bf16x8 aF[2], bF[4];
    #pragma unroll
    for (int mi = 0; mi < 2; mi++)
      aF[mi] = *(const bf16x8*)((const char*)sA + swz128(wv * 32 + mi * 16 + lo, kk * 32 + hi * 8));
    #pragma unroll
    for (int ni = 0; ni < 4; ni++)
      bF[ni] = *(const bf16x8*)((const char*)sB + swz128(ni * 16 + lo, kk * 32 + hi * 8));
    #pragma unroll
    for (int mi = 0; mi < 2; mi++)
      #pragma unroll
      for (int ni = 0; ni < 4; ni++)
        acc[mi][ni] = __builtin_amdgcn_mfma_f32_16x16x32_bf16(aF[mi], bF[ni], acc[mi][ni], 0, 0, 0);
  }
  #pragma unroll
  for (int ni = 0; ni < 4; ni++) {
    float bv = bias[ni * 16 + lo];
    #pragma unroll
    for (int mi = 0; mi < 2; mi++) {
      #pragma unroll
      for (int r2 = 0; r2 < 4; r2++) {
        int p = p0 + wv * 32 + mi * 16 + hi * 4 + r2;
        xo[((size_t)n * PP + p) * 64 + ni * 16 + lo] += acc[mi][ni][r2] + bv;
      }
    }
  }
}

// ---------------- fused MLP: LN2 + fc1 + gelu + fc2 + residual ----------------
__global__ __launch_bounds__(256) void k_mlp(const float* __restrict__ xin, const float* __restrict__ lng,
    const float* __restrict__ lnb, const float* __restrict__ w1, const float* __restrict__ b1,
    const float* __restrict__ w2, const float* __restrict__ b2, float* __restrict__ xo) {
  __shared__ bf16 sA[64 * 64];
  __shared__ bf16 sW1[128 * 64];
  __shared__ bf16 sHh[64 * 128];
  __shared__ bf16 sW2[64 * 128];
  int n = blockIdx.y;
  int p0 = blockIdx.x * 64;
  int tid = threadIdx.x, lane = tid & 63, wv = tid >> 6;
  int lo = lane & 15, hi = lane >> 4;
  { // fused LN staging: 4 threads per row, 16 channels each
    int row = tid >> 2, part = tid & 3;
    const float* xp = xin + ((size_t)n * PP + p0 + row) * 64 + part * 16;
    float v[16]; float s = 0.f, sq = 0.f;
    #pragma unroll
    for (int i = 0; i < 4; i++) {
      float4 d = *(const float4*)&xp[i * 4];
      v[i*4]=d.x; v[i*4+1]=d.y; v[i*4+2]=d.z; v[i*4+3]=d.w;
      s += d.x+d.y+d.z+d.w;
      sq += d.x*d.x+d.y*d.y+d.z*d.z+d.w*d.w;
    }
    s += __shfl_xor(s, 1, 64); sq += __shfl_xor(sq, 1, 64);
    s += __shfl_xor(s, 2, 64); sq += __shfl_xor(sq, 2, 64);
    float mu = s * (1.f/64.f);
    float rstd = rsqrtf(fmaxf(sq * (1.f/64.f) - mu*mu, 0.f) + 1e-5f);
    #pragma unroll
    for (int j2 = 0; j2 < 2; j2++) {
      bf16x8 o8;
      #pragma unroll
      for (int e = 0; e < 8; e++) {
        int c = part*16 + j2*8 + e;
        o8[e] = (bf16)((v[j2*8+e] - mu) * rstd * lng[c] + lnb[c]);
      }
      *(bf16x8*)((char*)sA + swz128(row, part*16 + j2*8)) = o8;
    }
  }
  f32x4 oacc[4];
  #pragma unroll
  for (int ni = 0; ni < 4; ni++) oacc[ni] = (f32x4){0.f, 0.f, 0.f, 0.f};
  for (int half = 0; half < 2; half++) {
    #pragma unroll
    for (int it = 0; it < 8; it++) {
      int idx = tid + it * 256;
      int oo = idx >> 4, q = idx & 15;
      float4 wv4 = *(const float4*)&w1[(size_t)(half * 128 + oo) * 64 + q * 4];
      bf16x4 b4; b4[0] = (bf16)wv4.x; b4[1] = (bf16)wv4.y; b4[2] = (bf16)wv4.z; b4[3] = (bf16)wv4.w;
      *(bf16x4*)((char*)sW1 + swz128(oo, q * 4)) = b4;
    }
    __syncthreads();
    f32x4 hacc[8];
    #pragma unroll
    for (int ni = 0; ni < 8; ni++) hacc[ni] = (f32x4){0.f, 0.f, 0.f, 0.f};
    #pragma unroll
    for (int kk = 0; kk < 2; kk++) {
      bf16x8 aF = *(const bf16x8*)((const char*)sA + swz128(wv * 16 + lo, kk * 32 + hi * 8));
      #pragma unroll
      for (int ni = 0; ni < 8; ni++) {
        bf16x8 bF = *(const bf16x8*)((const char*)sW1 + swz128(ni * 16 + lo, kk * 32 + hi * 8));
        hacc[ni] = __builtin_amdgcn_mfma_f32_16x16x32_bf16(aF, bF, hacc[ni], 0, 0, 0);
      }
    }
    #pragma unroll
    for (int ni = 0; ni < 8; ni++) {
      float bv = b1[half * 128 + ni * 16 + lo];
      #pragma unroll
      for (int r2 = 0; r2 < 4; r2++) {
        float hval = gelu_exact(hacc[ni][r2] + bv);
        *(bf16*)((char*)sHh + swzg(wv * 16 + hi * 4 + r2, ni * 16 + lo, 256)) = (bf16)hval;
      }
    }
    #pragma unroll
    for (int it = 0; it < 8; it++) {
      int idx = tid + it * 256;
      int oo = idx >> 5, q = idx & 31;
      float4 wv4 = *(const float4*)&w2[(size_t)oo * 256 + half * 128 + q * 4];
      bf16x4 b4; b4[0] = (bf16)wv4.x; b4[1] = (bf16)wv4.y; b4[2] = (bf16)wv4.z; b4[3] = (bf16)wv4.w;
      *(bf16x4*)((char*)sW2 + swzg(oo, q * 4, 256)) = b4;
    }
    __syncthreads();
    #pragma unroll
    for (int kk = 0; kk < 4; kk++) {
      bf16x8 aH = *(const bf16x8*)((const char*)sHh + swzg(wv * 16 + lo, kk * 32 + hi * 8, 256));
      #pragma unroll
      for (int ni = 0; ni < 4; ni++) {
        bf16x8 bF = *(const bf16x8*)((const char*)sW2 + swzg(ni * 16 + lo, kk * 32 + hi * 8, 256));
        oacc[ni] = __builtin_amdgcn_mfma_f32_16x16x32_bf16(aH, bF, oacc[ni], 0, 0, 0);
      }
    }
    __syncthreads();
  }
  #pragma unroll
  for (int ni = 0; ni < 4; ni++) {
    float bv = b2[ni * 16 + lo];
    #pragma unroll
    for (int r2 = 0; r2 < 4; r2++) {
      int p = p0 + wv * 16 + hi * 4 + r2;
      xo[((size_t)n * PP + p) * 64 + ni * 16 + lo] += oacc[ni][r2] + bv;
    }
  }
}

// ---------------- final untranspose: x_t[p][c] -> out[c][p] ----------------
__global__ __launch_bounds__(256) void k_untr(const float* __restrict__ x_t, float* __restrict__ out) {
  __shared__ float tile[64][68];
  int n = blockIdx.y; int p0 = blockIdx.x * 64;
  int tid = threadIdx.x;
  #pragma unroll
  for (int it = 0; it < 4; it++) {
    int g = tid + it * 256;
    int row = g >> 4, q = g & 15;
    float4 d = *(const float4*)&x_t[((size_t)n * PP + p0 + row) * 64 + q * 4];
    *(float4*)&tile[row][q * 4] = d;
  }
  __syncthreads();
  #pragma unroll
  for (int it = 0; it < 4; it++) {
    int g = tid + it * 256;
    int c = g >> 4, q = g & 15;
    float4 v;
    v.x = tile[q * 4 + 0][c]; v.y = tile[q * 4 + 1][c];
    v.z = tile[q * 4 + 2][c]; v.w = tile[q * 4 + 3][c];
    *(float4*)&out[((size_t)(n * 64 + c)) * PP + p0 + q * 4] = v;
  }
}

extern "C" void kernel_launch(void* const* d_in, const int* in_sizes, int n_in,
                              void* d_out, int out_size, void* d_ws, size_t ws_size,
                              hipStream_t stream) {
  const float* ex0 = (const float*)d_in[0];
  const float* ex  = (const float*)d_in[1];
  const float* img = (const float*)d_in[2];
  const float* pre = (const float*)d_in[3];
  const float* c0w = (const float*)d_in[4];
  const float* c0b = (const float*)d_in[5];
  const float* ln1g = (const float*)d_in[6];
  const float* ln1b = (const float*)d_in[7];
  const float* ln2g = (const float*)d_in[8];
  const float* ln2b = (const float*)d_in[9];
  const float* qkvw = (const float*)d_in[10];
  const float* qkvb = (const float*)d_in[11];
  const float* lw = (const float*)d_in[12];
  const float* lb = (const float*)d_in[13];
  const float* pw = (const float*)d_in[14];
  const float* pb = (const float*)d_in[15];
  const float* f1w = (const float*)d_in[16];
  const float* f1b = (const float*)d_in[17];
  const float* f2w = (const float*)d_in[18];
  const float* f2b = (const float*)d_in[19];

  float* W = (float*)d_ws;
  size_t o = 0;
  bf16* xct = (bf16*)(W + o);  o += (size_t)BB * GP * CK / 2;
  float* x_t  = W + o;         o += 3211264;
  bf16* attnRb = (bf16*)(W + o); o += 1605632;
  bf16* v_t  = (bf16*)(W + o); o += 1605632;
  bf16* z_t  = (bf16*)(W + o); o += 1605632;
  bf16* qR   = (bf16*)(W + o); o += 1605632;
  bf16* kR   = (bf16*)(W + o); o += 1605632;
  bf16* vT   = (bf16*)(W + o); o += 1605632;
  float* qd = W + o;           o += 12544;
  float* kd = W + o;           o += 12544;
  float* maskr = W + o;        o += 50176;
  bf16* wTb = (bf16*)(W + o);  o += 46080;
  int* gidx = (int*)(W + o);   o += 784;

  hipMemsetAsync(xct, 0, (size_t)BB * GP * CK * 2, stream);
  k_prep2<<<dim3(196, BB), dim3(256), 0, stream>>>(ex0, ex, img, pre, xct, maskr);
  k_wt2<<<dim3(360), dim3(256), 0, stream>>>(c0w, wTb);
  k_conv0m<<<dim3(98, BB), dim3(256), 0, stream>>>(xct, wTb, c0b, x_t);
  for (int i = 0; i < 4; i++) {
    k_qkv<<<dim3(98, BB), dim3(256), 0, stream>>>(x_t, ln1g + i * 64, ln1b + i * 64,
        qkvw + (size_t)i * 192 * 64, qkvb + i * 192, qR, kR, v_t);
    k_vpost<<<dim3(RR, BB), dim3(256), 0, stream>>>(qR, kR, v_t, qd, kd, vT);
    k_topk<<<dim3(RR, BB), dim3(64), 0, stream>>>(qd, kd, gidx);
    k_attn<<<dim3(BB * RR * 4), dim3(256), 0, stream>>>(qR, kR, vT, maskr, gidx, attnRb);
    k_lepe2<<<dim3(RR, BB), dim3(256), 0, stream>>>(v_t, attnRb, lw + (size_t)i * 64 * 25, lb + i * 64, z_t);
    k_proj<<<dim3(98, BB), dim3(256), 0, stream>>>(z_t, pw + (size_t)i * 64 * 64, pb + i * 64, x_t);
    k_mlp<<<dim3(196, BB), dim3(256), 0, stream>>>(x_t, ln2g + i * 64, ln2b + i * 64,
        f1w + (size_t)i * 256 * 64, f1b + i * 256, f2w + (size_t)i * 64 * 256, f2b + i * 64, x_t);
  }
  k_untr<<<dim3(196, BB), dim3(256), 0, stream>>>(x_t, (float*)d_out);
}

// Round 8
// 726.452 us; speedup vs baseline: 1.1475x; 1.0884x over previous
//
#include <hip/hip_runtime.h>

#define HW 112
#define PP 12544
#define BB 4
#define RR 49
#define RS 256
#define GW 114          // padded grid width (zero ring)
#define GP (GW*GW)      // 12996
#define CK 160          // padded channels for conv0

typedef __bf16 bf16;
typedef __bf16 bf16x8 __attribute__((ext_vector_type(8)));
typedef __bf16 bf16x4 __attribute__((ext_vector_type(4)));
typedef float f32x4 __attribute__((ext_vector_type(4)));

// XOR-swizzled byte offset in a row-major bf16 tile; rowbytes ∈ {128,256,512}
__device__ __forceinline__ int swzg(int row, int halfcol, int rowbytes) {
  int byte = halfcol * 2;
  return row * rowbytes + (byte & ~127) + ((((byte >> 4) ^ row) & 7) * 16) + (byte & 15);
}
__device__ __forceinline__ int swz128(int row, int halfcol) { return swzg(row, halfcol, 128); }

__device__ __forceinline__ float gelu_exact(float x) {
  return 0.5f * x * (1.f + erff(x * 0.70710678118654752f));
}

// async global->LDS (no VGPR round-trip). LDS dest = wave-uniform base + lane*size.
__device__ __forceinline__ void gl_lds16(const void* g, void* l) {
  __builtin_amdgcn_global_load_lds((const __attribute__((address_space(1))) unsigned int*)g,
                                   (__attribute__((address_space(3))) unsigned int*)l, 16, 0, 0);
}
__device__ __forceinline__ void gl_lds4(const void* g, void* l) {
  __builtin_amdgcn_global_load_lds((const __attribute__((address_space(1))) unsigned int*)g,
                                   (__attribute__((address_space(3))) unsigned int*)l, 4, 0, 0);
}

// ---------------- prep: downsample+concat -> xcat_t bf16 [n][grid 114x114][160], mask ----------------
__global__ __launch_bounds__(256) void k_prep2(const float* __restrict__ ex0, const float* __restrict__ ex,
    const float* __restrict__ img, const float* __restrict__ pre,
    bf16* __restrict__ xct, float* __restrict__ maskr) {
  __shared__ bf16 sT2[64 * 168];   // [pixel][168 ch] rows 336B (16B aligned)
  int n = blockIdx.y;
  int p0 = blockIdx.x * 64;
  int tid = threadIdx.x;
  uint4 zz = {0, 0, 0, 0};
  for (int i2 = tid; i2 < 1344; i2 += 256) ((uint4*)sT2)[i2] = zz;
  __syncthreads();
  int l = tid & 63, g = tid >> 6;
  int p = p0 + l;
  int h = p / HW, w = p % HW;
  for (int c = g; c < 131; c += 4) {
    float val;
    if (c < 64) {
      const float* s = ex0 + (((size_t)(n * 64 + c)) * 224 + 2 * h) * 224 + 2 * w;
      val = 0.5f * (0.5f * (s[0] + s[224]) + 0.5f * (s[1] + s[225]));
    } else if (c < 128) {
      val = ex[((size_t)(n * 64 + (c - 64))) * PP + p];
    } else {
      const float* s = img + (((size_t)(n * 3 + (c - 128))) * 224 + 2 * h) * 224 + 2 * w;
      val = 0.5f * (0.5f * (s[0] + s[224]) + 0.5f * (s[1] + s[225]));
    }
    sT2[l * 168 + c] = (bf16)val;
  }
  if (tid < 64) {
    const float* s = pre + ((size_t)n * 224 + 2 * h) * 224 + 2 * w;
    float v = 0.5f * (0.5f * (s[0] + s[224]) + 0.5f * (s[1] + s[225]));
    int r = (h >> 4) * 7 + (w >> 4); int sIdx = (h & 15) * 16 + (w & 15);
    maskr[(n * RR + r) * RS + sIdx] = (v > 0.0f) ? 0.0f : -100.0f;
  }
  __syncthreads();
  for (int i2 = tid; i2 < 1280; i2 += 256) {
    int row = i2 / 20, ch = i2 % 20;
    int pr = p0 + row;
    int hh = pr / HW, ww = pr % HW;
    uint4 d = *(const uint4*)(sT2 + row * 168 + ch * 8);
    *(uint4*)(xct + ((size_t)n * GP + (hh + 1) * GW + ww + 1) * CK + ch * 8) = d;
  }
}

// ---------------- conv0 weights -> wTb bf16 [9tap][5ks][64o][32c] ----------------
__global__ __launch_bounds__(256) void k_wt2(const float* __restrict__ w, bf16* __restrict__ wTb) {
  int t = blockIdx.x * 256 + threadIdx.x;
  if (t >= 9 * 5 * 64 * 32) return;
  int cc = t & 31; int o = (t >> 5) & 63; int ks = (t >> 11) % 5; int k = t / 10240;
  int c = ks * 32 + cc;
  wTb[t] = (bf16)((c < 131) ? w[((size_t)(o * 131) + c) * 9 + k] : 0.f);
}

// ---------------- conv0 as MFMA implicit GEMM: 9 shifted taps x 5 K-slices ----------------
__global__ __launch_bounds__(256) void k_conv0m(const bf16* __restrict__ xct, const bf16* __restrict__ wTb,
    const float* __restrict__ bias, float* __restrict__ out_t) {
  __shared__ bf16 sA[128 * 32];
  __shared__ bf16 sB[64 * 32];
  int n = blockIdx.y;
  int p0 = blockIdx.x * 128;
  int tid = threadIdx.x, lane = tid & 63, wv = tid >> 6;
  int lo = lane & 15, hi = lane >> 4;
  size_t gofsA[2];
  #pragma unroll
  for (int it = 0; it < 2; it++) {
    int idx = tid + it * 256;
    int row = idx >> 2, ch = idx & 3;
    int p = p0 + row;
    int hh = p / HW, ww = p % HW;
    gofsA[it] = ((size_t)(hh + 1) * GW + ww + 1) * (CK * 2) + ch * 16;
  }
  const char* xbase = (const char*)(xct + (size_t)n * GP * CK);
  f32x4 acc[2][4];
  #pragma unroll
  for (int mi = 0; mi < 2; mi++)
    #pragma unroll
    for (int ni = 0; ni < 4; ni++) acc[mi][ni] = (f32x4){0.f, 0.f, 0.f, 0.f};
  for (int tap = 0; tap < 9; tap++) {
    long shift = (long)((tap / 3 - 1) * GW + (tap % 3 - 1)) * (CK * 2);
    for (int ks = 0; ks < 5; ks++) {
      uint4 a0 = *(const uint4*)(xbase + gofsA[0] + shift + ks * 64);
      uint4 a1 = *(const uint4*)(xbase + gofsA[1] + shift + ks * 64);
      uint4 b0 = *(const uint4*)((const char*)wTb + ((size_t)(tap * 5 + ks) * 2048 + tid * 8) * 2);
      __syncthreads();
      *(uint4*)((char*)sA + tid * 16) = a0;
      *(uint4*)((char*)sA + (tid + 256) * 16) = a1;
      *(uint4*)((char*)sB + tid * 16) = b0;
      __syncthreads();
      bf16x8 aF[2], bF[4];
      #pragma unroll
      for (int mi = 0; mi < 2; mi++)
        aF[mi] = *(const bf16x8*)((const char*)sA + (wv * 32 + mi * 16 + lo) * 64 + hi * 16);
      #pragma unroll
      for (int ni = 0; ni < 4; ni++)
        bF[ni] = *(const bf16x8*)((const char*)sB + (ni * 16 + lo) * 64 + hi * 16);
      #pragma unroll
      for (int mi = 0; mi < 2; mi++)
        #pragma unroll
        for (int ni = 0; ni < 4; ni++)
          acc[mi][ni] = __builtin_amdgcn_mfma_f32_16x16x32_bf16(aF[mi], bF[ni], acc[mi][ni], 0, 0, 0);
    }
  }
  #pragma unroll
  for (int ni = 0; ni < 4; ni++) {
    float bv = bias[ni * 16 + lo];
    #pragma unroll
    for (int mi = 0; mi < 2; mi++) {
      #pragma unroll
      for (int r2 = 0; r2 < 4; r2++) {
        int p = p0 + wv * 32 + mi * 16 + hi * 4 + r2;
        out_t[((size_t)n * PP + p) * 64 + ni * 16 + lo] = acc[mi][ni][r2] + bv;
      }
    }
  }
}

// ---------------- qkv with fused LN1 ----------------
__global__ __launch_bounds__(256) void k_qkv(const float* __restrict__ xin, const float* __restrict__ lng,
    const float* __restrict__ lnb, const float* __restrict__ w, const float* __restrict__ bias,
    bf16* __restrict__ qRo, bf16* __restrict__ kRo, bf16* __restrict__ vto) {
  __shared__ bf16 sA[128 * 64];
  __shared__ bf16 sB[64 * 64];
  int n = blockIdx.y;
  int p0 = blockIdx.x * 128;
  int tid = threadIdx.x, lane = tid & 63, wv = tid >> 6;
  int lo = lane & 15, hi = lane >> 4;
  { // fused LN staging: 2 threads per row, 32 channels each
    int row = tid >> 1, part = tid & 1;
    const float* xp = xin + ((size_t)n * PP + p0 + row) * 64 + part * 32;
    float v[32]; float s = 0.f, sq = 0.f;
    #pragma unroll
    for (int i = 0; i < 8; i++) {
      float4 d = *(const float4*)&xp[i * 4];
      v[i*4]=d.x; v[i*4+1]=d.y; v[i*4+2]=d.z; v[i*4+3]=d.w;
      s += d.x+d.y+d.z+d.w;
      sq += d.x*d.x+d.y*d.y+d.z*d.z+d.w*d.w;
    }
    s += __shfl_xor(s, 1, 64); sq += __shfl_xor(sq, 1, 64);
    float mu = s * (1.f/64.f);
    float rstd = rsqrtf(fmaxf(sq * (1.f/64.f) - mu*mu, 0.f) + 1e-5f);
    #pragma unroll
    for (int j2 = 0; j2 < 4; j2++) {
      bf16x8 o8;
      #pragma unroll
      for (int e = 0; e < 8; e++) {
        int c = part*32 + j2*8 + e;
        o8[e] = (bf16)((v[j2*8+e] - mu) * rstd * lng[c] + lnb[c]);
      }
      *(bf16x8*)((char*)sA + swz128(row, part*32 + j2*8)) = o8;
    }
  }
  for (int ob = 0; ob < 3; ob++) {
    #pragma unroll
    for (int it = 0; it < 4; it++) {
      int idx = tid + it * 256;
      int oo = idx >> 4, q = idx & 15;
      float4 wv4 = *(const float4*)&w[(size_t)(ob * 64 + oo) * 64 + q * 4];
      bf16x4 b4; b4[0] = (bf16)wv4.x; b4[1] = (bf16)wv4.y; b4[2] = (bf16)wv4.z; b4[3] = (bf16)wv4.w;
      *(bf16x4*)((char*)sB + swz128(oo, q * 4)) = b4;
    }
    __syncthreads();
    f32x4 acc[2][4];
    #pragma unroll
    for (int mi = 0; mi < 2; mi++)
      #pragma unroll
      for (int ni = 0; ni < 4; ni++) acc[mi][ni] = (f32x4){0.f, 0.f, 0.f, 0.f};
    #pragma unroll
    for (int kk = 0; kk < 2; kk++) {
      bf16x8 aF[2], bF[4];
      #pragma unroll
      for (int mi = 0; mi < 2; mi++)
        aF[mi] = *(const bf16x8*)((const char*)sA + swz128(wv * 32 + mi * 16 + lo, kk * 32 + hi * 8));
      #pragma unroll
      for (int ni = 0; ni < 4; ni++)
        bF[ni] = *(const bf16x8*)((const char*)sB + swz128(ni * 16 + lo, kk * 32 + hi * 8));
      #pragma unroll
      for (int mi = 0; mi < 2; mi++)
        #pragma unroll
        for (int ni = 0; ni < 4; ni++)
          acc[mi][ni] = __builtin_amdgcn_mfma_f32_16x16x32_bf16(aF[mi], bF[ni], acc[mi][ni], 0, 0, 0);
    }
    #pragma unroll
    for (int ni = 0; ni < 4; ni++) {
      float bv = bias[ob * 64 + ni * 16 + lo];
      #pragma unroll
      for (int mi = 0; mi < 2; mi++) {
        #pragma unroll
        for (int r2 = 0; r2 < 4; r2++) {
          float rv = acc[mi][ni][r2] + bv;
          int p = p0 + wv * 32 + mi * 16 + hi * 4 + r2;
          int hh = p / HW, ww = p % HW;
          int rg = (hh >> 4) * 7 + (ww >> 4), s2 = (hh & 15) * 16 + (ww & 15);
          int o = ni * 16 + lo;
          if (ob == 0)      qRo[(((size_t)(n * RR + rg)) * RS + s2) * 64 + o] = (bf16)(rv * 0.125f);
          else if (ob == 1) kRo[(((size_t)(n * RR + rg)) * RS + s2) * 64 + o] = (bf16)rv;
          else              vto[((size_t)n * PP + p) * 64 + o] = (bf16)rv;
        }
      }
    }
    __syncthreads();
  }
}

// ---------------- per-region: vT transpose + qd/kd means ----------------
__global__ __launch_bounds__(256) void k_vpost(const bf16* __restrict__ qR, const bf16* __restrict__ kR,
    const bf16* __restrict__ v_t, float* __restrict__ qd, float* __restrict__ kd, bf16* __restrict__ vT) {
  __shared__ bf16 sT[64 * 264];
  __shared__ float rq[4][64], rk[4][64];
  int r = blockIdx.x, n = blockIdx.y;
  int nr = n * RR + r;
  int tid = threadIdx.x;
  int rh = (r / 7) * 16, rw = (r % 7) * 16;
  {
    int ph = rh + (tid >> 4), pw = rw + (tid & 15);
    const bf16* src = v_t + ((size_t)n * PP + ph * HW + pw) * 64;
    #pragma unroll
    for (int c8 = 0; c8 < 8; c8++) {
      bf16x8 d = *(const bf16x8*)(src + c8 * 8);
      #pragma unroll
      for (int j = 0; j < 8; j++) sT[(c8 * 8 + j) * 264 + tid] = d[j];
    }
  }
  {
    int c = tid & 63, sq = tid >> 6;
    const bf16* qb = qR + (size_t)nr * RS * 64;
    const bf16* kb = kR + (size_t)nr * RS * 64;
    float aq = 0.f, ak = 0.f;
    for (int s = sq * 64; s < sq * 64 + 64; s++) {
      aq += (float)qb[s * 64 + c];
      ak += (float)kb[s * 64 + c];
    }
    rq[sq][c] = aq; rk[sq][c] = ak;
  }
  __syncthreads();
  #pragma unroll
  for (int it = 0; it < 8; it++) {
    int idx = tid + it * 256;
    int row = idx >> 5, ch = idx & 31;
    uint4 d = *(const uint4*)(sT + row * 264 + ch * 8);
    *(uint4*)(vT + ((size_t)nr * 64 + row) * 256 + ch * 8) = d;
  }
  if (tid < 64) {
    int c = tid;
    qd[(n * 64 + c) * RR + r] = ((rq[0][c] + rq[1][c]) + (rq[2][c] + rq[3][c])) * (1.f / 256.f);
    kd[(n * 64 + c) * RR + r] = ((rk[0][c] + rk[1][c]) + (rk[2][c] + rk[3][c])) * (1.f / 256.f);
  }
}

// ---------------- top-4 routing: one wave per query region ----------------
__global__ __launch_bounds__(64) void k_topk(const float* __restrict__ qd, const float* __restrict__ kd,
    int* __restrict__ gidx) {
  int pq = blockIdx.x, n = blockIdx.y;
  int j = threadIdx.x;
  float a = -3e38f;
  if (j < RR) {
    a = 0.f;
    for (int c = 0; c < 64; c++)
      a += qd[(n * 64 + c) * RR + pq] * kd[(n * 64 + c) * RR + j];
  }
  for (int t = 0; t < 4; t++) {
    float bv = a; int bj = j;
    #pragma unroll
    for (int d = 32; d >= 1; d >>= 1) {
      float ov = __shfl_xor(bv, d, 64);
      int oj = __shfl_xor(bj, d, 64);
      if (ov > bv || (ov == bv && oj < bj)) { bv = ov; bj = oj; }
    }
    if (j == 0) gidx[(n * RR + pq) * 4 + t] = bj;
    if (j == bj) a = -3e38f;
  }
}

// ---------------- gathered-region flash attention: async gload_lds double-buffer, no spill ----------------
// grid = BB*RR*4 (XCD-swizzled); block = 4 waves; wave owns 16 Q rows; KVBLK=64
__global__ __launch_bounds__(256) void k_attn(const bf16* __restrict__ qR, const bf16* __restrict__ kR,
    const bf16* __restrict__ vT, const float* __restrict__ maskr, const int* __restrict__ gidx,
    bf16* __restrict__ attnRb) {
  __shared__ bf16 sKd[2][64 * 64];   // double-buffered K tile, swizzled content
  __shared__ bf16 sVd[2][64 * 64];   // double-buffered V tile, swizzled content
  __shared__ bf16 sP[4][16 * 64];
  __shared__ float sMaskB[2][64];
  int bid = blockIdx.x;
  int newid = (bid & 7) * 98 + (bid >> 3);   // 784 = 8*98: bijective XCD chunking
  int n = newid / (RR * 4); int rem = newid % (RR * 4); int r = rem >> 2, qs = rem & 3;
  int tid = threadIdx.x, lane = tid & 63, wv = tid >> 6;
  int lo = lane & 15, hi = lane >> 4;
  int m0 = qs * 64 + wv * 16;
  const bf16* qbase = qR + ((size_t)(n * RR + r)) * RS * 64;
  bf16x8 qF[2];
  #pragma unroll
  for (int kk = 0; kk < 2; kk++)
    qF[kk] = *(const bf16x8*)(qbase + (m0 + lo) * 64 + kk * 32 + hi * 8);

  // pre-swizzled per-lane GLOBAL byte offsets; LDS dest is linear (base + lane*16)
  int gofsK[2], gofsV[2];
  #pragma unroll
  for (int i = 0; i < 2; i++) {
    int row = wv * 16 + i * 8 + (lane >> 3);
    int s = lane & 7;
    int c4 = (s ^ row) & 7;
    gofsK[i] = row * 128 + c4 * 16;   // K tile rows are 128B
    gofsV[i] = row * 512 + c4 * 16;   // vT rows are 512B (256 bf16); +sub*128 in base
  }

  const int* gptr = gidx + (n * RR + r) * 4;
  int j0g = gptr[0], j1g = gptr[1], j2g = gptr[2], j3g = gptr[3];

  f32x4 zero4 = {0.f, 0.f, 0.f, 0.f};
  f32x4 Oacc[4];
  #pragma unroll
  for (int di = 0; di < 4; di++) Oacc[di] = zero4;
  float mrun[4], lrun[4];
  #pragma unroll
  for (int s = 0; s < 4; s++) { mrun[s] = -3e38f; lrun[s] = 0.f; }

  // ---- issue helper: 5 gload_lds per wave per tile (2 K + 2 V + 1 mask) ----
  #define ISSUE_TILE(JREG, SUB, BUF) do {                                            \
    const char* kb_ = (const char*)(kR + ((size_t)(n * RR + (JREG))) * RS * 64) + (SUB) * 8192; \
    const char* vb_ = (const char*)(vT + ((size_t)(n * RR + (JREG))) * 64 * RS) + (SUB) * 128;  \
    _Pragma("unroll")                                                                \
    for (int i_ = 0; i_ < 2; i_++) {                                                 \
      gl_lds16(kb_ + gofsK[i_], (char*)sKd + (BUF) * 8192 + wv * 2048 + i_ * 1024);  \
      gl_lds16(vb_ + gofsV[i_], (char*)sVd + (BUF) * 8192 + wv * 2048 + i_ * 1024);  \
    }                                                                                \
    gl_lds4(maskr + ((size_t)(n * RR + (JREG))) * RS + (SUB) * 64 + lane, (char*)sMaskB[(BUF)]); \
  } while (0)

  ISSUE_TILE(j0g, 0, 0);   // prologue: tile 0 -> buf 0

  for (int ts = 0; ts < 16; ts++) {
    int cur = ts & 1;
    // barrier A: all waves done reading buf cur^1 (previous iteration)
    asm volatile("s_waitcnt lgkmcnt(0)" ::: "memory");
    __builtin_amdgcn_s_barrier();
    __builtin_amdgcn_sched_barrier(0);
    if (ts < 15) {
      int nts = ts + 1;
      int jn = (nts < 8) ? (nts < 4 ? j0g : j1g) : (nts < 12 ? j2g : j3g);
      int nsub = nts & 3;
      ISSUE_TILE(jn, nsub, cur ^ 1);
      asm volatile("s_waitcnt vmcnt(5)" ::: "memory");   // current tile's 5 loads done
    } else {
      asm volatile("s_waitcnt vmcnt(0)" ::: "memory");
    }
    __builtin_amdgcn_s_barrier();
    __builtin_amdgcn_sched_barrier(0);
    // ---- compute from buf cur ----
    const char* sK = (const char*)sKd + cur * 8192;
    const char* sV = (const char*)sVd + cur * 8192;
    f32x4 Sacc[4];
    #pragma unroll
    for (int ni = 0; ni < 4; ni++) Sacc[ni] = zero4;
    #pragma unroll
    for (int kk = 0; kk < 2; kk++) {
      #pragma unroll
      for (int ni = 0; ni < 4; ni++) {
        bf16x8 bF = *(const bf16x8*)(sK + swz128(ni * 16 + lo, kk * 32 + hi * 8));
        Sacc[ni] = __builtin_amdgcn_mfma_f32_16x16x32_bf16(qF[kk], bF, Sacc[ni], 0, 0, 0);
      }
    }
    float mv[4];
    #pragma unroll
    for (int ni = 0; ni < 4; ni++) mv[ni] = sMaskB[cur][ni * 16 + lo];
    bf16* sPw = sP[wv];
    #pragma unroll
    for (int jj = 0; jj < 4; jj++) {
      float cm = fmaxf(fmaxf(Sacc[0][jj] + mv[0], Sacc[1][jj] + mv[1]),
                       fmaxf(Sacc[2][jj] + mv[2], Sacc[3][jj] + mv[3]));
      #pragma unroll
      for (int d2 = 1; d2 < 16; d2 <<= 1) cm = fmaxf(cm, __shfl_xor(cm, d2, 64));
      float nm = fmaxf(mrun[jj], cm);
      float sc = __expf(mrun[jj] - nm);
      float rsum = 0.f; float pv[4];
      #pragma unroll
      for (int ni = 0; ni < 4; ni++) { pv[ni] = __expf(Sacc[ni][jj] + mv[ni] - nm); rsum += pv[ni]; }
      #pragma unroll
      for (int d2 = 1; d2 < 16; d2 <<= 1) rsum += __shfl_xor(rsum, d2, 64);
      mrun[jj] = nm; lrun[jj] = lrun[jj] * sc + rsum;
      #pragma unroll
      for (int di = 0; di < 4; di++) Oacc[di][jj] *= sc;
      int prow = hi * 4 + jj;
      #pragma unroll
      for (int ni = 0; ni < 4; ni++)
        *(bf16*)((char*)sPw + swz128(prow, ni * 16 + lo)) = (bf16)pv[ni];
    }
    #pragma unroll
    for (int kk = 0; kk < 2; kk++) {
      bf16x8 pF = *(const bf16x8*)((const char*)sPw + swz128(lo, kk * 32 + hi * 8));
      #pragma unroll
      for (int di = 0; di < 4; di++) {
        bf16x8 vF = *(const bf16x8*)(sV + swz128(di * 16 + lo, kk * 32 + hi * 8));
        Oacc[di] = __builtin_amdgcn_mfma_f32_16x16x32_bf16(pF, vF, Oacc[di], 0, 0, 0);
      }
    }
  }
  #undef ISSUE_TILE
  // ---- coalesced epilogue: normalize -> LDS repack -> contiguous uint4 stores ----
  __syncthreads();                 // all waves finished compute
  bf16* sOut = sKd[0];             // 8KB = 64 rows x 64 ch
  #pragma unroll
  for (int jj = 0; jj < 4; jj++) {
    float inv = 1.f / lrun[jj];
    int row = wv * 16 + hi * 4 + jj;
    #pragma unroll
    for (int di = 0; di < 4; di++)
      sOut[row * 64 + di * 16 + lo] = (bf16)(Oacc[di][jj] * inv);
  }
  __syncthreads();
  bf16* dst = attnRb + (((size_t)(n * RR + r)) * RS + qs * 64) * 64;
  #pragma unroll
  for (int it = 0; it < 2; it++) {
    int idx = tid + it * 256;
    *(uint4*)(dst + idx * 8) = *(const uint4*)(sOut + idx * 8);
  }
}

// ---------------- lepe 5x5 dw + from_regions (attnR bf16) ----------------
__global__ __launch_bounds__(256) void k_lepe2(const bf16* __restrict__ v_t, const bf16* __restrict__ attnRb,
    const float* __restrict__ lw, const float* __restrict__ lb, bf16* __restrict__ z_t) {
  __shared__ bf16 sH[400 * 72];
  __shared__ float sW[25][64];
  int r = blockIdx.x, n = blockIdx.y;
  int rh = (r / 7) * 16, rw = (r % 7) * 16;
  int tid = threadIdx.x;
  for (int i = tid; i < 1600; i += 256) { int c = i / 25, k = i % 25; sW[k][c] = lw[c * 25 + k]; }
  for (int g = tid; g < 3200; g += 256) {
    int pix = g >> 3, c4 = g & 7;
    int yy = pix / 20, xx = pix % 20;
    int hh = rh + yy - 2, ww = rw + xx - 2;
    uint4 d = {0, 0, 0, 0};
    if ((unsigned)hh < HW && (unsigned)ww < HW)
      d = *(const uint4*)(v_t + ((size_t)n * PP + hh * HW + ww) * 64 + c4 * 8);
    *(uint4*)((char*)sH + pix * 144 + c4 * 16) = d;
  }
  __syncthreads();
  int y = tid >> 4, x = tid & 15;
  float acc[64];
  const bf16* ar = attnRb + (((size_t)(n * RR + r)) * RS + tid) * 64;
  #pragma unroll
  for (int c8 = 0; c8 < 8; c8++) {
    bf16x8 av = *(const bf16x8*)(ar + c8 * 8);
    #pragma unroll
    for (int j = 0; j < 8; j++) acc[c8 * 8 + j] = lb[c8 * 8 + j] + (float)av[j];
  }
  for (int t25 = 0; t25 < 25; t25++) {
    int dh = t25 / 5, dw = t25 % 5;
    int pix = (y + dh) * 20 + (x + dw);
    #pragma unroll
    for (int c8 = 0; c8 < 8; c8++) {
      bf16x8 hv = *(const bf16x8*)((const char*)sH + pix * 144 + c8 * 16);
      #pragma unroll
      for (int j = 0; j < 8; j++) acc[c8 * 8 + j] += (float)hv[j] * sW[t25][c8 * 8 + j];
    }
  }
  bf16* zp = z_t + ((size_t)n * PP + (rh + y) * HW + rw + x) * 64;
  #pragma unroll
  for (int c8 = 0; c8 < 8; c8++) {
    bf16x8 o8;
    #pragma unroll
    for (int j = 0; j < 8; j++) o8[j] = (bf16)acc[c8 * 8 + j];
    *(bf16x8*)(zp + c8 * 8) = o8;
  }
}

// ---------------- proj GEMM: z_t -> x_t += ----------------
__global__ __launch_bounds__(256) void k_proj(const bf16* __restrict__ A, const float* __restrict__ w,
    const float* __restrict__ bias, float* __restrict__ xo) {
  __shared__ bf16 sA[128 * 64];
  __shared__ bf16 sB[64 * 64];
  int n = blockIdx.y;
  int p0 = blockIdx.x * 128;
  int tid = threadIdx.x, lane = tid & 63, wv = tid >> 6;
  int lo = lane & 15, hi = lane >> 4;
  const bf16* Abase = A + (size_t)n * PP * 64;
  #pragma unroll
  for (int it = 0; it < 4; it++) {
    int idx = tid + it * 256;
    int row = idx >> 3, c4 = idx & 7;
    uint4 d = *(const uint4*)(Abase + (size_t)(p0 + row) * 64 + c4 * 8);
    *(uint4*)((char*)sA + row * 128 + (((c4 ^ row) & 7) * 16)) = d;
  }
  #pragma unroll
  for (int it = 0; it < 4; it++) {
    int idx = tid + it * 256;
    int oo = idx >> 4, q = idx & 15;
    float4 wv4 = *(const float4*)&w[(size_t)oo * 64 + q * 4];
    bf16x4 b4; b4[0] = (bf16)wv4.x; b4[1] = (bf16)wv4.y; b4[2] = (bf16)wv4.z; b4[3] = (bf16)wv4.w;
    *(bf16x4*)((char*)sB + swz128(oo, q * 4)) = b4;
  }
  __syncthreads();
  f32x4 acc[2][4];
  #pragma unroll
  for (int mi = 0; mi < 2; mi++)
    #pragma unroll
    for (int ni = 0; ni < 4; ni++) acc[mi][ni] = (f32x4){0.f, 0.f, 0.f, 0.f};
  #pragma unroll
  for (int kk = 0; kk < 2; kk++) {
    bf16x8 aF[2], bF[4];
    #pragma unroll
    for (int mi = 0; mi < 2; mi++)
      aF[mi] = *(const bf16x8*)((const char*)sA + swz128(wv * 32 + mi * 16 + lo, kk * 32 + hi * 8));
    #pragma unroll
    for (int ni = 0; ni < 4; ni++)
      bF[ni] = *(const bf16x8*)((const char*)sB + swz128(ni * 16 + lo, kk * 32 + hi * 8));
    #pragma unroll
    for (int mi = 0; mi < 2; mi++)
      #pragma unroll
      for (int ni = 0; ni < 4; ni++)
        acc[mi][ni] = __builtin_amdgcn_mfma_f32_16x16x32_bf16(aF[mi], bF[ni], acc[mi][ni], 0, 0, 0);
  }
  #pragma unroll
  for (int ni = 0; ni < 4; ni++) {
    float bv = bias[ni * 16 + lo];
    #pragma unroll
    for (int mi = 0; mi < 2; mi++) {
      #pragma unroll
      for (int r2 = 0; r2 < 4; r2++) {
        int p = p0 + wv * 32 + mi * 16 + hi * 4 + r2;
        xo[((size_t)n * PP + p) * 64 + ni * 16 + lo] += acc[mi][ni][r2] + bv;
      }
    }
  }
}

// ---------------- fused MLP: LN2 + fc1 + gelu + fc2 + residual ----------------
__global__ __launch_bounds__(256) void k_mlp(const float* __restrict__ xin, const float* __restrict__ lng,
    const float* __restrict__ lnb, const float* __restrict__ w1, const float* __restrict__ b1,
    const float* __restrict__ w2, const float* __restrict__ b2, float* __restrict__ xo) {
  __shared__ bf16 sA[64 * 64];
  __shared__ bf16 sW1[128 * 64];
  __shared__ bf16 sHh[64 * 128];
  __shared__ bf16 sW2[64 * 128];
  int n = blockIdx.y;
  int p0 = blockIdx.x * 64;
  int tid = threadIdx.x, lane = tid & 63, wv = tid >> 6;
  int lo = lane & 15, hi = lane >> 4;
  { // fused LN staging: 4 threads per row, 16 channels each
    int row = tid >> 2, part = tid & 3;
    const float* xp = xin + ((size_t)n * PP + p0 + row) * 64 + part * 16;
    float v[16]; float s = 0.f, sq = 0.f;
    #pragma unroll
    for (int i = 0; i < 4; i++) {
      float4 d = *(const float4*)&xp[i * 4];
      v[i*4]=d.x; v[i*4+1]=d.y; v[i*4+2]=d.z; v[i*4+3]=d.w;
      s += d.x+d.y+d.z+d.w;
      sq += d.x*d.x+d.y*d.y+d.z*d.z+d.w*d.w;
    }
    s += __shfl_xor(s, 1, 64); sq += __shfl_xor(sq, 1, 64);
    s += __shfl_xor(s, 2, 64); sq += __shfl_xor(sq, 2, 64);
    float mu = s * (1.f/64.f);
    float rstd = rsqrtf(fmaxf(sq * (1.f/64.f) - mu*mu, 0.f) + 1e-5f);
    #pragma unroll
    for (int j2 = 0; j2 < 2; j2++) {
      bf16x8 o8;
      #pragma unroll
      for (int e = 0; e < 8; e++) {
        int c = part*16 + j2*8 + e;
        o8[e] = (bf16)((v[j2*8+e] - mu) * rstd * lng[c] + lnb[c]);
      }
      *(bf16x8*)((char*)sA + swz128(row, part*16 + j2*8)) = o8;
    }
  }
  f32x4 oacc[4];
  #pragma unroll
  for (int ni = 0; ni < 4; ni++) oacc[ni] = (f32x4){0.f, 0.f, 0.f, 0.f};
  for (int half = 0; half < 2; half++) {
    #pragma unroll
    for (int it = 0; it < 8; it++) {
      int idx = tid + it * 256;
      int oo = idx >> 4, q = idx & 15;
      float4 wv4 = *(const float4*)&w1[(size_t)(half * 128 + oo) * 64 + q * 4];
      bf16x4 b4; b4[0] = (bf16)wv4.x; b4[1] = (bf16)wv4.y; b4[2] = (bf16)wv4.z; b4[3] = (bf16)wv4.w;
      *(bf16x4*)((char*)sW1 + swz128(oo, q * 4)) = b4;
    }
    __syncthreads();
    f32x4 hacc[8];
    #pragma unroll
    for (int ni = 0; ni < 8; ni++) hacc[ni] = (f32x4){0.f, 0.f, 0.f, 0.f};
    #pragma unroll
    for (int kk = 0; kk < 2; kk++) {
      bf16x8 aF = *(const bf16x8*)((const char*)sA + swz128(wv * 16 + lo, kk * 32 + hi * 8));
      #pragma unroll
      for (int ni = 0; ni < 8; ni++) {
        bf16x8 bF = *(const bf16x8*)((const char*)sW1 + swz128(ni * 16 + lo, kk * 32 + hi * 8));
        hacc[ni] = __builtin_amdgcn_mfma_f32_16x16x32_bf16(aF, bF, hacc[ni], 0, 0, 0);
      }
    }
    #pragma unroll
    for (int ni = 0; ni < 8; ni++) {
      float bv = b1[half * 128 + ni * 16 + lo];
      #pragma unroll
      for (int r2 = 0; r2 < 4; r2++) {
        float hval = gelu_exact(hacc[ni][r2] + bv);
        *(bf16*)((char*)sHh + swzg(wv * 16 + hi * 4 + r2, ni * 16 + lo, 256)) = (bf16)hval;
      }
    }
    #pragma unroll
    for (int it = 0; it < 8; it++) {
      int idx = tid + it * 256;
      int oo = idx >> 5, q = idx & 31;
      float4 wv4 = *(const float4*)&w2[(size_t)oo * 256 + half * 128 + q * 4];
      bf16x4 b4; b4[0] = (bf16)wv4.x; b4[1] = (bf16)wv4.y; b4[2] = (bf16)wv4.z; b4[3] = (bf16)wv4.w;
      *(bf16x4*)((char*)sW2 + swzg(oo, q * 4, 256)) = b4;
    }
    __syncthreads();
    #pragma unroll
    for (int kk = 0; kk < 4; kk++) {
      bf16x8 aH = *(const bf16x8*)((const char*)sHh + swzg(wv * 16 + lo, kk * 32 + hi * 8, 256));
      #pragma unroll
      for (int ni = 0; ni < 4; ni++) {
        bf16x8 bF = *(const bf16x8*)((const char*)sW2 + swzg(ni * 16 + lo, kk * 32 + hi * 8, 256));
        oacc[ni] = __builtin_amdgcn_mfma_f32_16x16x32_bf16(aH, bF, oacc[ni], 0, 0, 0);
      }
    }
    __syncthreads();
  }
  #pragma unroll
  for (int ni = 0; ni < 4; ni++) {
    float bv = b2[ni * 16 + lo];
    #pragma unroll
    for (int r2 = 0; r2 < 4; r2++) {
      int p = p0 + wv * 16 + hi * 4 + r2;
      xo[((size_t)n * PP + p) * 64 + ni * 16 + lo] += oacc[ni][r2] + bv;
    }
  }
}

// ---------------- final untranspose: x_t[p][c] -> out[c][p] ----------------
__global__ __launch_bounds__(256) void k_untr(const float* __restrict__ x_t, float* __restrict__ out) {
  __shared__ float tile[64][68];
  int n = blockIdx.y; int p0 = blockIdx.x * 64;
  int tid = threadIdx.x;
  #pragma unroll
  for (int it = 0; it < 4; it++) {
    int g = tid + it * 256;
    int row = g >> 4, q = g & 15;
    float4 d = *(const float4*)&x_t[((size_t)n * PP + p0 + row) * 64 + q * 4];
    *(float4*)&tile[row][q * 4] = d;
  }
  __syncthreads();
  #pragma unroll
  for (int it = 0; it < 4; it++) {
    int g = tid + it * 256;
    int c = g >> 4, q = g & 15;
    float4 v;
    v.x = tile[q * 4 + 0][c]; v.y = tile[q * 4 + 1][c];
    v.z = tile[q * 4 + 2][c]; v.w = tile[q * 4 + 3][c];
    *(float4*)&out[((size_t)(n * 64 + c)) * PP + p0 + q * 4] = v;
  }
}

extern "C" void kernel_launch(void* const* d_in, const int* in_sizes, int n_in,
                              void* d_out, int out_size, void* d_ws, size_t ws_size,
                              hipStream_t stream) {
  const float* ex0 = (const float*)d_in[0];
  const float* ex  = (const float*)d_in[1];
  const float* img = (const float*)d_in[2];
  const float* pre = (const float*)d_in[3];
  const float* c0w = (const float*)d_in[4];
  const float* c0b = (const float*)d_in[5];
  const float* ln1g = (const float*)d_in[6];
  const float* ln1b = (const float*)d_in[7];
  const float* ln2g = (const float*)d_in[8];
  const float* ln2b = (const float*)d_in[9];
  const float* qkvw = (const float*)d_in[10];
  const float* qkvb = (const float*)d_in[11];
  const float* lw = (const float*)d_in[12];
  const float* lb = (const float*)d_in[13];
  const float* pw = (const float*)d_in[14];
  const float* pb = (const float*)d_in[15];
  const float* f1w = (const float*)d_in[16];
  const float* f1b = (const float*)d_in[17];
  const float* f2w = (const float*)d_in[18];
  const float* f2b = (const float*)d_in[19];

  float* W = (float*)d_ws;
  size_t o = 0;
  bf16* xct = (bf16*)(W + o);  o += (size_t)BB * GP * CK / 2;
  float* x_t  = W + o;         o += 3211264;
  bf16* attnRb = (bf16*)(W + o); o += 1605632;
  bf16* v_t  = (bf16*)(W + o); o += 1605632;
  bf16* z_t  = (bf16*)(W + o); o += 1605632;
  bf16* qR   = (bf16*)(W + o); o += 1605632;
  bf16* kR   = (bf16*)(W + o); o += 1605632;
  bf16* vT   = (bf16*)(W + o); o += 1605632;
  float* qd = W + o;           o += 12544;
  float* kd = W + o;           o += 12544;
  float* maskr = W + o;        o += 50176;
  bf16* wTb = (bf16*)(W + o);  o += 46080;
  int* gidx = (int*)(W + o);   o += 784;

  hipMemsetAsync(xct, 0, (size_t)BB * GP * CK * 2, stream);
  k_prep2<<<dim3(196, BB), dim3(256), 0, stream>>>(ex0, ex, img, pre, xct, maskr);
  k_wt2<<<dim3(360), dim3(256), 0, stream>>>(c0w, wTb);
  k_conv0m<<<dim3(98, BB), dim3(256), 0, stream>>>(xct, wTb, c0b, x_t);
  for (int i = 0; i < 4; i++) {
    k_qkv<<<dim3(98, BB), dim3(256), 0, stream>>>(x_t, ln1g + i * 64, ln1b + i * 64,
        qkvw + (size_t)i * 192 * 64, qkvb + i * 192, qR, kR, v_t);
    k_vpost<<<dim3(RR, BB), dim3(256), 0, stream>>>(qR, kR, v_t, qd, kd, vT);
    k_topk<<<dim3(RR, BB), dim3(64), 0, stream>>>(qd, kd, gidx);
    k_attn<<<dim3(BB * RR * 4), dim3(256), 0, stream>>>(qR, kR, vT, maskr, gidx, attnRb);
    k_lepe2<<<dim3(RR, BB), dim3(256), 0, stream>>>(v_t, attnRb, lw + (size_t)i * 64 * 25, lb + i * 64, z_t);
    k_proj<<<dim3(98, BB), dim3(256), 0, stream>>>(z_t, pw + (size_t)i * 64 * 64, pb + i * 64, x_t);
    k_mlp<<<dim3(196, BB), dim3(256), 0, stream>>>(x_t, ln2g + i * 64, ln2b + i * 64,
        f1w + (size_t)i * 256 * 64, f1b + i * 256, f2w + (size_t)i * 64 * 256, f2b + i * 64, x_t);
  }
  k_untr<<<dim3(196, BB), dim3(256), 0, stream>>>(x_t, (float*)d_out);
}

// Round 9
// 656.048 us; speedup vs baseline: 1.2706x; 1.1073x over previous
//
#include <hip/hip_runtime.h>

#define HW 112
#define PP 12544
#define BB 4
#define RR 49
#define RS 256
#define GW 114          // padded grid width (zero ring)
#define GP (GW*GW)      // 12996
#define CK 160          // padded channels for conv0

typedef __bf16 bf16;
typedef __bf16 bf16x8 __attribute__((ext_vector_type(8)));
typedef __bf16 bf16x4 __attribute__((ext_vector_type(4)));
typedef float f32x4 __attribute__((ext_vector_type(4)));

// XOR-swizzled byte offset in a row-major bf16 tile; rowbytes ∈ {128,256,512}
__device__ __forceinline__ int swzg(int row, int halfcol, int rowbytes) {
  int byte = halfcol * 2;
  return row * rowbytes + (byte & ~127) + ((((byte >> 4) ^ row) & 7) * 16) + (byte & 15);
}
__device__ __forceinline__ int swz128(int row, int halfcol) { return swzg(row, halfcol, 128); }

__device__ __forceinline__ float gelu_exact(float x) {
  return 0.5f * x * (1.f + erff(x * 0.70710678118654752f));
}

// async global->LDS (no VGPR round-trip). LDS dest = wave-uniform base + lane*size.
__device__ __forceinline__ void gl_lds16(const void* g, void* l) {
  __builtin_amdgcn_global_load_lds((const __attribute__((address_space(1))) unsigned int*)g,
                                   (__attribute__((address_space(3))) unsigned int*)l, 16, 0, 0);
}
__device__ __forceinline__ void gl_lds4(const void* g, void* l) {
  __builtin_amdgcn_global_load_lds((const __attribute__((address_space(1))) unsigned int*)g,
                                   (__attribute__((address_space(3))) unsigned int*)l, 4, 0, 0);
}

// ---------------- prep: downsample+concat -> xcat_t bf16 [n][grid 114x114][160], mask ----------------
__global__ __launch_bounds__(256) void k_prep2(const float* __restrict__ ex0, const float* __restrict__ ex,
    const float* __restrict__ img, const float* __restrict__ pre,
    bf16* __restrict__ xct, float* __restrict__ maskr) {
  __shared__ bf16 sT2[64 * 168];   // [pixel][168 ch] rows 336B (16B aligned)
  int n = blockIdx.y;
  int p0 = blockIdx.x * 64;
  int tid = threadIdx.x;
  uint4 zz = {0, 0, 0, 0};
  for (int i2 = tid; i2 < 1344; i2 += 256) ((uint4*)sT2)[i2] = zz;
  __syncthreads();
  int l = tid & 63, g = tid >> 6;
  int p = p0 + l;
  int h = p / HW, w = p % HW;
  for (int c = g; c < 131; c += 4) {
    float val;
    if (c < 64) {
      const float* s = ex0 + (((size_t)(n * 64 + c)) * 224 + 2 * h) * 224 + 2 * w;
      val = 0.5f * (0.5f * (s[0] + s[224]) + 0.5f * (s[1] + s[225]));
    } else if (c < 128) {
      val = ex[((size_t)(n * 64 + (c - 64))) * PP + p];
    } else {
      const float* s = img + (((size_t)(n * 3 + (c - 128))) * 224 + 2 * h) * 224 + 2 * w;
      val = 0.5f * (0.5f * (s[0] + s[224]) + 0.5f * (s[1] + s[225]));
    }
    sT2[l * 168 + c] = (bf16)val;
  }
  if (tid < 64) {
    const float* s = pre + ((size_t)n * 224 + 2 * h) * 224 + 2 * w;
    float v = 0.5f * (0.5f * (s[0] + s[224]) + 0.5f * (s[1] + s[225]));
    int r = (h >> 4) * 7 + (w >> 4); int sIdx = (h & 15) * 16 + (w & 15);
    maskr[(n * RR + r) * RS + sIdx] = (v > 0.0f) ? 0.0f : -100.0f;
  }
  __syncthreads();
  for (int i2 = tid; i2 < 1280; i2 += 256) {
    int row = i2 / 20, ch = i2 % 20;
    int pr = p0 + row;
    int hh = pr / HW, ww = pr % HW;
    uint4 d = *(const uint4*)(sT2 + row * 168 + ch * 8);
    *(uint4*)(xct + ((size_t)n * GP + (hh + 1) * GW + ww + 1) * CK + ch * 8) = d;
  }
}

// ---------------- conv0 weights -> wTb bf16 [9tap][5ks][64o][32c] ----------------
__global__ __launch_bounds__(256) void k_wt2(const float* __restrict__ w, bf16* __restrict__ wTb) {
  int t = blockIdx.x * 256 + threadIdx.x;
  if (t >= 9 * 5 * 64 * 32) return;
  int cc = t & 31; int o = (t >> 5) & 63; int ks = (t >> 11) % 5; int k = t / 10240;
  int c = ks * 32 + cc;
  wTb[t] = (bf16)((c < 131) ? w[((size_t)(o * 131) + c) * 9 + k] : 0.f);
}

// ---------------- conv0 as MFMA implicit GEMM: 9 shifted taps x 5 K-slices ----------------
__global__ __launch_bounds__(256) void k_conv0m(const bf16* __restrict__ xct, const bf16* __restrict__ wTb,
    const float* __restrict__ bias, float* __restrict__ out_t) {
  __shared__ bf16 sA[128 * 32];
  __shared__ bf16 sB[64 * 32];
  int n = blockIdx.y;
  int p0 = blockIdx.x * 128;
  int tid = threadIdx.x, lane = tid & 63, wv = tid >> 6;
  int lo = lane & 15, hi = lane >> 4;
  size_t gofsA[2];
  #pragma unroll
  for (int it = 0; it < 2; it++) {
    int idx = tid + it * 256;
    int row = idx >> 2, ch = idx & 3;
    int p = p0 + row;
    int hh = p / HW, ww = p % HW;
    gofsA[it] = ((size_t)(hh + 1) * GW + ww + 1) * (CK * 2) + ch * 16;
  }
  const char* xbase = (const char*)(xct + (size_t)n * GP * CK);
  f32x4 acc[2][4];
  #pragma unroll
  for (int mi = 0; mi < 2; mi++)
    #pragma unroll
    for (int ni = 0; ni < 4; ni++) acc[mi][ni] = (f32x4){0.f, 0.f, 0.f, 0.f};
  for (int tap = 0; tap < 9; tap++) {
    long shift = (long)((tap / 3 - 1) * GW + (tap % 3 - 1)) * (CK * 2);
    for (int ks = 0; ks < 5; ks++) {
      uint4 a0 = *(const uint4*)(xbase + gofsA[0] + shift + ks * 64);
      uint4 a1 = *(const uint4*)(xbase + gofsA[1] + shift + ks * 64);
      uint4 b0 = *(const uint4*)((const char*)wTb + ((size_t)(tap * 5 + ks) * 2048 + tid * 8) * 2);
      __syncthreads();
      *(uint4*)((char*)sA + tid * 16) = a0;
      *(uint4*)((char*)sA + (tid + 256) * 16) = a1;
      *(uint4*)((char*)sB + tid * 16) = b0;
      __syncthreads();
      bf16x8 aF[2], bF[4];
      #pragma unroll
      for (int mi = 0; mi < 2; mi++)
        aF[mi] = *(const bf16x8*)((const char*)sA + (wv * 32 + mi * 16 + lo) * 64 + hi * 16);
      #pragma unroll
      for (int ni = 0; ni < 4; ni++)
        bF[ni] = *(const bf16x8*)((const char*)sB + (ni * 16 + lo) * 64 + hi * 16);
      #pragma unroll
      for (int mi = 0; mi < 2; mi++)
        #pragma unroll
        for (int ni = 0; ni < 4; ni++)
          acc[mi][ni] = __builtin_amdgcn_mfma_f32_16x16x32_bf16(aF[mi], bF[ni], acc[mi][ni], 0, 0, 0);
    }
  }
  #pragma unroll
  for (int ni = 0; ni < 4; ni++) {
    float bv = bias[ni * 16 + lo];
    #pragma unroll
    for (int mi = 0; mi < 2; mi++) {
      #pragma unroll
      for (int r2 = 0; r2 < 4; r2++) {
        int p = p0 + wv * 32 + mi * 16 + hi * 4 + r2;
        out_t[((size_t)n * PP + p) * 64 + ni * 16 + lo] = acc[mi][ni][r2] + bv;
      }
    }
  }
}

// ---------------- qkv with fused LN1 ----------------
__global__ __launch_bounds__(256) void k_qkv(const float* __restrict__ xin, const float* __restrict__ lng,
    const float* __restrict__ lnb, const float* __restrict__ w, const float* __restrict__ bias,
    bf16* __restrict__ qRo, bf16* __restrict__ kRo, bf16* __restrict__ vto) {
  __shared__ bf16 sA[128 * 64];
  __shared__ bf16 sB[64 * 64];
  int n = blockIdx.y;
  int p0 = blockIdx.x * 128;
  int tid = threadIdx.x, lane = tid & 63, wv = tid >> 6;
  int lo = lane & 15, hi = lane >> 4;
  { // fused LN staging: 2 threads per row, 32 channels each
    int row = tid >> 1, part = tid & 1;
    const float* xp = xin + ((size_t)n * PP + p0 + row) * 64 + part * 32;
    float v[32]; float s = 0.f, sq = 0.f;
    #pragma unroll
    for (int i = 0; i < 8; i++) {
      float4 d = *(const float4*)&xp[i * 4];
      v[i*4]=d.x; v[i*4+1]=d.y; v[i*4+2]=d.z; v[i*4+3]=d.w;
      s += d.x+d.y+d.z+d.w;
      sq += d.x*d.x+d.y*d.y+d.z*d.z+d.w*d.w;
    }
    s += __shfl_xor(s, 1, 64); sq += __shfl_xor(sq, 1, 64);
    float mu = s * (1.f/64.f);
    float rstd = rsqrtf(fmaxf(sq * (1.f/64.f) - mu*mu, 0.f) + 1e-5f);
    #pragma unroll
    for (int j2 = 0; j2 < 4; j2++) {
      bf16x8 o8;
      #pragma unroll
      for (int e = 0; e < 8; e++) {
        int c = part*32 + j2*8 + e;
        o8[e] = (bf16)((v[j2*8+e] - mu) * rstd * lng[c] + lnb[c]);
      }
      *(bf16x8*)((char*)sA + swz128(row, part*32 + j2*8)) = o8;
    }
  }
  for (int ob = 0; ob < 3; ob++) {
    #pragma unroll
    for (int it = 0; it < 4; it++) {
      int idx = tid + it * 256;
      int oo = idx >> 4, q = idx & 15;
      float4 wv4 = *(const float4*)&w[(size_t)(ob * 64 + oo) * 64 + q * 4];
      bf16x4 b4; b4[0] = (bf16)wv4.x; b4[1] = (bf16)wv4.y; b4[2] = (bf16)wv4.z; b4[3] = (bf16)wv4.w;
      *(bf16x4*)((char*)sB + swz128(oo, q * 4)) = b4;
    }
    __syncthreads();
    f32x4 acc[2][4];
    #pragma unroll
    for (int mi = 0; mi < 2; mi++)
      #pragma unroll
      for (int ni = 0; ni < 4; ni++) acc[mi][ni] = (f32x4){0.f, 0.f, 0.f, 0.f};
    #pragma unroll
    for (int kk = 0; kk < 2; kk++) {
      bf16x8 aF[2], bF[4];
      #pragma unroll
      for (int mi = 0; mi < 2; mi++)
        aF[mi] = *(const bf16x8*)((const char*)sA + swz128(wv * 32 + mi * 16 + lo, kk * 32 + hi * 8));
      #pragma unroll
      for (int ni = 0; ni < 4; ni++)
        bF[ni] = *(const bf16x8*)((const char*)sB + swz128(ni * 16 + lo, kk * 32 + hi * 8));
      #pragma unroll
      for (int mi = 0; mi < 2; mi++)
        #pragma unroll
        for (int ni = 0; ni < 4; ni++)
          acc[mi][ni] = __builtin_amdgcn_mfma_f32_16x16x32_bf16(aF[mi], bF[ni], acc[mi][ni], 0, 0, 0);
    }
    #pragma unroll
    for (int ni = 0; ni < 4; ni++) {
      float bv = bias[ob * 64 + ni * 16 + lo];
      #pragma unroll
      for (int mi = 0; mi < 2; mi++) {
        #pragma unroll
        for (int r2 = 0; r2 < 4; r2++) {
          float rv = acc[mi][ni][r2] + bv;
          int p = p0 + wv * 32 + mi * 16 + hi * 4 + r2;
          int hh = p / HW, ww = p % HW;
          int rg = (hh >> 4) * 7 + (ww >> 4), s2 = (hh & 15) * 16 + (ww & 15);
          int o = ni * 16 + lo;
          if (ob == 0)      qRo[(((size_t)(n * RR + rg)) * RS + s2) * 64 + o] = (bf16)(rv * 0.125f);
          else if (ob == 1) kRo[(((size_t)(n * RR + rg)) * RS + s2) * 64 + o] = (bf16)rv;
          else              vto[((size_t)n * PP + p) * 64 + o] = (bf16)rv;
        }
      }
    }
    __syncthreads();
  }
}

// ---------------- per-region: vT transpose + qd/kd means ----------------
__global__ __launch_bounds__(256) void k_vpost(const bf16* __restrict__ qR, const bf16* __restrict__ kR,
    const bf16* __restrict__ v_t, float* __restrict__ qd, float* __restrict__ kd, bf16* __restrict__ vT) {
  __shared__ bf16 sT[64 * 264];
  __shared__ float rq[4][64], rk[4][64];
  int r = blockIdx.x, n = blockIdx.y;
  int nr = n * RR + r;
  int tid = threadIdx.x;
  int rh = (r / 7) * 16, rw = (r % 7) * 16;
  {
    int ph = rh + (tid >> 4), pw = rw + (tid & 15);
    const bf16* src = v_t + ((size_t)n * PP + ph * HW + pw) * 64;
    #pragma unroll
    for (int c8 = 0; c8 < 8; c8++) {
      bf16x8 d = *(const bf16x8*)(src + c8 * 8);
      #pragma unroll
      for (int j = 0; j < 8; j++) sT[(c8 * 8 + j) * 264 + tid] = d[j];
    }
  }
  {
    int c = tid & 63, sq = tid >> 6;
    const bf16* qb = qR + (size_t)nr * RS * 64;
    const bf16* kb = kR + (size_t)nr * RS * 64;
    float aq = 0.f, ak = 0.f;
    for (int s = sq * 64; s < sq * 64 + 64; s++) {
      aq += (float)qb[s * 64 + c];
      ak += (float)kb[s * 64 + c];
    }
    rq[sq][c] = aq; rk[sq][c] = ak;
  }
  __syncthreads();
  #pragma unroll
  for (int it = 0; it < 8; it++) {
    int idx = tid + it * 256;
    int row = idx >> 5, ch = idx & 31;
    uint4 d = *(const uint4*)(sT + row * 264 + ch * 8);
    *(uint4*)(vT + ((size_t)nr * 64 + row) * 256 + ch * 8) = d;
  }
  if (tid < 64) {
    int c = tid;
    qd[(n * 64 + c) * RR + r] = ((rq[0][c] + rq[1][c]) + (rq[2][c] + rq[3][c])) * (1.f / 256.f);
    kd[(n * 64 + c) * RR + r] = ((rk[0][c] + rk[1][c]) + (rk[2][c] + rk[3][c])) * (1.f / 256.f);
  }
}

// ---------------- top-4 routing: one wave per query region ----------------
__global__ __launch_bounds__(64) void k_topk(const float* __restrict__ qd, const float* __restrict__ kd,
    int* __restrict__ gidx) {
  int pq = blockIdx.x, n = blockIdx.y;
  int j = threadIdx.x;
  float a = -3e38f;
  if (j < RR) {
    a = 0.f;
    for (int c = 0; c < 64; c++)
      a += qd[(n * 64 + c) * RR + pq] * kd[(n * 64 + c) * RR + j];
  }
  for (int t = 0; t < 4; t++) {
    float bv = a; int bj = j;
    #pragma unroll
    for (int d = 32; d >= 1; d >>= 1) {
      float ov = __shfl_xor(bv, d, 64);
      int oj = __shfl_xor(bj, d, 64);
      if (ov > bv || (ov == bv && oj < bj)) { bv = ov; bj = oj; }
    }
    if (j == 0) gidx[(n * RR + pq) * 4 + t] = bj;
    if (j == bj) a = -3e38f;
  }
}

// ---------------- gathered-region flash attention: swapped QK^T, per-lane softmax ----------------
// grid = BB*RR*4 (XCD-swizzled); block = 4 waves; wave owns 16 Q rows; KVBLK=64
__global__ __launch_bounds__(256) void k_attn(const bf16* __restrict__ qR, const bf16* __restrict__ kR,
    const bf16* __restrict__ vT, const float* __restrict__ maskr, const int* __restrict__ gidx,
    bf16* __restrict__ attnRb) {
  __shared__ bf16 sKd[2][64 * 64];   // double-buffered K tile, swizzled content
  __shared__ bf16 sVd[2][64 * 64];   // double-buffered V tile, swizzled content
  __shared__ bf16 sP[4][16 * 64];
  __shared__ float sMaskB[2][64];
  int bid = blockIdx.x;
  int newid = (bid & 7) * 98 + (bid >> 3);   // 784 = 8*98: bijective XCD chunking
  int n = newid / (RR * 4); int rem = newid % (RR * 4); int r = rem >> 2, qs = rem & 3;
  int tid = threadIdx.x, lane = tid & 63, wv = tid >> 6;
  int lo = lane & 15, hi = lane >> 4;
  int m0 = qs * 64 + wv * 16;
  const bf16* qbase = qR + ((size_t)(n * RR + r)) * RS * 64;
  bf16x8 qF[2];
  #pragma unroll
  for (int kk = 0; kk < 2; kk++)
    qF[kk] = *(const bf16x8*)(qbase + (m0 + lo) * 64 + kk * 32 + hi * 8);

  // pre-swizzled per-lane GLOBAL byte offsets; LDS dest is linear (base + lane*16)
  int gofsK[2], gofsV[2];
  #pragma unroll
  for (int i = 0; i < 2; i++) {
    int row = wv * 16 + i * 8 + (lane >> 3);
    int s = lane & 7;
    int c4 = (s ^ row) & 7;
    gofsK[i] = row * 128 + c4 * 16;   // K tile rows are 128B
    gofsV[i] = row * 512 + c4 * 16;   // vT rows are 512B (256 bf16); +sub*128 in base
  }

  const int* gptr = gidx + (n * RR + r) * 4;
  int j0g = gptr[0], j1g = gptr[1], j2g = gptr[2], j3g = gptr[3];

  f32x4 zero4 = {0.f, 0.f, 0.f, 0.f};
  f32x4 Oacc[4];
  #pragma unroll
  for (int di = 0; di < 4; di++) Oacc[di] = zero4;
  float mrun = -3e38f, lrun = 0.f;   // per-lane: owns q = m0 + lo

  #define ISSUE_TILE(JREG, SUB, BUF) do {                                            \
    const char* kb_ = (const char*)(kR + ((size_t)(n * RR + (JREG))) * RS * 64) + (SUB) * 8192; \
    const char* vb_ = (const char*)(vT + ((size_t)(n * RR + (JREG))) * 64 * RS) + (SUB) * 128;  \
    _Pragma("unroll")                                                                \
    for (int i_ = 0; i_ < 2; i_++) {                                                 \
      gl_lds16(kb_ + gofsK[i_], (char*)sKd + (BUF) * 8192 + wv * 2048 + i_ * 1024);  \
      gl_lds16(vb_ + gofsV[i_], (char*)sVd + (BUF) * 8192 + wv * 2048 + i_ * 1024);  \
    }                                                                                \
    gl_lds4(maskr + ((size_t)(n * RR + (JREG))) * RS + (SUB) * 64 + lane, (char*)sMaskB[(BUF)]); \
  } while (0)

  ISSUE_TILE(j0g, 0, 0);   // prologue: tile 0 -> buf 0

  for (int ts = 0; ts < 16; ts++) {
    int cur = ts & 1;
    asm volatile("s_waitcnt lgkmcnt(0)" ::: "memory");
    __builtin_amdgcn_s_barrier();
    __builtin_amdgcn_sched_barrier(0);
    if (ts < 15) {
      int nts = ts + 1;
      int jn = (nts < 8) ? (nts < 4 ? j0g : j1g) : (nts < 12 ? j2g : j3g);
      int nsub = nts & 3;
      ISSUE_TILE(jn, nsub, cur ^ 1);
      asm volatile("s_waitcnt vmcnt(5)" ::: "memory");   // current tile's 5 loads done
    } else {
      asm volatile("s_waitcnt vmcnt(0)" ::: "memory");
    }
    __builtin_amdgcn_s_barrier();
    __builtin_amdgcn_sched_barrier(0);
    const char* sK = (const char*)sKd + cur * 8192;
    const char* sV = (const char*)sVd + cur * 8192;
    // ---- swapped QK^T: D[k][q]; lane (lo,hi) holds S[q=lo][k=ni*16+hi*4+jj] ----
    f32x4 Sacc[4];
    #pragma unroll
    for (int ni = 0; ni < 4; ni++) Sacc[ni] = zero4;
    #pragma unroll
    for (int kk = 0; kk < 2; kk++) {
      #pragma unroll
      for (int ni = 0; ni < 4; ni++) {
        bf16x8 kF = *(const bf16x8*)(sK + swz128(ni * 16 + lo, kk * 32 + hi * 8));
        Sacc[ni] = __builtin_amdgcn_mfma_f32_16x16x32_bf16(kF, qF[kk], Sacc[ni], 0, 0, 0);
      }
    }
    // ---- per-lane softmax (q = lo) ----
    const float* mB = sMaskB[cur];
    float ml = -3e38f;
    #pragma unroll
    for (int ni = 0; ni < 4; ni++) {
      #pragma unroll
      for (int jj = 0; jj < 4; jj++) {
        float sv = Sacc[ni][jj] + mB[ni * 16 + hi * 4 + jj];
        Sacc[ni][jj] = sv;
        ml = fmaxf(ml, sv);
      }
    }
    ml = fmaxf(ml, __shfl_xor(ml, 16, 64));
    ml = fmaxf(ml, __shfl_xor(ml, 32, 64));
    float nm = fmaxf(mrun, ml);
    float sc = __expf(mrun - nm);
    float rs = 0.f;
    bf16* sPw = sP[wv];
    #pragma unroll
    for (int ni = 0; ni < 4; ni++) {
      #pragma unroll
      for (int jj = 0; jj < 4; jj++) {
        float pv = __expf(Sacc[ni][jj] - nm);
        rs += pv;
        *(bf16*)((char*)sPw + swz128(lo, ni * 16 + hi * 4 + jj)) = (bf16)pv;
      }
    }
    rs += __shfl_xor(rs, 16, 64);
    rs += __shfl_xor(rs, 32, 64);
    mrun = nm; lrun = lrun * sc + rs;
    // ---- rescale Oacc: component jj is q-row hi*4+jj; fetch its sc from lane lo=q ----
    float scq[4];
    #pragma unroll
    for (int jj = 0; jj < 4; jj++) scq[jj] = __shfl(sc, hi * 4 + jj, 16);
    #pragma unroll
    for (int di = 0; di < 4; di++)
      #pragma unroll
      for (int jj = 0; jj < 4; jj++) Oacc[di][jj] *= scq[jj];
    // ---- PV ----
    #pragma unroll
    for (int kk = 0; kk < 2; kk++) {
      bf16x8 pF = *(const bf16x8*)((const char*)sPw + swz128(lo, kk * 32 + hi * 8));
      #pragma unroll
      for (int di = 0; di < 4; di++) {
        bf16x8 vF = *(const bf16x8*)(sV + swz128(di * 16 + lo, kk * 32 + hi * 8));
        Oacc[di] = __builtin_amdgcn_mfma_f32_16x16x32_bf16(pF, vF, Oacc[di], 0, 0, 0);
      }
    }
  }
  #undef ISSUE_TILE
  // ---- coalesced epilogue: normalize -> LDS repack -> contiguous uint4 stores ----
  __syncthreads();                 // all waves finished compute
  float inv = 1.f / lrun;          // for q = lo
  float invq[4];
  #pragma unroll
  for (int jj = 0; jj < 4; jj++) invq[jj] = __shfl(inv, hi * 4 + jj, 16);
  bf16* sOut = sKd[0];             // 8KB = 64 rows x 64 ch
  #pragma unroll
  for (int jj = 0; jj < 4; jj++) {
    int row = wv * 16 + hi * 4 + jj;
    #pragma unroll
    for (int di = 0; di < 4; di++)
      sOut[row * 64 + di * 16 + lo] = (bf16)(Oacc[di][jj] * invq[jj]);
  }
  __syncthreads();
  bf16* dst = attnRb + (((size_t)(n * RR + r)) * RS + qs * 64) * 64;
  #pragma unroll
  for (int it = 0; it < 2; it++) {
    int idx = tid + it * 256;
    *(uint4*)(dst + idx * 8) = *(const uint4*)(sOut + idx * 8);
  }
}

// ---------------- lepe 5x5 dw + from_regions (attnR bf16) ----------------
__global__ __launch_bounds__(256) void k_lepe2(const bf16* __restrict__ v_t, const bf16* __restrict__ attnRb,
    const float* __restrict__ lw, const float* __restrict__ lb, bf16* __restrict__ z_t) {
  __shared__ bf16 sH[400 * 72];
  __shared__ float sW[25][64];
  int r = blockIdx.x, n = blockIdx.y;
  int rh = (r / 7) * 16, rw = (r % 7) * 16;
  int tid = threadIdx.x;
  for (int i = tid; i < 1600; i += 256) { int c = i / 25, k = i % 25; sW[k][c] = lw[c * 25 + k]; }
  for (int g = tid; g < 3200; g += 256) {
    int pix = g >> 3, c4 = g & 7;
    int yy = pix / 20, xx = pix % 20;
    int hh = rh + yy - 2, ww = rw + xx - 2;
    uint4 d = {0, 0, 0, 0};
    if ((unsigned)hh < HW && (unsigned)ww < HW)
      d = *(const uint4*)(v_t + ((size_t)n * PP + hh * HW + ww) * 64 + c4 * 8);
    *(uint4*)((char*)sH + pix * 144 + c4 * 16) = d;
  }
  __syncthreads();
  int y = tid >> 4, x = tid & 15;
  float acc[64];
  const bf16* ar = attnRb + (((size_t)(n * RR + r)) * RS + tid) * 64;
  #pragma unroll
  for (int c8 = 0; c8 < 8; c8++) {
    bf16x8 av = *(const bf16x8*)(ar + c8 * 8);
    #pragma unroll
    for (int j = 0; j < 8; j++) acc[c8 * 8 + j] = lb[c8 * 8 + j] + (float)av[j];
  }
  for (int t25 = 0; t25 < 25; t25++) {
    int dh = t25 / 5, dw = t25 % 5;
    int pix = (y + dh) * 20 + (x + dw);
    #pragma unroll
    for (int c8 = 0; c8 < 8; c8++) {
      bf16x8 hv = *(const bf16x8*)((const char*)sH + pix * 144 + c8 * 16);
      #pragma unroll
      for (int j = 0; j < 8; j++) acc[c8 * 8 + j] += (float)hv[j] * sW[t25][c8 * 8 + j];
    }
  }
  bf16* zp = z_t + ((size_t)n * PP + (rh + y) * HW + rw + x) * 64;
  #pragma unroll
  for (int c8 = 0; c8 < 8; c8++) {
    bf16x8 o8;
    #pragma unroll
    for (int j = 0; j < 8; j++) o8[j] = (bf16)acc[c8 * 8 + j];
    *(bf16x8*)(zp + c8 * 8) = o8;
  }
}

// ---------------- proj GEMM: z_t -> x_t += ----------------
__global__ __launch_bounds__(256) void k_proj(const bf16* __restrict__ A, const float* __restrict__ w,
    const float* __restrict__ bias, float* __restrict__ xo) {
  __shared__ bf16 sA[128 * 64];
  __shared__ bf16 sB[64 * 64];
  int n = blockIdx.y;
  int p0 = blockIdx.x * 128;
  int tid = threadIdx.x, lane = tid & 63, wv = tid >> 6;
  int lo = lane & 15, hi = lane >> 4;
  const bf16* Abase = A + (size_t)n * PP * 64;
  #pragma unroll
  for (int it = 0; it < 4; it++) {
    int idx = tid + it * 256;
    int row = idx >> 3, c4 = idx & 7;
    uint4 d = *(const uint4*)(Abase + (size_t)(p0 + row) * 64 + c4 * 8);
    *(uint4*)((char*)sA + row * 128 + (((c4 ^ row) & 7) * 16)) = d;
  }
  #pragma unroll
  for (int it = 0; it < 4; it++) {
    int idx = tid + it * 256;
    int oo = idx >> 4, q = idx & 15;
    float4 wv4 = *(const float4*)&w[(size_t)oo * 64 + q * 4];
    bf16x4 b4; b4[0] = (bf16)wv4.x; b4[1] = (bf16)wv4.y; b4[2] = (bf16)wv4.z; b4[3] = (bf16)wv4.w;
    *(bf16x4*)((char*)sB + swz128(oo, q * 4)) = b4;
  }
  __syncthreads();
  f32x4 acc[2][4];
  #pragma unroll
  for (int mi = 0; mi < 2; mi++)
    #pragma unroll
    for (int ni = 0; ni < 4; ni++) acc[mi][ni] = (f32x4){0.f, 0.f, 0.f, 0.f};
  #pragma unroll
  for (int kk = 0; kk < 2; kk++) {
    bf16x8 aF[2], bF[4];
    #pragma unroll
    for (int mi = 0; mi < 2; mi++)
      aF[mi] = *(const bf16x8*)((const char*)sA + swz128(wv * 32 + mi * 16 + lo, kk * 32 + hi * 8));
    #pragma unroll
    for (int ni = 0; ni < 4; ni++)
      bF[ni] = *(const bf16x8*)((const char*)sB + swz128(ni * 16 + lo, kk * 32 + hi * 8));
    #pragma unroll
    for (int mi = 0; mi < 2; mi++)
      #pragma unroll
      for (int ni = 0; ni < 4; ni++)
        acc[mi][ni] = __builtin_amdgcn_mfma_f32_16x16x32_bf16(aF[mi], bF[ni], acc[mi][ni], 0, 0, 0);
  }
  #pragma unroll
  for (int ni = 0; ni < 4; ni++) {
    float bv = bias[ni * 16 + lo];
    #pragma unroll
    for (int mi = 0; mi < 2; mi++) {
      #pragma unroll
      for (int r2 = 0; r2 < 4; r2++) {
        int p = p0 + wv * 32 + mi * 16 + hi * 4 + r2;
        xo[((size_t)n * PP + p) * 64 + ni * 16 + lo] += acc[mi][ni][r2] + bv;
      }
    }
  }
}

// ---------------- fused MLP: LN2 + fc1 + gelu + fc2 + residual ----------------
__global__ __launch_bounds__(256) void k_mlp(const float* __restrict__ xin, const float* __restrict__ lng,
    const float* __restrict__ lnb, const float* __restrict__ w1, const float* __restrict__ b1,
    const float* __restrict__ w2, const float* __restrict__ b2, float* __restrict__ xo) {
  __shared__ bf16 sA[64 * 64];
  __shared__ bf16 sW1[128 * 64];
  __shared__ bf16 sHh[64 * 128];
  __shared__ bf16 sW2[64 * 128];
  int n = blockIdx.y;
  int p0 = blockIdx.x * 64;
  int tid = threadIdx.x, lane = tid & 63, wv = tid >> 6;
  int lo = lane & 15, hi = lane >> 4;
  { // fused LN staging: 4 threads per row, 16 channels each
    int row = tid >> 2, part = tid & 3;
    const float* xp = xin + ((size_t)n * PP + p0 + row) * 64 + part * 16;
    float v[16]; float s = 0.f, sq = 0.f;
    #pragma unroll
    for (int i = 0; i < 4; i++) {
      float4 d = *(const float4*)&xp[i * 4];
      v[i*4]=d.x; v[i*4+1]=d.y; v[i*4+2]=d.z; v[i*4+3]=d.w;
      s += d.x+d.y+d.z+d.w;
      sq += d.x*d.x+d.y*d.y+d.z*d.z+d.w*d.w;
    }
    s += __shfl_xor(s, 1, 64); sq += __shfl_xor(sq, 1, 64);
    s += __shfl_xor(s, 2, 64); sq += __shfl_xor(sq, 2, 64);
    float mu = s * (1.f/64.f);
    float rstd = rsqrtf(fmaxf(sq * (1.f/64.f) - mu*mu, 0.f) + 1e-5f);
    #pragma unroll
    for (int j2 = 0; j2 < 2; j2++) {
      bf16x8 o8;
      #pragma unroll
      for (int e = 0; e < 8; e++) {
        int c = part*16 + j2*8 + e;
        o8[e] = (bf16)((v[j2*8+e] - mu) * rstd * lng[c] + lnb[c]);
      }
      *(bf16x8*)((char*)sA + swz128(row, part*16 + j2*8)) = o8;
    }
  }
  f32x4 oacc[4];
  #pragma unroll
  for (int ni = 0; ni < 4; ni++) oacc[ni] = (f32x4){0.f, 0.f, 0.f, 0.f};
  for (int half = 0; half < 2; half++) {
    #pragma unroll
    for (int it = 0; it < 8; it++) {
      int idx = tid + it * 256;
      int oo = idx >> 4, q = idx & 15;
      float4 wv4 = *(const float4*)&w1[(size_t)(half * 128 + oo) * 64 + q * 4];
      bf16x4 b4; b4[0] = (bf16)wv4.x; b4[1] = (bf16)wv4.y; b4[2] = (bf16)wv4.z; b4[3] = (bf16)wv4.w;
      *(bf16x4*)((char*)sW1 + swz128(oo, q * 4)) = b4;
    }
    __syncthreads();
    f32x4 hacc[8];
    #pragma unroll
    for (int ni = 0; ni < 8; ni++) hacc[ni] = (f32x4){0.f, 0.f, 0.f, 0.f};
    #pragma unroll
    for (int kk = 0; kk < 2; kk++) {
      bf16x8 aF = *(const bf16x8*)((const char*)sA + swz128(wv * 16 + lo, kk * 32 + hi * 8));
      #pragma unroll
      for (int ni = 0; ni < 8; ni++) {
        bf16x8 bF = *(const bf16x8*)((const char*)sW1 + swz128(ni * 16 + lo, kk * 32 + hi * 8));
        hacc[ni] = __builtin_amdgcn_mfma_f32_16x16x32_bf16(aF, bF, hacc[ni], 0, 0, 0);
      }
    }
    #pragma unroll
    for (int ni = 0; ni < 8; ni++) {
      float bv = b1[half * 128 + ni * 16 + lo];
      #pragma unroll
      for (int r2 = 0; r2 < 4; r2++) {
        float hval = gelu_exact(hacc[ni][r2] + bv);
        *(bf16*)((char*)sHh + swzg(wv * 16 + hi * 4 + r2, ni * 16 + lo, 256)) = (bf16)hval;
      }
    }
    #pragma unroll
    for (int it = 0; it < 8; it++) {
      int idx = tid + it * 256;
      int oo = idx >> 5, q = idx & 31;
      float4 wv4 = *(const float4*)&w2[(size_t)oo * 256 + half * 128 + q * 4];
      bf16x4 b4; b4[0] = (bf16)wv4.x; b4[1] = (bf16)wv4.y; b4[2] = (bf16)wv4.z; b4[3] = (bf16)wv4.w;
      *(bf16x4*)((char*)sW2 + swzg(oo, q * 4, 256)) = b4;
    }
    __syncthreads();
    #pragma unroll
    for (int kk = 0; kk < 4; kk++) {
      bf16x8 aH = *(const bf16x8*)((const char*)sHh + swzg(wv * 16 + lo, kk * 32 + hi * 8, 256));
      #pragma unroll
      for (int ni = 0; ni < 4; ni++) {
        bf16x8 bF = *(const bf16x8*)((const char*)sW2 + swzg(ni * 16 + lo, kk * 32 + hi * 8, 256));
        oacc[ni] = __builtin_amdgcn_mfma_f32_16x16x32_bf16(aH, bF, oacc[ni], 0, 0, 0);
      }
    }
    __syncthreads();
  }
  #pragma unroll
  for (int ni = 0; ni < 4; ni++) {
    float bv = b2[ni * 16 + lo];
    #pragma unroll
    for (int r2 = 0; r2 < 4; r2++) {
      int p = p0 + wv * 16 + hi * 4 + r2;
      xo[((size_t)n * PP + p) * 64 + ni * 16 + lo] += oacc[ni][r2] + bv;
    }
  }
}

// ---------------- final untranspose: x_t[p][c] -> out[c][p] ----------------
__global__ __launch_bounds__(256) void k_untr(const float* __restrict__ x_t, float* __restrict__ out) {
  __shared__ float tile[64][68];
  int n = blockIdx.y; int p0 = blockIdx.x * 64;
  int tid = threadIdx.x;
  #pragma unroll
  for (int it = 0; it < 4; it++) {
    int g = tid + it * 256;
    int row = g >> 4, q = g & 15;
    float4 d = *(const float4*)&x_t[((size_t)n * PP + p0 + row) * 64 + q * 4];
    *(float4*)&tile[row][q * 4] = d;
  }
  __syncthreads();
  #pragma unroll
  for (int it = 0; it < 4; it++) {
    int g = tid + it * 256;
    int c = g >> 4, q = g & 15;
    float4 v;
    v.x = tile[q * 4 + 0][c]; v.y = tile[q * 4 + 1][c];
    v.z = tile[q * 4 + 2][c]; v.w = tile[q * 4 + 3][c];
    *(float4*)&out[((size_t)(n * 64 + c)) * PP + p0 + q * 4] = v;
  }
}

extern "C" void kernel_launch(void* const* d_in, const int* in_sizes, int n_in,
                              void* d_out, int out_size, void* d_ws, size_t ws_size,
                              hipStream_t stream) {
  const float* ex0 = (const float*)d_in[0];
  const float* ex  = (const float*)d_in[1];
  const float* img = (const float*)d_in[2];
  const float* pre = (const float*)d_in[3];
  const float* c0w = (const float*)d_in[4];
  const float* c0b = (const float*)d_in[5];
  const float* ln1g = (const float*)d_in[6];
  const float* ln1b = (const float*)d_in[7];
  const float* ln2g = (const float*)d_in[8];
  const float* ln2b = (const float*)d_in[9];
  const float* qkvw = (const float*)d_in[10];
  const float* qkvb = (const float*)d_in[11];
  const float* lw = (const float*)d_in[12];
  const float* lb = (const float*)d_in[13];
  const float* pw = (const float*)d_in[14];
  const float* pb = (const float*)d_in[15];
  const float* f1w = (const float*)d_in[16];
  const float* f1b = (const float*)d_in[17];
  const float* f2w = (const float*)d_in[18];
  const float* f2b = (const float*)d_in[19];

  float* W = (float*)d_ws;
  size_t o = 0;
  bf16* xct = (bf16*)(W + o);  o += (size_t)BB * GP * CK / 2;
  float* x_t  = W + o;         o += 3211264;
  bf16* attnRb = (bf16*)(W + o); o += 1605632;
  bf16* v_t  = (bf16*)(W + o); o += 1605632;
  bf16* z_t  = (bf16*)(W + o); o += 1605632;
  bf16* qR   = (bf16*)(W + o); o += 1605632;
  bf16* kR   = (bf16*)(W + o); o += 1605632;
  bf16* vT   = (bf16*)(W + o); o += 1605632;
  float* qd = W + o;           o += 12544;
  float* kd = W + o;           o += 12544;
  float* maskr = W + o;        o += 50176;
  bf16* wTb = (bf16*)(W + o);  o += 46080;
  int* gidx = (int*)(W + o);   o += 784;

  hipMemsetAsync(xct, 0, (size_t)BB * GP * CK * 2, stream);
  k_prep2<<<dim3(196, BB), dim3(256), 0, stream>>>(ex0, ex, img, pre, xct, maskr);
  k_wt2<<<dim3(360), dim3(256), 0, stream>>>(c0w, wTb);
  k_conv0m<<<dim3(98, BB), dim3(256), 0, stream>>>(xct, wTb, c0b, x_t);
  for (int i = 0; i < 4; i++) {
    k_qkv<<<dim3(98, BB), dim3(256), 0, stream>>>(x_t, ln1g + i * 64, ln1b + i * 64,
        qkvw + (size_t)i * 192 * 64, qkvb + i * 192, qR, kR, v_t);
    k_vpost<<<dim3(RR, BB), dim3(256), 0, stream>>>(qR, kR, v_t, qd, kd, vT);
    k_topk<<<dim3(RR, BB), dim3(64), 0, stream>>>(qd, kd, gidx);
    k_attn<<<dim3(BB * RR * 4), dim3(256), 0, stream>>>(qR, kR, vT, maskr, gidx, attnRb);
    k_lepe2<<<dim3(RR, BB), dim3(256), 0, stream>>>(v_t, attnRb, lw + (size_t)i * 64 * 25, lb + i * 64, z_t);
    k_proj<<<dim3(98, BB), dim3(256), 0, stream>>>(z_t, pw + (size_t)i * 64 * 64, pb + i * 64, x_t);
    k_mlp<<<dim3(196, BB), dim3(256), 0, stream>>>(x_t, ln2g + i * 64, ln2b + i * 64,
        f1w + (size_t)i * 256 * 64, f1b + i * 256, f2w + (size_t)i * 64 * 256, f2b + i * 64, x_t);
  }
  k_untr<<<dim3(196, BB), dim3(256), 0, stream>>>(x_t, (float*)d_out);
}

// Round 10
// 614.089 us; speedup vs baseline: 1.3574x; 1.0683x over previous
//
#include <hip/hip_runtime.h>

#define HW 112
#define PP 12544
#define BB 4
#define RR 49
#define RS 256
#define GW 114          // padded grid width (zero ring)
#define GP (GW*GW)      // 12996
#define CK 160          // padded channels for conv0

typedef __bf16 bf16;
typedef __bf16 bf16x8 __attribute__((ext_vector_type(8)));
typedef __bf16 bf16x4 __attribute__((ext_vector_type(4)));
typedef float f32x4 __attribute__((ext_vector_type(4)));

// XOR-swizzled byte offset in a row-major bf16 tile; rowbytes ∈ {128,256,512}
__device__ __forceinline__ int swzg(int row, int halfcol, int rowbytes) {
  int byte = halfcol * 2;
  return row * rowbytes + (byte & ~127) + ((((byte >> 4) ^ row) & 7) * 16) + (byte & 15);
}
__device__ __forceinline__ int swz128(int row, int halfcol) { return swzg(row, halfcol, 128); }

__device__ __forceinline__ float gelu_exact(float x) {
  return 0.5f * x * (1.f + erff(x * 0.70710678118654752f));
}

// async global->LDS (no VGPR round-trip). LDS dest = wave-uniform base + lane*size.
__device__ __forceinline__ void gl_lds16(const void* g, void* l) {
  __builtin_amdgcn_global_load_lds((const __attribute__((address_space(1))) unsigned int*)g,
                                   (__attribute__((address_space(3))) unsigned int*)l, 16, 0, 0);
}
__device__ __forceinline__ void gl_lds4(const void* g, void* l) {
  __builtin_amdgcn_global_load_lds((const __attribute__((address_space(1))) unsigned int*)g,
                                   (__attribute__((address_space(3))) unsigned int*)l, 4, 0, 0);
}

// ---------------- prep: downsample+concat -> xcat_t bf16 [n][grid 114x114][160], mask ----------------
__global__ __launch_bounds__(256) void k_prep2(const float* __restrict__ ex0, const float* __restrict__ ex,
    const float* __restrict__ img, const float* __restrict__ pre,
    bf16* __restrict__ xct, float* __restrict__ maskr) {
  __shared__ bf16 sT2[64 * 168];   // [pixel][168 ch] rows 336B (16B aligned)
  int n = blockIdx.y;
  int p0 = blockIdx.x * 64;
  int tid = threadIdx.x;
  uint4 zz = {0, 0, 0, 0};
  for (int i2 = tid; i2 < 1344; i2 += 256) ((uint4*)sT2)[i2] = zz;
  __syncthreads();
  int l = tid & 63, g = tid >> 6;
  int p = p0 + l;
  int h = p / HW, w = p % HW;
  for (int c = g; c < 131; c += 4) {
    float val;
    if (c < 64) {
      const float* s = ex0 + (((size_t)(n * 64 + c)) * 224 + 2 * h) * 224 + 2 * w;
      val = 0.5f * (0.5f * (s[0] + s[224]) + 0.5f * (s[1] + s[225]));
    } else if (c < 128) {
      val = ex[((size_t)(n * 64 + (c - 64))) * PP + p];
    } else {
      const float* s = img + (((size_t)(n * 3 + (c - 128))) * 224 + 2 * h) * 224 + 2 * w;
      val = 0.5f * (0.5f * (s[0] + s[224]) + 0.5f * (s[1] + s[225]));
    }
    sT2[l * 168 + c] = (bf16)val;
  }
  if (tid < 64) {
    const float* s = pre + ((size_t)n * 224 + 2 * h) * 224 + 2 * w;
    float v = 0.5f * (0.5f * (s[0] + s[224]) + 0.5f * (s[1] + s[225]));
    int r = (h >> 4) * 7 + (w >> 4); int sIdx = (h & 15) * 16 + (w & 15);
    maskr[(n * RR + r) * RS + sIdx] = (v > 0.0f) ? 0.0f : -100.0f;
  }
  __syncthreads();
  for (int i2 = tid; i2 < 1280; i2 += 256) {
    int row = i2 / 20, ch = i2 % 20;
    int pr = p0 + row;
    int hh = pr / HW, ww = pr % HW;
    uint4 d = *(const uint4*)(sT2 + row * 168 + ch * 8);
    *(uint4*)(xct + ((size_t)n * GP + (hh + 1) * GW + ww + 1) * CK + ch * 8) = d;
  }
}

// ---------------- conv0 weights -> wTb bf16 [9tap][5ks][64o][32c] ----------------
__global__ __launch_bounds__(256) void k_wt2(const float* __restrict__ w, bf16* __restrict__ wTb) {
  int t = blockIdx.x * 256 + threadIdx.x;
  if (t >= 9 * 5 * 64 * 32) return;
  int cc = t & 31; int o = (t >> 5) & 63; int ks = (t >> 11) % 5; int k = t / 10240;
  int c = ks * 32 + cc;
  wTb[t] = (bf16)((c < 131) ? w[((size_t)(o * 131) + c) * 9 + k] : 0.f);
}

// ---------------- conv0 as MFMA implicit GEMM: 9 shifted taps x 5 K-slices ----------------
__global__ __launch_bounds__(256) void k_conv0m(const bf16* __restrict__ xct, const bf16* __restrict__ wTb,
    const float* __restrict__ bias, float* __restrict__ out_t) {
  __shared__ bf16 sA[128 * 32];
  __shared__ bf16 sB[64 * 32];
  int n = blockIdx.y;
  int p0 = blockIdx.x * 128;
  int tid = threadIdx.x, lane = tid & 63, wv = tid >> 6;
  int lo = lane & 15, hi = lane >> 4;
  size_t gofsA[2];
  #pragma unroll
  for (int it = 0; it < 2; it++) {
    int idx = tid + it * 256;
    int row = idx >> 2, ch = idx & 3;
    int p = p0 + row;
    int hh = p / HW, ww = p % HW;
    gofsA[it] = ((size_t)(hh + 1) * GW + ww + 1) * (CK * 2) + ch * 16;
  }
  const char* xbase = (const char*)(xct + (size_t)n * GP * CK);
  f32x4 acc[2][4];
  #pragma unroll
  for (int mi = 0; mi < 2; mi++)
    #pragma unroll
    for (int ni = 0; ni < 4; ni++) acc[mi][ni] = (f32x4){0.f, 0.f, 0.f, 0.f};
  for (int tap = 0; tap < 9; tap++) {
    long shift = (long)((tap / 3 - 1) * GW + (tap % 3 - 1)) * (CK * 2);
    for (int ks = 0; ks < 5; ks++) {
      uint4 a0 = *(const uint4*)(xbase + gofsA[0] + shift + ks * 64);
      uint4 a1 = *(const uint4*)(xbase + gofsA[1] + shift + ks * 64);
      uint4 b0 = *(const uint4*)((const char*)wTb + ((size_t)(tap * 5 + ks) * 2048 + tid * 8) * 2);
      __syncthreads();
      *(uint4*)((char*)sA + tid * 16) = a0;
      *(uint4*)((char*)sA + (tid + 256) * 16) = a1;
      *(uint4*)((char*)sB + tid * 16) = b0;
      __syncthreads();
      bf16x8 aF[2], bF[4];
      #pragma unroll
      for (int mi = 0; mi < 2; mi++)
        aF[mi] = *(const bf16x8*)((const char*)sA + (wv * 32 + mi * 16 + lo) * 64 + hi * 16);
      #pragma unroll
      for (int ni = 0; ni < 4; ni++)
        bF[ni] = *(const bf16x8*)((const char*)sB + (ni * 16 + lo) * 64 + hi * 16);
      #pragma unroll
      for (int mi = 0; mi < 2; mi++)
        #pragma unroll
        for (int ni = 0; ni < 4; ni++)
          acc[mi][ni] = __builtin_amdgcn_mfma_f32_16x16x32_bf16(aF[mi], bF[ni], acc[mi][ni], 0, 0, 0);
    }
  }
  #pragma unroll
  for (int ni = 0; ni < 4; ni++) {
    float bv = bias[ni * 16 + lo];
    #pragma unroll
    for (int mi = 0; mi < 2; mi++) {
      #pragma unroll
      for (int r2 = 0; r2 < 4; r2++) {
        int p = p0 + wv * 32 + mi * 16 + hi * 4 + r2;
        out_t[((size_t)n * PP + p) * 64 + ni * 16 + lo] = acc[mi][ni][r2] + bv;
      }
    }
  }
}

// ---------------- qkv with fused LN1 ----------------
__global__ __launch_bounds__(256) void k_qkv(const float* __restrict__ xin, const float* __restrict__ lng,
    const float* __restrict__ lnb, const float* __restrict__ w, const float* __restrict__ bias,
    bf16* __restrict__ qRo, bf16* __restrict__ kRo, bf16* __restrict__ vto) {
  __shared__ bf16 sA[128 * 64];
  __shared__ bf16 sB[64 * 64];
  int n = blockIdx.y;
  int p0 = blockIdx.x * 128;
  int tid = threadIdx.x, lane = tid & 63, wv = tid >> 6;
  int lo = lane & 15, hi = lane >> 4;
  { // fused LN staging: 2 threads per row, 32 channels each
    int row = tid >> 1, part = tid & 1;
    const float* xp = xin + ((size_t)n * PP + p0 + row) * 64 + part * 32;
    float v[32]; float s = 0.f, sq = 0.f;
    #pragma unroll
    for (int i = 0; i < 8; i++) {
      float4 d = *(const float4*)&xp[i * 4];
      v[i*4]=d.x; v[i*4+1]=d.y; v[i*4+2]=d.z; v[i*4+3]=d.w;
      s += d.x+d.y+d.z+d.w;
      sq += d.x*d.x+d.y*d.y+d.z*d.z+d.w*d.w;
    }
    s += __shfl_xor(s, 1, 64); sq += __shfl_xor(sq, 1, 64);
    float mu = s * (1.f/64.f);
    float rstd = rsqrtf(fmaxf(sq * (1.f/64.f) - mu*mu, 0.f) + 1e-5f);
    #pragma unroll
    for (int j2 = 0; j2 < 4; j2++) {
      bf16x8 o8;
      #pragma unroll
      for (int e = 0; e < 8; e++) {
        int c = part*32 + j2*8 + e;
        o8[e] = (bf16)((v[j2*8+e] - mu) * rstd * lng[c] + lnb[c]);
      }
      *(bf16x8*)((char*)sA + swz128(row, part*32 + j2*8)) = o8;
    }
  }
  for (int ob = 0; ob < 3; ob++) {
    #pragma unroll
    for (int it = 0; it < 4; it++) {
      int idx = tid + it * 256;
      int oo = idx >> 4, q = idx & 15;
      float4 wv4 = *(const float4*)&w[(size_t)(ob * 64 + oo) * 64 + q * 4];
      bf16x4 b4; b4[0] = (bf16)wv4.x; b4[1] = (bf16)wv4.y; b4[2] = (bf16)wv4.z; b4[3] = (bf16)wv4.w;
      *(bf16x4*)((char*)sB + swz128(oo, q * 4)) = b4;
    }
    __syncthreads();
    f32x4 acc[2][4];
    #pragma unroll
    for (int mi = 0; mi < 2; mi++)
      #pragma unroll
      for (int ni = 0; ni < 4; ni++) acc[mi][ni] = (f32x4){0.f, 0.f, 0.f, 0.f};
    #pragma unroll
    for (int kk = 0; kk < 2; kk++) {
      bf16x8 aF[2], bF[4];
      #pragma unroll
      for (int mi = 0; mi < 2; mi++)
        aF[mi] = *(const bf16x8*)((const char*)sA + swz128(wv * 32 + mi * 16 + lo, kk * 32 + hi * 8));
      #pragma unroll
      for (int ni = 0; ni < 4; ni++)
        bF[ni] = *(const bf16x8*)((const char*)sB + swz128(ni * 16 + lo, kk * 32 + hi * 8));
      #pragma unroll
      for (int mi = 0; mi < 2; mi++)
        #pragma unroll
        for (int ni = 0; ni < 4; ni++)
          acc[mi][ni] = __builtin_amdgcn_mfma_f32_16x16x32_bf16(aF[mi], bF[ni], acc[mi][ni], 0, 0, 0);
    }
    #pragma unroll
    for (int ni = 0; ni < 4; ni++) {
      float bv = bias[ob * 64 + ni * 16 + lo];
      #pragma unroll
      for (int mi = 0; mi < 2; mi++) {
        #pragma unroll
        for (int r2 = 0; r2 < 4; r2++) {
          float rv = acc[mi][ni][r2] + bv;
          int p = p0 + wv * 32 + mi * 16 + hi * 4 + r2;
          int hh = p / HW, ww = p % HW;
          int rg = (hh >> 4) * 7 + (ww >> 4), s2 = (hh & 15) * 16 + (ww & 15);
          int o = ni * 16 + lo;
          if (ob == 0)      qRo[(((size_t)(n * RR + rg)) * RS + s2) * 64 + o] = (bf16)(rv * 0.125f);
          else if (ob == 1) kRo[(((size_t)(n * RR + rg)) * RS + s2) * 64 + o] = (bf16)rv;
          else              vto[((size_t)n * PP + p) * 64 + o] = (bf16)rv;
        }
      }
    }
    __syncthreads();
  }
}

// ---------------- per-region: vT transpose + qd/kd means ----------------
__global__ __launch_bounds__(256) void k_vpost(const bf16* __restrict__ qR, const bf16* __restrict__ kR,
    const bf16* __restrict__ v_t, float* __restrict__ qd, float* __restrict__ kd, bf16* __restrict__ vT) {
  __shared__ bf16 sT[64 * 264];
  __shared__ float rq[4][64], rk[4][64];
  int r = blockIdx.x, n = blockIdx.y;
  int nr = n * RR + r;
  int tid = threadIdx.x;
  int rh = (r / 7) * 16, rw = (r % 7) * 16;
  {
    int ph = rh + (tid >> 4), pw = rw + (tid & 15);
    const bf16* src = v_t + ((size_t)n * PP + ph * HW + pw) * 64;
    #pragma unroll
    for (int c8 = 0; c8 < 8; c8++) {
      bf16x8 d = *(const bf16x8*)(src + c8 * 8);
      #pragma unroll
      for (int j = 0; j < 8; j++) sT[(c8 * 8 + j) * 264 + tid] = d[j];
    }
  }
  {
    int c = tid & 63, sq = tid >> 6;
    const bf16* qb = qR + (size_t)nr * RS * 64;
    const bf16* kb = kR + (size_t)nr * RS * 64;
    float aq = 0.f, ak = 0.f;
    for (int s = sq * 64; s < sq * 64 + 64; s++) {
      aq += (float)qb[s * 64 + c];
      ak += (float)kb[s * 64 + c];
    }
    rq[sq][c] = aq; rk[sq][c] = ak;
  }
  __syncthreads();
  #pragma unroll
  for (int it = 0; it < 8; it++) {
    int idx = tid + it * 256;
    int row = idx >> 5, ch = idx & 31;
    uint4 d = *(const uint4*)(sT + row * 264 + ch * 8);
    *(uint4*)(vT + ((size_t)nr * 64 + row) * 256 + ch * 8) = d;
  }
  if (tid < 64) {
    int c = tid;
    qd[(n * 64 + c) * RR + r] = ((rq[0][c] + rq[1][c]) + (rq[2][c] + rq[3][c])) * (1.f / 256.f);
    kd[(n * 64 + c) * RR + r] = ((rk[0][c] + rk[1][c]) + (rk[2][c] + rk[3][c])) * (1.f / 256.f);
  }
}

// ---------------- top-4 routing: one wave per query region ----------------
__global__ __launch_bounds__(64) void k_topk(const float* __restrict__ qd, const float* __restrict__ kd,
    int* __restrict__ gidx) {
  int pq = blockIdx.x, n = blockIdx.y;
  int j = threadIdx.x;
  float a = -3e38f;
  if (j < RR) {
    a = 0.f;
    for (int c = 0; c < 64; c++)
      a += qd[(n * 64 + c) * RR + pq] * kd[(n * 64 + c) * RR + j];
  }
  for (int t = 0; t < 4; t++) {
    float bv = a; int bj = j;
    #pragma unroll
    for (int d = 32; d >= 1; d >>= 1) {
      float ov = __shfl_xor(bv, d, 64);
      int oj = __shfl_xor(bj, d, 64);
      if (ov > bv || (ov == bv && oj < bj)) { bv = ov; bj = oj; }
    }
    if (j == 0) gidx[(n * RR + pq) * 4 + t] = bj;
    if (j == bj) a = -3e38f;
  }
}

// ---------------- gathered-region flash attention: 8-wave blocks, swapped QK^T ----------------
// grid = BB*RR*2 (XCD-swizzled); block = 8 waves (512 thr); wave owns 16 Q rows; KVBLK=64
__global__ __launch_bounds__(512, 6) void k_attn(const bf16* __restrict__ qR, const bf16* __restrict__ kR,
    const bf16* __restrict__ vT, const float* __restrict__ maskr, const int* __restrict__ gidx,
    bf16* __restrict__ attnRb) {
  __shared__ bf16 sKd[2][64 * 64];   // double-buffered K tile, swizzled content (16KB)
  __shared__ bf16 sVd[2][64 * 64];   // double-buffered V tile (16KB)
  __shared__ bf16 sP[8][16 * 64];    // per-wave P (16KB)
  __shared__ float sMaskB[2][64];
  int bid = blockIdx.x;
  int newid = (bid & 7) * 49 + (bid >> 3);   // 392 = 8*49: bijective XCD chunking
  int n = newid / (RR * 2); int rem = newid % (RR * 2); int r = rem >> 1, qsp = rem & 1;
  int tid = threadIdx.x, lane = tid & 63, wv = tid >> 6;
  int lo = lane & 15, hi = lane >> 4;
  int m0 = qsp * 128 + wv * 16;
  const bf16* qbase = qR + ((size_t)(n * RR + r)) * RS * 64;
  bf16x8 qF[2];
  #pragma unroll
  for (int kk = 0; kk < 2; kk++)
    qF[kk] = *(const bf16x8*)(qbase + (m0 + lo) * 64 + kk * 32 + hi * 8);

  // pre-swizzled per-lane GLOBAL byte offsets; LDS dest linear (wave base + lane*16)
  int gofsK, gofsV;
  {
    int rowT = wv * 8 + (lane >> 3);   // tile row 0..63 covered by 8 waves
    int c4 = ((lane & 7) ^ rowT) & 7;
    gofsK = rowT * 128 + c4 * 16;      // K tile rows are 128B
    gofsV = rowT * 512 + c4 * 16;      // vT rows are 512B; +sub*128 in base
  }

  const int* gptr = gidx + (n * RR + r) * 4;
  int j0g = gptr[0], j1g = gptr[1], j2g = gptr[2], j3g = gptr[3];

  f32x4 zero4 = {0.f, 0.f, 0.f, 0.f};
  f32x4 Oacc[4];
  #pragma unroll
  for (int di = 0; di < 4; di++) Oacc[di] = zero4;
  float mrun = -3e38f, lrun = 0.f;   // per-lane: owns q = m0 + lo

  // issue per wave per tile: 1 K + 1 V gl_lds16 (+ mask on wave 0)
  #define ISSUE_TILE(JREG, SUB, BUF) do {                                            \
    const char* kb_ = (const char*)(kR + ((size_t)(n * RR + (JREG))) * RS * 64) + (SUB) * 8192; \
    const char* vb_ = (const char*)(vT + ((size_t)(n * RR + (JREG))) * 64 * RS) + (SUB) * 128;  \
    gl_lds16(kb_ + gofsK, (char*)sKd + (BUF) * 8192 + wv * 1024);                    \
    gl_lds16(vb_ + gofsV, (char*)sVd + (BUF) * 8192 + wv * 1024);                    \
    if (wv == 0) gl_lds4(maskr + ((size_t)(n * RR + (JREG))) * RS + (SUB) * 64 + lane, (char*)sMaskB[(BUF)]); \
  } while (0)

  ISSUE_TILE(j0g, 0, 0);   // prologue: tile 0 -> buf 0

  for (int ts = 0; ts < 16; ts++) {
    int cur = ts & 1;
    asm volatile("s_waitcnt lgkmcnt(0)" ::: "memory");
    __builtin_amdgcn_s_barrier();
    __builtin_amdgcn_sched_barrier(0);
    if (ts < 15) {
      int nts = ts + 1;
      int jn = (nts < 8) ? (nts < 4 ? j0g : j1g) : (nts < 12 ? j2g : j3g);
      int nsub = nts & 3;
      ISSUE_TILE(jn, nsub, cur ^ 1);
      if (wv == 0) { asm volatile("s_waitcnt vmcnt(3)" ::: "memory"); }
      else         { asm volatile("s_waitcnt vmcnt(2)" ::: "memory"); }
    } else {
      asm volatile("s_waitcnt vmcnt(0)" ::: "memory");
    }
    __builtin_amdgcn_s_barrier();
    __builtin_amdgcn_sched_barrier(0);
    const char* sK = (const char*)sKd + cur * 8192;
    const char* sV = (const char*)sVd + cur * 8192;
    // ---- swapped QK^T: lane (lo,hi) holds S[q=lo][k=ni*16+hi*4+jj] ----
    f32x4 Sacc[4];
    #pragma unroll
    for (int ni = 0; ni < 4; ni++) Sacc[ni] = zero4;
    #pragma unroll
    for (int kk = 0; kk < 2; kk++) {
      #pragma unroll
      for (int ni = 0; ni < 4; ni++) {
        bf16x8 kF = *(const bf16x8*)(sK + swz128(ni * 16 + lo, kk * 32 + hi * 8));
        Sacc[ni] = __builtin_amdgcn_mfma_f32_16x16x32_bf16(kF, qF[kk], Sacc[ni], 0, 0, 0);
      }
    }
    // ---- per-lane softmax (q = lo) ----
    const float* mB = sMaskB[cur];
    float ml = -3e38f;
    #pragma unroll
    for (int ni = 0; ni < 4; ni++) {
      #pragma unroll
      for (int jj = 0; jj < 4; jj++) {
        float sv = Sacc[ni][jj] + mB[ni * 16 + hi * 4 + jj];
        Sacc[ni][jj] = sv;
        ml = fmaxf(ml, sv);
      }
    }
    ml = fmaxf(ml, __shfl_xor(ml, 16, 64));
    ml = fmaxf(ml, __shfl_xor(ml, 32, 64));
    float nm = fmaxf(mrun, ml);
    float sc = __expf(mrun - nm);
    float rs = 0.f;
    bf16* sPw = sP[wv];
    #pragma unroll
    for (int ni = 0; ni < 4; ni++) {
      #pragma unroll
      for (int jj = 0; jj < 4; jj++) {
        float pv = __expf(Sacc[ni][jj] - nm);
        rs += pv;
        *(bf16*)((char*)sPw + swz128(lo, ni * 16 + hi * 4 + jj)) = (bf16)pv;
      }
    }
    rs += __shfl_xor(rs, 16, 64);
    rs += __shfl_xor(rs, 32, 64);
    mrun = nm; lrun = lrun * sc + rs;
    // ---- rescale Oacc: component jj is q-row hi*4+jj; fetch its sc from lane lo=q ----
    float scq[4];
    #pragma unroll
    for (int jj = 0; jj < 4; jj++) scq[jj] = __shfl(sc, hi * 4 + jj, 16);
    #pragma unroll
    for (int di = 0; di < 4; di++)
      #pragma unroll
      for (int jj = 0; jj < 4; jj++) Oacc[di][jj] *= scq[jj];
    // ---- PV ----
    #pragma unroll
    for (int kk = 0; kk < 2; kk++) {
      bf16x8 pF = *(const bf16x8*)((const char*)sPw + swz128(lo, kk * 32 + hi * 8));
      #pragma unroll
      for (int di = 0; di < 4; di++) {
        bf16x8 vF = *(const bf16x8*)(sV + swz128(di * 16 + lo, kk * 32 + hi * 8));
        Oacc[di] = __builtin_amdgcn_mfma_f32_16x16x32_bf16(pF, vF, Oacc[di], 0, 0, 0);
      }
    }
  }
  #undef ISSUE_TILE
  // ---- coalesced epilogue: normalize -> LDS repack (reuse sKd, 16KB = 128x64) -> uint4 stores ----
  __syncthreads();                 // all waves finished compute
  float inv = 1.f / lrun;          // for q = lo
  float invq[4];
  #pragma unroll
  for (int jj = 0; jj < 4; jj++) invq[jj] = __shfl(inv, hi * 4 + jj, 16);
  bf16* sOut = (bf16*)sKd;         // 16KB = 128 rows x 64 ch
  #pragma unroll
  for (int jj = 0; jj < 4; jj++) {
    int row = wv * 16 + hi * 4 + jj;
    #pragma unroll
    for (int di = 0; di < 4; di++)
      sOut[row * 64 + di * 16 + lo] = (bf16)(Oacc[di][jj] * invq[jj]);
  }
  __syncthreads();
  bf16* dst = attnRb + (((size_t)(n * RR + r)) * RS + qsp * 128) * 64;
  #pragma unroll
  for (int it = 0; it < 2; it++) {
    int idx = tid + it * 512;
    *(uint4*)(dst + idx * 8) = *(const uint4*)(sOut + idx * 8);
  }
}

// ---------------- lepe 5x5 dw + from_regions (attnR bf16) ----------------
__global__ __launch_bounds__(256) void k_lepe2(const bf16* __restrict__ v_t, const bf16* __restrict__ attnRb,
    const float* __restrict__ lw, const float* __restrict__ lb, bf16* __restrict__ z_t) {
  __shared__ bf16 sH[400 * 72];
  __shared__ float sW[25][64];
  int r = blockIdx.x, n = blockIdx.y;
  int rh = (r / 7) * 16, rw = (r % 7) * 16;
  int tid = threadIdx.x;
  for (int i = tid; i < 1600; i += 256) { int c = i / 25, k = i % 25; sW[k][c] = lw[c * 25 + k]; }
  for (int g = tid; g < 3200; g += 256) {
    int pix = g >> 3, c4 = g & 7;
    int yy = pix / 20, xx = pix % 20;
    int hh = rh + yy - 2, ww = rw + xx - 2;
    uint4 d = {0, 0, 0, 0};
    if ((unsigned)hh < HW && (unsigned)ww < HW)
      d = *(const uint4*)(v_t + ((size_t)n * PP + hh * HW + ww) * 64 + c4 * 8);
    *(uint4*)((char*)sH + pix * 144 + c4 * 16) = d;
  }
  __syncthreads();
  int y = tid >> 4, x = tid & 15;
  float acc[64];
  const bf16* ar = attnRb + (((size_t)(n * RR + r)) * RS + tid) * 64;
  #pragma unroll
  for (int c8 = 0; c8 < 8; c8++) {
    bf16x8 av = *(const bf16x8*)(ar + c8 * 8);
    #pragma unroll
    for (int j = 0; j < 8; j++) acc[c8 * 8 + j] = lb[c8 * 8 + j] + (float)av[j];
  }
  for (int t25 = 0; t25 < 25; t25++) {
    int dh = t25 / 5, dw = t25 % 5;
    int pix = (y + dh) * 20 + (x + dw);
    #pragma unroll
    for (int c8 = 0; c8 < 8; c8++) {
      bf16x8 hv = *(const bf16x8*)((const char*)sH + pix * 144 + c8 * 16);
      #pragma unroll
      for (int j = 0; j < 8; j++) acc[c8 * 8 + j] += (float)hv[j] * sW[t25][c8 * 8 + j];
    }
  }
  bf16* zp = z_t + ((size_t)n * PP + (rh + y) * HW + rw + x) * 64;
  #pragma unroll
  for (int c8 = 0; c8 < 8; c8++) {
    bf16x8 o8;
    #pragma unroll
    for (int j = 0; j < 8; j++) o8[j] = (bf16)acc[c8 * 8 + j];
    *(bf16x8*)(zp + c8 * 8) = o8;
  }
}

// ---------------- proj GEMM: z_t -> x_t += ----------------
__global__ __launch_bounds__(256) void k_proj(const bf16* __restrict__ A, const float* __restrict__ w,
    const float* __restrict__ bias, float* __restrict__ xo) {
  __shared__ bf16 sA[128 * 64];
  __shared__ bf16 sB[64 * 64];
  int n = blockIdx.y;
  int p0 = blockIdx.x * 128;
  int tid = threadIdx.x, lane = tid & 63, wv = tid >> 6;
  int lo = lane & 15, hi = lane >> 4;
  const bf16* Abase = A + (size_t)n * PP * 64;
  #pragma unroll
  for (int it = 0; it < 4; it++) {
    int idx = tid + it * 256;
    int row = idx >> 3, c4 = idx & 7;
    uint4 d = *(const uint4*)(Abase + (size_t)(p0 + row) * 64 + c4 * 8);
    *(uint4*)((char*)sA + row * 128 + (((c4 ^ row) & 7) * 16)) = d;
  }
  #pragma unroll
  for (int it = 0; it < 4; it++) {
    int idx = tid + it * 256;
    int oo = idx >> 4, q = idx & 15;
    float4 wv4 = *(const float4*)&w[(size_t)oo * 64 + q * 4];
    bf16x4 b4; b4[0] = (bf16)wv4.x; b4[1] = (bf16)wv4.y; b4[2] = (bf16)wv4.z; b4[3] = (bf16)wv4.w;
    *(bf16x4*)((char*)sB + swz128(oo, q * 4)) = b4;
  }
  __syncthreads();
  f32x4 acc[2][4];
  #pragma unroll
  for (int mi = 0; mi < 2; mi++)
    #pragma unroll
    for (int ni = 0; ni < 4; ni++) acc[mi][ni] = (f32x4){0.f, 0.f, 0.f, 0.f};
  #pragma unroll
  for (int kk = 0; kk < 2; kk++) {
    bf16x8 aF[2], bF[4];
    #pragma unroll
    for (int mi = 0; mi < 2; mi++)
      aF[mi] = *(const bf16x8*)((const char*)sA + swz128(wv * 32 + mi * 16 + lo, kk * 32 + hi * 8));
    #pragma unroll
    for (int ni = 0; ni < 4; ni++)
      bF[ni] = *(const bf16x8*)((const char*)sB + swz128(ni * 16 + lo, kk * 32 + hi * 8));
    #pragma unroll
    for (int mi = 0; mi < 2; mi++)
      #pragma unroll
      for (int ni = 0; ni < 4; ni++)
        acc[mi][ni] = __builtin_amdgcn_mfma_f32_16x16x32_bf16(aF[mi], bF[ni], acc[mi][ni], 0, 0, 0);
  }
  #pragma unroll
  for (int ni = 0; ni < 4; ni++) {
    float bv = bias[ni * 16 + lo];
    #pragma unroll
    for (int mi = 0; mi < 2; mi++) {
      #pragma unroll
      for (int r2 = 0; r2 < 4; r2++) {
        int p = p0 + wv * 32 + mi * 16 + hi * 4 + r2;
        xo[((size_t)n * PP + p) * 64 + ni * 16 + lo] += acc[mi][ni][r2] + bv;
      }
    }
  }
}

// ---------------- fused MLP: LN2 + fc1 + gelu + fc2 + residual ----------------
__global__ __launch_bounds__(256) void k_mlp(const float* __restrict__ xin, const float* __restrict__ lng,
    const float* __restrict__ lnb, const float* __restrict__ w1, const float* __restrict__ b1,
    const float* __restrict__ w2, const float* __restrict__ b2, float* __restrict__ xo) {
  __shared__ bf16 sA[64 * 64];
  __shared__ bf16 sW1[128 * 64];
  __shared__ bf16 sHh[64 * 128];
  __shared__ bf16 sW2[64 * 128];
  int n = blockIdx.y;
  int p0 = blockIdx.x * 64;
  int tid = threadIdx.x, lane = tid & 63, wv = tid >> 6;
  int lo = lane & 15, hi = lane >> 4;
  { // fused LN staging: 4 threads per row, 16 channels each
    int row = tid >> 2, part = tid & 3;
    const float* xp = xin + ((size_t)n * PP + p0 + row) * 64 + part * 16;
    float v[16]; float s = 0.f, sq = 0.f;
    #pragma unroll
    for (int i = 0; i < 4; i++) {
      float4 d = *(const float4*)&xp[i * 4];
      v[i*4]=d.x; v[i*4+1]=d.y; v[i*4+2]=d.z; v[i*4+3]=d.w;
      s += d.x+d.y+d.z+d.w;
      sq += d.x*d.x+d.y*d.y+d.z*d.z+d.w*d.w;
    }
    s += __shfl_xor(s, 1, 64); sq += __shfl_xor(sq, 1, 64);
    s += __shfl_xor(s, 2, 64); sq += __shfl_xor(sq, 2, 64);
    float mu = s * (1.f/64.f);
    float rstd = rsqrtf(fmaxf(sq * (1.f/64.f) - mu*mu, 0.f) + 1e-5f);
    #pragma unroll
    for (int j2 = 0; j2 < 2; j2++) {
      bf16x8 o8;
      #pragma unroll
      for (int e = 0; e < 8; e++) {
        int c = part*16 + j2*8 + e;
        o8[e] = (bf16)((v[j2*8+e] - mu) * rstd * lng[c] + lnb[c]);
      }
      *(bf16x8*)((char*)sA + swz128(row, part*16 + j2*8)) = o8;
    }
  }
  f32x4 oacc[4];
  #pragma unroll
  for (int ni = 0; ni < 4; ni++) oacc[ni] = (f32x4){0.f, 0.f, 0.f, 0.f};
  for (int half = 0; half < 2; half++) {
    #pragma unroll
    for (int it = 0; it < 8; it++) {
      int idx = tid + it * 256;
      int oo = idx >> 4, q = idx & 15;
      float4 wv4 = *(const float4*)&w1[(size_t)(half * 128 + oo) * 64 + q * 4];
      bf16x4 b4; b4[0] = (bf16)wv4.x; b4[1] = (bf16)wv4.y; b4[2] = (bf16)wv4.z; b4[3] = (bf16)wv4.w;
      *(bf16x4*)((char*)sW1 + swz128(oo, q * 4)) = b4;
    }
    __syncthreads();
    f32x4 hacc[8];
    #pragma unroll
    for (int ni = 0; ni < 8; ni++) hacc[ni] = (f32x4){0.f, 0.f, 0.f, 0.f};
    #pragma unroll
    for (int kk = 0; kk < 2; kk++) {
      bf16x8 aF = *(const bf16x8*)((const char*)sA + swz128(wv * 16 + lo, kk * 32 + hi * 8));
      #pragma unroll
      for (int ni = 0; ni < 8; ni++) {
        bf16x8 bF = *(const bf16x8*)((const char*)sW1 + swz128(ni * 16 + lo, kk * 32 + hi * 8));
        hacc[ni] = __builtin_amdgcn_mfma_f32_16x16x32_bf16(aF, bF, hacc[ni], 0, 0, 0);
      }
    }
    #pragma unroll
    for (int ni = 0; ni < 8; ni++) {
      float bv = b1[half * 128 + ni * 16 + lo];
      #pragma unroll
      for (int r2 = 0; r2 < 4; r2++) {
        float hval = gelu_exact(hacc[ni][r2] + bv);
        *(bf16*)((char*)sHh + swzg(wv * 16 + hi * 4 + r2, ni * 16 + lo, 256)) = (bf16)hval;
      }
    }
    #pragma unroll
    for (int it = 0; it < 8; it++) {
      int idx = tid + it * 256;
      int oo = idx >> 5, q = idx & 31;
      float4 wv4 = *(const float4*)&w2[(size_t)oo * 256 + half * 128 + q * 4];
      bf16x4 b4; b4[0] = (bf16)wv4.x; b4[1] = (bf16)wv4.y; b4[2] = (bf16)wv4.z; b4[3] = (bf16)wv4.w;
      *(bf16x4*)((char*)sW2 + swzg(oo, q * 4, 256)) = b4;
    }
    __syncthreads();
    #pragma unroll
    for (int kk = 0; kk < 4; kk++) {
      bf16x8 aH = *(const bf16x8*)((const char*)sHh + swzg(wv * 16 + lo, kk * 32 + hi * 8, 256));
      #pragma unroll
      for (int ni = 0; ni < 4; ni++) {
        bf16x8 bF = *(const bf16x8*)((const char*)sW2 + swzg(ni * 16 + lo, kk * 32 + hi * 8, 256));
        oacc[ni] = __builtin_amdgcn_mfma_f32_16x16x32_bf16(aH, bF, oacc[ni], 0, 0, 0);
      }
    }
    __syncthreads();
  }
  #pragma unroll
  for (int ni = 0; ni < 4; ni++) {
    float bv = b2[ni * 16 + lo];
    #pragma unroll
    for (int r2 = 0; r2 < 4; r2++) {
      int p = p0 + wv * 16 + hi * 4 + r2;
      xo[((size_t)n * PP + p) * 64 + ni * 16 + lo] += oacc[ni][r2] + bv;
    }
  }
}

// ---------------- final untranspose: x_t[p][c] -> out[c][p] ----------------
__global__ __launch_bounds__(256) void k_untr(const float* __restrict__ x_t, float* __restrict__ out) {
  __shared__ float tile[64][68];
  int n = blockIdx.y; int p0 = blockIdx.x * 64;
  int tid = threadIdx.x;
  #pragma unroll
  for (int it = 0; it < 4; it++) {
    int g = tid + it * 256;
    int row = g >> 4, q = g & 15;
    float4 d = *(const float4*)&x_t[((size_t)n * PP + p0 + row) * 64 + q * 4];
    *(float4*)&tile[row][q * 4] = d;
  }
  __syncthreads();
  #pragma unroll
  for (int it = 0; it < 4; it++) {
    int g = tid + it * 256;
    int c = g >> 4, q = g & 15;
    float4 v;
    v.x = tile[q * 4 + 0][c]; v.y = tile[q * 4 + 1][c];
    v.z = tile[q * 4 + 2][c]; v.w = tile[q * 4 + 3][c];
    *(float4*)&out[((size_t)(n * 64 + c)) * PP + p0 + q * 4] = v;
  }
}

extern "C" void kernel_launch(void* const* d_in, const int* in_sizes, int n_in,
                              void* d_out, int out_size, void* d_ws, size_t ws_size,
                              hipStream_t stream) {
  const float* ex0 = (const float*)d_in[0];
  const float* ex  = (const float*)d_in[1];
  const float* img = (const float*)d_in[2];
  const float* pre = (const float*)d_in[3];
  const float* c0w = (const float*)d_in[4];
  const float* c0b = (const float*)d_in[5];
  const float* ln1g = (const float*)d_in[6];
  const float* ln1b = (const float*)d_in[7];
  const float* ln2g = (const float*)d_in[8];
  const float* ln2b = (const float*)d_in[9];
  const float* qkvw = (const float*)d_in[10];
  const float* qkvb = (const float*)d_in[11];
  const float* lw = (const float*)d_in[12];
  const float* lb = (const float*)d_in[13];
  const float* pw = (const float*)d_in[14];
  const float* pb = (const float*)d_in[15];
  const float* f1w = (const float*)d_in[16];
  const float* f1b = (const float*)d_in[17];
  const float* f2w = (const float*)d_in[18];
  const float* f2b = (const float*)d_in[19];

  float* W = (float*)d_ws;
  size_t o = 0;
  bf16* xct = (bf16*)(W + o);  o += (size_t)BB * GP * CK / 2;
  float* x_t  = W + o;         o += 3211264;
  bf16* attnRb = (bf16*)(W + o); o += 1605632;
  bf16* v_t  = (bf16*)(W + o); o += 1605632;
  bf16* z_t  = (bf16*)(W + o); o += 1605632;
  bf16* qR   = (bf16*)(W + o); o += 1605632;
  bf16* kR   = (bf16*)(W + o); o += 1605632;
  bf16* vT   = (bf16*)(W + o); o += 1605632;
  float* qd = W + o;           o += 12544;
  float* kd = W + o;           o += 12544;
  float* maskr = W + o;        o += 50176;
  bf16* wTb = (bf16*)(W + o);  o += 46080;
  int* gidx = (int*)(W + o);   o += 784;

  hipMemsetAsync(xct, 0, (size_t)BB * GP * CK * 2, stream);
  k_prep2<<<dim3(196, BB), dim3(256), 0, stream>>>(ex0, ex, img, pre, xct, maskr);
  k_wt2<<<dim3(360), dim3(256), 0, stream>>>(c0w, wTb);
  k_conv0m<<<dim3(98, BB), dim3(256), 0, stream>>>(xct, wTb, c0b, x_t);
  for (int i = 0; i < 4; i++) {
    k_qkv<<<dim3(98, BB), dim3(256), 0, stream>>>(x_t, ln1g + i * 64, ln1b + i * 64,
        qkvw + (size_t)i * 192 * 64, qkvb + i * 192, qR, kR, v_t);
    k_vpost<<<dim3(RR, BB), dim3(256), 0, stream>>>(qR, kR, v_t, qd, kd, vT);
    k_topk<<<dim3(RR, BB), dim3(64), 0, stream>>>(qd, kd, gidx);
    k_attn<<<dim3(BB * RR * 2), dim3(512), 0, stream>>>(qR, kR, vT, maskr, gidx, attnRb);
    k_lepe2<<<dim3(RR, BB), dim3(256), 0, stream>>>(v_t, attnRb, lw + (size_t)i * 64 * 25, lb + i * 64, z_t);
    k_proj<<<dim3(98, BB), dim3(256), 0, stream>>>(z_t, pw + (size_t)i * 64 * 64, pb + i * 64, x_t);
    k_mlp<<<dim3(196, BB), dim3(256), 0, stream>>>(x_t, ln2g + i * 64, ln2b + i * 64,
        f1w + (size_t)i * 256 * 64, f1b + i * 256, f2w + (size_t)i * 64 * 256, f2b + i * 64, x_t);
  }
  k_untr<<<dim3(196, BB), dim3(256), 0, stream>>>(x_t, (float*)d_out);
}

// Round 11
// 491.109 us; speedup vs baseline: 1.6974x; 1.2504x over previous
//
#include <hip/hip_runtime.h>

#define HW 112
#define PP 12544
#define BB 4
#define RR 49
#define RS 256
#define GW 114          // padded grid width (zero ring)
#define GP (GW*GW)      // 12996
#define CK 160          // padded channels for conv0

typedef __bf16 bf16;
typedef __bf16 bf16x8 __attribute__((ext_vector_type(8)));
typedef __bf16 bf16x4 __attribute__((ext_vector_type(4)));
typedef float f32x4 __attribute__((ext_vector_type(4)));

// XOR-swizzled byte offset in a row-major bf16 tile; rowbytes ∈ {128,256,512}
__device__ __forceinline__ int swzg(int row, int halfcol, int rowbytes) {
  int byte = halfcol * 2;
  return row * rowbytes + (byte & ~127) + ((((byte >> 4) ^ row) & 7) * 16) + (byte & 15);
}
__device__ __forceinline__ int swz128(int row, int halfcol) { return swzg(row, halfcol, 128); }

__device__ __forceinline__ float gelu_exact(float x) {
  return 0.5f * x * (1.f + erff(x * 0.70710678118654752f));
}

// async global->LDS (no VGPR round-trip). LDS dest = wave-uniform base + lane*size.
__device__ __forceinline__ void gl_lds16(const void* g, void* l) {
  __builtin_amdgcn_global_load_lds((const __attribute__((address_space(1))) unsigned int*)g,
                                   (__attribute__((address_space(3))) unsigned int*)l, 16, 0, 0);
}
__device__ __forceinline__ void gl_lds4(const void* g, void* l) {
  __builtin_amdgcn_global_load_lds((const __attribute__((address_space(1))) unsigned int*)g,
                                   (__attribute__((address_space(3))) unsigned int*)l, 4, 0, 0);
}

// ---------------- prep: downsample+concat -> xcat_t bf16 [n][grid 114x114][160], mask ----------------
__global__ __launch_bounds__(256) void k_prep2(const float* __restrict__ ex0, const float* __restrict__ ex,
    const float* __restrict__ img, const float* __restrict__ pre,
    bf16* __restrict__ xct, float* __restrict__ maskr) {
  __shared__ bf16 sT2[64 * 168];
  int n = blockIdx.y;
  int p0 = blockIdx.x * 64;
  int tid = threadIdx.x;
  uint4 zz = {0, 0, 0, 0};
  for (int i2 = tid; i2 < 1344; i2 += 256) ((uint4*)sT2)[i2] = zz;
  __syncthreads();
  int l = tid & 63, g = tid >> 6;
  int p = p0 + l;
  int h = p / HW, w = p % HW;
  for (int c = g; c < 131; c += 4) {
    float val;
    if (c < 64) {
      const float* s = ex0 + (((size_t)(n * 64 + c)) * 224 + 2 * h) * 224 + 2 * w;
      val = 0.5f * (0.5f * (s[0] + s[224]) + 0.5f * (s[1] + s[225]));
    } else if (c < 128) {
      val = ex[((size_t)(n * 64 + (c - 64))) * PP + p];
    } else {
      const float* s = img + (((size_t)(n * 3 + (c - 128))) * 224 + 2 * h) * 224 + 2 * w;
      val = 0.5f * (0.5f * (s[0] + s[224]) + 0.5f * (s[1] + s[225]));
    }
    sT2[l * 168 + c] = (bf16)val;
  }
  if (tid < 64) {
    const float* s = pre + ((size_t)n * 224 + 2 * h) * 224 + 2 * w;
    float v = 0.5f * (0.5f * (s[0] + s[224]) + 0.5f * (s[1] + s[225]));
    int r = (h >> 4) * 7 + (w >> 4); int sIdx = (h & 15) * 16 + (w & 15);
    maskr[(n * RR + r) * RS + sIdx] = (v > 0.0f) ? 0.0f : -100.0f;
  }
  __syncthreads();
  for (int i2 = tid; i2 < 1280; i2 += 256) {
    int row = i2 / 20, ch = i2 % 20;
    int pr = p0 + row;
    int hh = pr / HW, ww = pr % HW;
    uint4 d = *(const uint4*)(sT2 + row * 168 + ch * 8);
    *(uint4*)(xct + ((size_t)n * GP + (hh + 1) * GW + ww + 1) * CK + ch * 8) = d;
  }
}

// ---------------- conv0 weights -> wTb bf16 [9tap][5ks][64o][32c] ----------------
__global__ __launch_bounds__(256) void k_wt2(const float* __restrict__ w, bf16* __restrict__ wTb) {
  int t = blockIdx.x * 256 + threadIdx.x;
  if (t >= 9 * 5 * 64 * 32) return;
  int cc = t & 31; int o = (t >> 5) & 63; int ks = (t >> 11) % 5; int k = t / 10240;
  int c = ks * 32 + cc;
  wTb[t] = (bf16)((c < 131) ? w[((size_t)(o * 131) + c) * 9 + k] : 0.f);
}

// ---------------- conv0 as MFMA implicit GEMM ----------------
__global__ __launch_bounds__(256) void k_conv0m(const bf16* __restrict__ xct, const bf16* __restrict__ wTb,
    const float* __restrict__ bias, float* __restrict__ out_t) {
  __shared__ bf16 sA[128 * 32];
  __shared__ bf16 sB[64 * 32];
  int n = blockIdx.y;
  int p0 = blockIdx.x * 128;
  int tid = threadIdx.x, lane = tid & 63, wv = tid >> 6;
  int lo = lane & 15, hi = lane >> 4;
  size_t gofsA[2];
  #pragma unroll
  for (int it = 0; it < 2; it++) {
    int idx = tid + it * 256;
    int row = idx >> 2, ch = idx & 3;
    int p = p0 + row;
    int hh = p / HW, ww = p % HW;
    gofsA[it] = ((size_t)(hh + 1) * GW + ww + 1) * (CK * 2) + ch * 16;
  }
  const char* xbase = (const char*)(xct + (size_t)n * GP * CK);
  f32x4 acc[2][4];
  #pragma unroll
  for (int mi = 0; mi < 2; mi++)
    #pragma unroll
    for (int ni = 0; ni < 4; ni++) acc[mi][ni] = (f32x4){0.f, 0.f, 0.f, 0.f};
  for (int tap = 0; tap < 9; tap++) {
    long shift = (long)((tap / 3 - 1) * GW + (tap % 3 - 1)) * (CK * 2);
    for (int ks = 0; ks < 5; ks++) {
      uint4 a0 = *(const uint4*)(xbase + gofsA[0] + shift + ks * 64);
      uint4 a1 = *(const uint4*)(xbase + gofsA[1] + shift + ks * 64);
      uint4 b0 = *(const uint4*)((const char*)wTb + ((size_t)(tap * 5 + ks) * 2048 + tid * 8) * 2);
      __syncthreads();
      *(uint4*)((char*)sA + tid * 16) = a0;
      *(uint4*)((char*)sA + (tid + 256) * 16) = a1;
      *(uint4*)((char*)sB + tid * 16) = b0;
      __syncthreads();
      bf16x8 aF[2], bF[4];
      #pragma unroll
      for (int mi = 0; mi < 2; mi++)
        aF[mi] = *(const bf16x8*)((const char*)sA + (wv * 32 + mi * 16 + lo) * 64 + hi * 16);
      #pragma unroll
      for (int ni = 0; ni < 4; ni++)
        bF[ni] = *(const bf16x8*)((const char*)sB + (ni * 16 + lo) * 64 + hi * 16);
      #pragma unroll
      for (int mi = 0; mi < 2; mi++)
        #pragma unroll
        for (int ni = 0; ni < 4; ni++)
          acc[mi][ni] = __builtin_amdgcn_mfma_f32_16x16x32_bf16(aF[mi], bF[ni], acc[mi][ni], 0, 0, 0);
    }
  }
  #pragma unroll
  for (int ni = 0; ni < 4; ni++) {
    float bv = bias[ni * 16 + lo];
    #pragma unroll
    for (int mi = 0; mi < 2; mi++) {
      #pragma unroll
      for (int r2 = 0; r2 < 4; r2++) {
        int p = p0 + wv * 32 + mi * 16 + hi * 4 + r2;
        out_t[((size_t)n * PP + p) * 64 + ni * 16 + lo] = acc[mi][ni][r2] + bv;
      }
    }
  }
}

// ---------------- fused region qkv: LN1 + qkv GEMM + qR/kR/v_t/vT + qd/kd ----------------
// grid (RR, BB); block 256 = one region (256 pixels)
__global__ __launch_bounds__(256) void k_qkvr(const float* __restrict__ xin, const float* __restrict__ lng,
    const float* __restrict__ lnb, const float* __restrict__ w, const float* __restrict__ bias,
    bf16* __restrict__ qRo, bf16* __restrict__ kRo, bf16* __restrict__ vto, bf16* __restrict__ vTo,
    float* __restrict__ qd, float* __restrict__ kd) {
  __shared__ __align__(16) char smem[43008];
  bf16* sA = (bf16*)smem;               // 256x64 tile, 32768B
  bf16* sB = (bf16*)(smem + 32768);     // 64x64 weights, 8192B
  float* rq = (float*)(smem + 40960);   // [4][64]
  float* rk = (float*)(smem + 41984);   // [4][64]
  bf16* sT = (bf16*)smem;               // overlay for vT transpose (64x264)
  int r = blockIdx.x, n = blockIdx.y;
  int nr = n * RR + r;
  int rh = (r / 7) * 16, rw = (r % 7) * 16;
  int tid = threadIdx.x, lane = tid & 63, wv = tid >> 6;
  int lo = lane & 15, hi = lane >> 4;
  // LN staging: 2 threads per pixel-row, two halves
  #pragma unroll
  for (int h2 = 0; h2 < 2; h2++) {
    int row = h2 * 128 + (tid >> 1), part = tid & 1;
    int y = row >> 4, x = row & 15;
    const float* xp = xin + ((size_t)n * PP + (rh + y) * HW + rw + x) * 64 + part * 32;
    float v[32]; float s = 0.f, sq = 0.f;
    #pragma unroll
    for (int i = 0; i < 8; i++) {
      float4 d = *(const float4*)&xp[i * 4];
      v[i*4]=d.x; v[i*4+1]=d.y; v[i*4+2]=d.z; v[i*4+3]=d.w;
      s += d.x+d.y+d.z+d.w;
      sq += d.x*d.x+d.y*d.y+d.z*d.z+d.w*d.w;
    }
    s += __shfl_xor(s, 1, 64); sq += __shfl_xor(sq, 1, 64);
    float mu = s * (1.f/64.f);
    float rstd = rsqrtf(fmaxf(sq * (1.f/64.f) - mu*mu, 0.f) + 1e-5f);
    #pragma unroll
    for (int j2 = 0; j2 < 4; j2++) {
      bf16x8 o8;
      #pragma unroll
      for (int e = 0; e < 8; e++) {
        int c = part*32 + j2*8 + e;
        o8[e] = (bf16)((v[j2*8+e] - mu) * rstd * lng[c] + lnb[c]);
      }
      *(bf16x8*)((char*)sA + swz128(row, part*32 + j2*8)) = o8;
    }
  }
  for (int ob = 0; ob < 3; ob++) {
    #pragma unroll
    for (int it = 0; it < 4; it++) {
      int idx = tid + it * 256;
      int oo = idx >> 4, q = idx & 15;
      float4 wv4 = *(const float4*)&w[(size_t)(ob * 64 + oo) * 64 + q * 4];
      bf16x4 b4; b4[0] = (bf16)wv4.x; b4[1] = (bf16)wv4.y; b4[2] = (bf16)wv4.z; b4[3] = (bf16)wv4.w;
      *(bf16x4*)((char*)sB + swz128(oo, q * 4)) = b4;
    }
    __syncthreads();
    f32x4 acc[4][4];
    #pragma unroll
    for (int mi = 0; mi < 4; mi++)
      #pragma unroll
      for (int ni = 0; ni < 4; ni++) acc[mi][ni] = (f32x4){0.f, 0.f, 0.f, 0.f};
    #pragma unroll
    for (int kk = 0; kk < 2; kk++) {
      bf16x8 aF[4], bF[4];
      #pragma unroll
      for (int mi = 0; mi < 4; mi++)
        aF[mi] = *(const bf16x8*)((const char*)sA + swz128(wv * 64 + mi * 16 + lo, kk * 32 + hi * 8));
      #pragma unroll
      for (int ni = 0; ni < 4; ni++)
        bF[ni] = *(const bf16x8*)((const char*)sB + swz128(ni * 16 + lo, kk * 32 + hi * 8));
      #pragma unroll
      for (int mi = 0; mi < 4; mi++)
        #pragma unroll
        for (int ni = 0; ni < 4; ni++)
          acc[mi][ni] = __builtin_amdgcn_mfma_f32_16x16x32_bf16(aF[mi], bF[ni], acc[mi][ni], 0, 0, 0);
    }
    float bv[4];
    #pragma unroll
    for (int ni = 0; ni < 4; ni++) bv[ni] = bias[ob * 64 + ni * 16 + lo];
    if (ob == 0) {
      float part_[4] = {0.f, 0.f, 0.f, 0.f};
      #pragma unroll
      for (int ni = 0; ni < 4; ni++) {
        #pragma unroll
        for (int mi = 0; mi < 4; mi++) {
          #pragma unroll
          for (int r2 = 0; r2 < 4; r2++) {
            float rv = acc[mi][ni][r2] + bv[ni];
            int s = wv * 64 + mi * 16 + hi * 4 + r2;
            qRo[((size_t)nr * RS + s) * 64 + ni * 16 + lo] = (bf16)(rv * 0.125f);
            part_[ni] += rv;
          }
        }
        part_[ni] += __shfl_xor(part_[ni], 16, 64);
        part_[ni] += __shfl_xor(part_[ni], 32, 64);
        if (hi == 0) rq[wv * 64 + ni * 16 + lo] = part_[ni];
      }
      __syncthreads();
    } else if (ob == 1) {
      float part_[4] = {0.f, 0.f, 0.f, 0.f};
      #pragma unroll
      for (int ni = 0; ni < 4; ni++) {
        #pragma unroll
        for (int mi = 0; mi < 4; mi++) {
          #pragma unroll
          for (int r2 = 0; r2 < 4; r2++) {
            float rv = acc[mi][ni][r2] + bv[ni];
            int s = wv * 64 + mi * 16 + hi * 4 + r2;
            kRo[((size_t)nr * RS + s) * 64 + ni * 16 + lo] = (bf16)rv;
            part_[ni] += rv;
          }
        }
        part_[ni] += __shfl_xor(part_[ni], 16, 64);
        part_[ni] += __shfl_xor(part_[ni], 32, 64);
        if (hi == 0) rk[wv * 64 + ni * 16 + lo] = part_[ni];
      }
      __syncthreads();
    } else {
      __syncthreads();   // all waves done reading sA/sB -> safe to overlay sT
      #pragma unroll
      for (int ni = 0; ni < 4; ni++) {
        int ch = ni * 16 + lo;
        #pragma unroll
        for (int mi = 0; mi < 4; mi++) {
          #pragma unroll
          for (int r2 = 0; r2 < 4; r2++) {
            float rv = acc[mi][ni][r2] + bv[ni];
            int s = wv * 64 + mi * 16 + hi * 4 + r2;
            bf16 b = (bf16)rv;
            vto[((size_t)n * PP + (rh + (s >> 4)) * HW + rw + (s & 15)) * 64 + ch] = b;
            sT[ch * 264 + s] = b;
          }
        }
      }
      __syncthreads();
      #pragma unroll
      for (int it = 0; it < 8; it++) {
        int idx = tid + it * 256;
        int row = idx >> 5, ch8 = idx & 31;
        uint4 d = *(const uint4*)(sT + row * 264 + ch8 * 8);
        *(uint4*)(vTo + ((size_t)nr * 64 + row) * 256 + ch8 * 8) = d;
      }
      if (tid < 64) {
        int c = tid;
        qd[(n * 64 + c) * RR + r] = ((rq[c] + rq[64 + c]) + (rq[128 + c] + rq[192 + c])) * (1.f / 256.f);
        kd[(n * 64 + c) * RR + r] = ((rk[c] + rk[64 + c]) + (rk[128 + c] + rk[192 + c])) * (1.f / 256.f);
      }
    }
  }
}

// ---------------- top-4 routing: one wave per query region ----------------
__global__ __launch_bounds__(64) void k_topk(const float* __restrict__ qd, const float* __restrict__ kd,
    int* __restrict__ gidx) {
  int pq = blockIdx.x, n = blockIdx.y;
  int j = threadIdx.x;
  float a = -3e38f;
  if (j < RR) {
    a = 0.f;
    for (int c = 0; c < 64; c++)
      a += qd[(n * 64 + c) * RR + pq] * kd[(n * 64 + c) * RR + j];
  }
  for (int t = 0; t < 4; t++) {
    float bv = a; int bj = j;
    #pragma unroll
    for (int d = 32; d >= 1; d >>= 1) {
      float ov = __shfl_xor(bv, d, 64);
      int oj = __shfl_xor(bj, d, 64);
      if (ov > bv || (ov == bv && oj < bj)) { bv = ov; bj = oj; }
    }
    if (j == 0) gidx[(n * RR + pq) * 4 + t] = bj;
    if (j == bj) a = -3e38f;
  }
}

// ---------------- gathered-region flash attention: 8-wave blocks, swapped QK^T ----------------
__global__ __launch_bounds__(512, 6) void k_attn(const bf16* __restrict__ qR, const bf16* __restrict__ kR,
    const bf16* __restrict__ vT, const float* __restrict__ maskr, const int* __restrict__ gidx,
    bf16* __restrict__ attnRb) {
  __shared__ bf16 sKd[2][64 * 64];
  __shared__ bf16 sVd[2][64 * 64];
  __shared__ bf16 sP[8][16 * 64];
  __shared__ float sMaskB[2][64];
  int bid = blockIdx.x;
  int newid = (bid & 7) * 49 + (bid >> 3);   // 392 = 8*49: bijective XCD chunking
  int n = newid / (RR * 2); int rem = newid % (RR * 2); int r = rem >> 1, qsp = rem & 1;
  int tid = threadIdx.x, lane = tid & 63, wv = tid >> 6;
  int lo = lane & 15, hi = lane >> 4;
  int m0 = qsp * 128 + wv * 16;
  const bf16* qbase = qR + ((size_t)(n * RR + r)) * RS * 64;
  bf16x8 qF[2];
  #pragma unroll
  for (int kk = 0; kk < 2; kk++)
    qF[kk] = *(const bf16x8*)(qbase + (m0 + lo) * 64 + kk * 32 + hi * 8);

  int gofsK, gofsV;
  {
    int rowT = wv * 8 + (lane >> 3);
    int c4 = ((lane & 7) ^ rowT) & 7;
    gofsK = rowT * 128 + c4 * 16;
    gofsV = rowT * 512 + c4 * 16;
  }

  const int* gptr = gidx + (n * RR + r) * 4;
  int j0g = gptr[0], j1g = gptr[1], j2g = gptr[2], j3g = gptr[3];

  f32x4 zero4 = {0.f, 0.f, 0.f, 0.f};
  f32x4 Oacc[4];
  #pragma unroll
  for (int di = 0; di < 4; di++) Oacc[di] = zero4;
  float mrun = -3e38f, lrun = 0.f;

  #define ISSUE_TILE(JREG, SUB, BUF) do {                                            \
    const char* kb_ = (const char*)(kR + ((size_t)(n * RR + (JREG))) * RS * 64) + (SUB) * 8192; \
    const char* vb_ = (const char*)(vT + ((size_t)(n * RR + (JREG))) * 64 * RS) + (SUB) * 128;  \
    gl_lds16(kb_ + gofsK, (char*)sKd + (BUF) * 8192 + wv * 1024);                    \
    gl_lds16(vb_ + gofsV, (char*)sVd + (BUF) * 8192 + wv * 1024);                    \
    if (wv == 0) gl_lds4(maskr + ((size_t)(n * RR + (JREG))) * RS + (SUB) * 64 + lane, (char*)sMaskB[(BUF)]); \
  } while (0)

  ISSUE_TILE(j0g, 0, 0);

  for (int ts = 0; ts < 16; ts++) {
    int cur = ts & 1;
    asm volatile("s_waitcnt lgkmcnt(0)" ::: "memory");
    __builtin_amdgcn_s_barrier();
    __builtin_amdgcn_sched_barrier(0);
    if (ts < 15) {
      int nts = ts + 1;
      int jn = (nts < 8) ? (nts < 4 ? j0g : j1g) : (nts < 12 ? j2g : j3g);
      int nsub = nts & 3;
      ISSUE_TILE(jn, nsub, cur ^ 1);
      if (wv == 0) { asm volatile("s_waitcnt vmcnt(3)" ::: "memory"); }
      else         { asm volatile("s_waitcnt vmcnt(2)" ::: "memory"); }
    } else {
      asm volatile("s_waitcnt vmcnt(0)" ::: "memory");
    }
    __builtin_amdgcn_s_barrier();
    __builtin_amdgcn_sched_barrier(0);
    const char* sK = (const char*)sKd + cur * 8192;
    const char* sV = (const char*)sVd + cur * 8192;
    f32x4 Sacc[4];
    #pragma unroll
    for (int ni = 0; ni < 4; ni++) Sacc[ni] = zero4;
    #pragma unroll
    for (int kk = 0; kk < 2; kk++) {
      #pragma unroll
      for (int ni = 0; ni < 4; ni++) {
        bf16x8 kF = *(const bf16x8*)(sK + swz128(ni * 16 + lo, kk * 32 + hi * 8));
        Sacc[ni] = __builtin_amdgcn_mfma_f32_16x16x32_bf16(kF, qF[kk], Sacc[ni], 0, 0, 0);
      }
    }
    const float* mB = sMaskB[cur];
    float ml = -3e38f;
    #pragma unroll
    for (int ni = 0; ni < 4; ni++) {
      #pragma unroll
      for (int jj = 0; jj < 4; jj++) {
        float sv = Sacc[ni][jj] + mB[ni * 16 + hi * 4 + jj];
        Sacc[ni][jj] = sv;
        ml = fmaxf(ml, sv);
      }
    }
    ml = fmaxf(ml, __shfl_xor(ml, 16, 64));
    ml = fmaxf(ml, __shfl_xor(ml, 32, 64));
    float nm = fmaxf(mrun, ml);
    float sc = __expf(mrun - nm);
    float rs = 0.f;
    bf16* sPw = sP[wv];
    #pragma unroll
    for (int ni = 0; ni < 4; ni++) {
      #pragma unroll
      for (int jj = 0; jj < 4; jj++) {
        float pv = __expf(Sacc[ni][jj] - nm);
        rs += pv;
        *(bf16*)((char*)sPw + swz128(lo, ni * 16 + hi * 4 + jj)) = (bf16)pv;
      }
    }
    rs += __shfl_xor(rs, 16, 64);
    rs += __shfl_xor(rs, 32, 64);
    mrun = nm; lrun = lrun * sc + rs;
    float scq[4];
    #pragma unroll
    for (int jj = 0; jj < 4; jj++) scq[jj] = __shfl(sc, hi * 4 + jj, 16);
    #pragma unroll
    for (int di = 0; di < 4; di++)
      #pragma unroll
      for (int jj = 0; jj < 4; jj++) Oacc[di][jj] *= scq[jj];
    #pragma unroll
    for (int kk = 0; kk < 2; kk++) {
      bf16x8 pF = *(const bf16x8*)((const char*)sPw + swz128(lo, kk * 32 + hi * 8));
      #pragma unroll
      for (int di = 0; di < 4; di++) {
        bf16x8 vF = *(const bf16x8*)(sV + swz128(di * 16 + lo, kk * 32 + hi * 8));
        Oacc[di] = __builtin_amdgcn_mfma_f32_16x16x32_bf16(pF, vF, Oacc[di], 0, 0, 0);
      }
    }
  }
  #undef ISSUE_TILE
  __syncthreads();
  float inv = 1.f / lrun;
  float invq[4];
  #pragma unroll
  for (int jj = 0; jj < 4; jj++) invq[jj] = __shfl(inv, hi * 4 + jj, 16);
  bf16* sOut = (bf16*)sKd;
  #pragma unroll
  for (int jj = 0; jj < 4; jj++) {
    int row = wv * 16 + hi * 4 + jj;
    #pragma unroll
    for (int di = 0; di < 4; di++)
      sOut[row * 64 + di * 16 + lo] = (bf16)(Oacc[di][jj] * invq[jj]);
  }
  __syncthreads();
  bf16* dst = attnRb + (((size_t)(n * RR + r)) * RS + qsp * 128) * 64;
  #pragma unroll
  for (int it = 0; it < 2; it++) {
    int idx = tid + it * 512;
    *(uint4*)(dst + idx * 8) = *(const uint4*)(sOut + idx * 8);
  }
}

// ---------------- fused lepe + proj: dw5x5 + from_regions + proj GEMM + residual ----------------
// grid (RR, BB); block 256 = one region
__global__ __launch_bounds__(256) void k_lepe3(const bf16* __restrict__ v_t, const bf16* __restrict__ attnRb,
    const float* __restrict__ lw, const float* __restrict__ lb,
    const float* __restrict__ pw, const float* __restrict__ pb, float* __restrict__ xo) {
  __shared__ __align__(16) char smem[64000];
  bf16* sH = (bf16*)smem;               // 400*72 bf16 = 57600B (halo)
  float* sW = (float*)(smem + 57600);   // 25*64 f32 = 6400B
  bf16* zA = (bf16*)smem;               // overlay: 256x64 A-tile (32768B)
  bf16* sBp = (bf16*)(smem + 32768);    // overlay: 64x64 proj weights (8192B)
  int r = blockIdx.x, n = blockIdx.y;
  int rh = (r / 7) * 16, rw = (r % 7) * 16;
  int tid = threadIdx.x, lane = tid & 63, wv = tid >> 6;
  int lo = lane & 15, hi = lane >> 4;
  for (int i = tid; i < 1600; i += 256) { int c = i / 25, k = i % 25; sW[k * 64 + c] = lw[c * 25 + k]; }
  for (int g = tid; g < 3200; g += 256) {
    int pix = g >> 3, c4 = g & 7;
    int yy = pix / 20, xx = pix % 20;
    int hh = rh + yy - 2, ww = rw + xx - 2;
    uint4 d = {0, 0, 0, 0};
    if ((unsigned)hh < HW && (unsigned)ww < HW)
      d = *(const uint4*)(v_t + ((size_t)n * PP + hh * HW + ww) * 64 + c4 * 8);
    *(uint4*)((char*)sH + pix * 144 + c4 * 16) = d;
  }
  __syncthreads();
  int y = tid >> 4, x = tid & 15;
  float acc[64];
  const bf16* ar = attnRb + (((size_t)(n * RR + r)) * RS + tid) * 64;
  #pragma unroll
  for (int c8 = 0; c8 < 8; c8++) {
    bf16x8 av = *(const bf16x8*)(ar + c8 * 8);
    #pragma unroll
    for (int j = 0; j < 8; j++) acc[c8 * 8 + j] = lb[c8 * 8 + j] + (float)av[j];
  }
  for (int t25 = 0; t25 < 25; t25++) {
    int dh = t25 / 5, dw = t25 % 5;
    int pix = (y + dh) * 20 + (x + dw);
    #pragma unroll
    for (int c8 = 0; c8 < 8; c8++) {
      bf16x8 hv = *(const bf16x8*)((const char*)sH + pix * 144 + c8 * 16);
      #pragma unroll
      for (int j = 0; j < 8; j++) acc[c8 * 8 + j] += (float)hv[j] * sW[t25 * 64 + c8 * 8 + j];
    }
  }
  __syncthreads();   // halo reads done -> safe to overlay zA/sBp
  // write z A-tile (swizzled) + stage proj weights
  #pragma unroll
  for (int i = 0; i < 8; i++) {
    bf16x8 o8;
    #pragma unroll
    for (int j = 0; j < 8; j++) o8[j] = (bf16)acc[i * 8 + j];
    *(bf16x8*)((char*)zA + swz128(tid, i * 8)) = o8;
  }
  #pragma unroll
  for (int it = 0; it < 4; it++) {
    int idx = tid + it * 256;
    int oo = idx >> 4, q = idx & 15;
    float4 wv4 = *(const float4*)&pw[(size_t)oo * 64 + q * 4];
    bf16x4 b4; b4[0] = (bf16)wv4.x; b4[1] = (bf16)wv4.y; b4[2] = (bf16)wv4.z; b4[3] = (bf16)wv4.w;
    *(bf16x4*)((char*)sBp + swz128(oo, q * 4)) = b4;
  }
  __syncthreads();
  f32x4 acc2[4][4];
  #pragma unroll
  for (int mi = 0; mi < 4; mi++)
    #pragma unroll
    for (int ni = 0; ni < 4; ni++) acc2[mi][ni] = (f32x4){0.f, 0.f, 0.f, 0.f};
  #pragma unroll
  for (int kk = 0; kk < 2; kk++) {
    bf16x8 aF[4], bF[4];
    #pragma unroll
    for (int mi = 0; mi < 4; mi++)
      aF[mi] = *(const bf16x8*)((const char*)zA + swz128(wv * 64 + mi * 16 + lo, kk * 32 + hi * 8));
    #pragma unroll
    for (int ni = 0; ni < 4; ni++)
      bF[ni] = *(const bf16x8*)((const char*)sBp + swz128(ni * 16 + lo, kk * 32 + hi * 8));
    #pragma unroll
    for (int mi = 0; mi < 4; mi++)
      #pragma unroll
      for (int ni = 0; ni < 4; ni++)
        acc2[mi][ni] = __builtin_amdgcn_mfma_f32_16x16x32_bf16(aF[mi], bF[ni], acc2[mi][ni], 0, 0, 0);
  }
  #pragma unroll
  for (int ni = 0; ni < 4; ni++) {
    float bv = pb[ni * 16 + lo];
    #pragma unroll
    for (int mi = 0; mi < 4; mi++) {
      #pragma unroll
      for (int r2 = 0; r2 < 4; r2++) {
        int s = wv * 64 + mi * 16 + hi * 4 + r2;
        int p = (rh + (s >> 4)) * HW + rw + (s & 15);
        xo[((size_t)n * PP + p) * 64 + ni * 16 + lo] += acc2[mi][ni][r2] + bv;
      }
    }
  }
}

// ---------------- fused MLP: LN2 + fc1 + gelu + fc2 + residual ----------------
__global__ __launch_bounds__(256) void k_mlp(const float* __restrict__ xin, const float* __restrict__ lng,
    const float* __restrict__ lnb, const float* __restrict__ w1, const float* __restrict__ b1,
    const float* __restrict__ w2, const float* __restrict__ b2, float* __restrict__ xo) {
  __shared__ bf16 sA[64 * 64];
  __shared__ bf16 sW1[128 * 64];
  __shared__ bf16 sHh[64 * 128];
  __shared__ bf16 sW2[64 * 128];
  int n = blockIdx.y;
  int p0 = blockIdx.x * 64;
  int tid = threadIdx.x, lane = tid & 63, wv = tid >> 6;
  int lo = lane & 15, hi = lane >> 4;
  { // fused LN staging: 4 threads per row, 16 channels each
    int row = tid >> 2, part = tid & 3;
    const float* xp = xin + ((size_t)n * PP + p0 + row) * 64 + part * 16;
    float v[16]; float s = 0.f, sq = 0.f;
    #pragma unroll
    for (int i = 0; i < 4; i++) {
      float4 d = *(const float4*)&xp[i * 4];
      v[i*4]=d.x; v[i*4+1]=d.y; v[i*4+2]=d.z; v[i*4+3]=d.w;
      s += d.x+d.y+d.z+d.w;
      sq += d.x*d.x+d.y*d.y+d.z*d.z+d.w*d.w;
    }
    s += __shfl_xor(s, 1, 64); sq += __shfl_xor(sq, 1, 64);
    s += __shfl_xor(s, 2, 64); sq += __shfl_xor(sq, 2, 64);
    float mu = s * (1.f/64.f);
    float rstd = rsqrtf(fmaxf(sq * (1.f/64.f) - mu*mu, 0.f) + 1e-5f);
    #pragma unroll
    for (int j2 = 0; j2 < 2; j2++) {
      bf16x8 o8;
      #pragma unroll
      for (int e = 0; e < 8; e++) {
        int c = part*16 + j2*8 + e;
        o8[e] = (bf16)((v[j2*8+e] - mu) * rstd * lng[c] + lnb[c]);
      }
      *(bf16x8*)((char*)sA + swz128(row, part*16 + j2*8)) = o8;
    }
  }
  f32x4 oacc[4];
  #pragma unroll
  for (int ni = 0; ni < 4; ni++) oacc[ni] = (f32x4){0.f, 0.f, 0.f, 0.f};
  for (int half = 0; half < 2; half++) {
    #pragma unroll
    for (int it = 0; it < 8; it++) {
      int idx = tid + it * 256;
      int oo = idx >> 4, q = idx & 15;
      float4 wv4 = *(const float4*)&w1[(size_t)(half * 128 + oo) * 64 + q * 4];
      bf16x4 b4; b4[0] = (bf16)wv4.x; b4[1] = (bf16)wv4.y; b4[2] = (bf16)wv4.z; b4[3] = (bf16)wv4.w;
      *(bf16x4*)((char*)sW1 + swz128(oo, q * 4)) = b4;
    }
    __syncthreads();
    f32x4 hacc[8];
    #pragma unroll
    for (int ni = 0; ni < 8; ni++) hacc[ni] = (f32x4){0.f, 0.f, 0.f, 0.f};
    #pragma unroll
    for (int kk = 0; kk < 2; kk++) {
      bf16x8 aF = *(const bf16x8*)((const char*)sA + swz128(wv * 16 + lo, kk * 32 + hi * 8));
      #pragma unroll
      for (int ni = 0; ni < 8; ni++) {
        bf16x8 bF = *(const bf16x8*)((const char*)sW1 + swz128(ni * 16 + lo, kk * 32 + hi * 8));
        hacc[ni] = __builtin_amdgcn_mfma_f32_16x16x32_bf16(aF, bF, hacc[ni], 0, 0, 0);
      }
    }
    #pragma unroll
    for (int ni = 0; ni < 8; ni++) {
      float bv = b1[half * 128 + ni * 16 + lo];
      #pragma unroll
      for (int r2 = 0; r2 < 4; r2++) {
        float hval = gelu_exact(hacc[ni][r2] + bv);
        *(bf16*)((char*)sHh + swzg(wv * 16 + hi * 4 + r2, ni * 16 + lo, 256)) = (bf16)hval;
      }
    }
    #pragma unroll
    for (int it = 0; it < 8; it++) {
      int idx = tid + it * 256;
      int oo = idx >> 5, q = idx & 31;
      float4 wv4 = *(const float4*)&w2[(size_t)oo * 256 + half * 128 + q * 4];
      bf16x4 b4; b4[0] = (bf16)wv4.x; b4[1] = (bf16)wv4.y; b4[2] = (bf16)wv4.z; b4[3] = (bf16)wv4.w;
      *(bf16x4*)((char*)sW2 + swzg(oo, q * 4, 256)) = b4;
    }
    __syncthreads();
    #pragma unroll
    for (int kk = 0; kk < 4; kk++) {
      bf16x8 aH = *(const bf16x8*)((const char*)sHh + swzg(wv * 16 + lo, kk * 32 + hi * 8, 256));
      #pragma unroll
      for (int ni = 0; ni < 4; ni++) {
        bf16x8 bF = *(const bf16x8*)((const char*)sW2 + swzg(ni * 16 + lo, kk * 32 + hi * 8, 256));
        oacc[ni] = __builtin_amdgcn_mfma_f32_16x16x32_bf16(aH, bF, oacc[ni], 0, 0, 0);
      }
    }
    __syncthreads();
  }
  #pragma unroll
  for (int ni = 0; ni < 4; ni++) {
    float bv = b2[ni * 16 + lo];
    #pragma unroll
    for (int r2 = 0; r2 < 4; r2++) {
      int p = p0 + wv * 16 + hi * 4 + r2;
      xo[((size_t)n * PP + p) * 64 + ni * 16 + lo] += oacc[ni][r2] + bv;
    }
  }
}

// ---------------- final untranspose: x_t[p][c] -> out[c][p] ----------------
__global__ __launch_bounds__(256) void k_untr(const float* __restrict__ x_t, float* __restrict__ out) {
  __shared__ float tile[64][68];
  int n = blockIdx.y; int p0 = blockIdx.x * 64;
  int tid = threadIdx.x;
  #pragma unroll
  for (int it = 0; it < 4; it++) {
    int g = tid + it * 256;
    int row = g >> 4, q = g & 15;
    float4 d = *(const float4*)&x_t[((size_t)n * PP + p0 + row) * 64 + q * 4];
    *(float4*)&tile[row][q * 4] = d;
  }
  __syncthreads();
  #pragma unroll
  for (int it = 0; it < 4; it++) {
    int g = tid + it * 256;
    int c = g >> 4, q = g & 15;
    float4 v;
    v.x = tile[q * 4 + 0][c]; v.y = tile[q * 4 + 1][c];
    v.z = tile[q * 4 + 2][c]; v.w = tile[q * 4 + 3][c];
    *(float4*)&out[((size_t)(n * 64 + c)) * PP + p0 + q * 4] = v;
  }
}

extern "C" void kernel_launch(void* const* d_in, const int* in_sizes, int n_in,
                              void* d_out, int out_size, void* d_ws, size_t ws_size,
                              hipStream_t stream) {
  const float* ex0 = (const float*)d_in[0];
  const float* ex  = (const float*)d_in[1];
  const float* img = (const float*)d_in[2];
  const float* pre = (const float*)d_in[3];
  const float* c0w = (const float*)d_in[4];
  const float* c0b = (const float*)d_in[5];
  const float* ln1g = (const float*)d_in[6];
  const float* ln1b = (const float*)d_in[7];
  const float* ln2g = (const float*)d_in[8];
  const float* ln2b = (const float*)d_in[9];
  const float* qkvw = (const float*)d_in[10];
  const float* qkvb = (const float*)d_in[11];
  const float* lw = (const float*)d_in[12];
  const float* lb = (const float*)d_in[13];
  const float* pw = (const float*)d_in[14];
  const float* pb = (const float*)d_in[15];
  const float* f1w = (const float*)d_in[16];
  const float* f1b = (const float*)d_in[17];
  const float* f2w = (const float*)d_in[18];
  const float* f2b = (const float*)d_in[19];

  float* W = (float*)d_ws;
  size_t o = 0;
  bf16* xct = (bf16*)(W + o);  o += (size_t)BB * GP * CK / 2;
  float* x_t  = W + o;         o += 3211264;
  bf16* attnRb = (bf16*)(W + o); o += 1605632;
  bf16* v_t  = (bf16*)(W + o); o += 1605632;
  bf16* qR   = (bf16*)(W + o); o += 1605632;
  bf16* kR   = (bf16*)(W + o); o += 1605632;
  bf16* vT   = (bf16*)(W + o); o += 1605632;
  float* qd = W + o;           o += 12544;
  float* kd = W + o;           o += 12544;
  float* maskr = W + o;        o += 50176;
  bf16* wTb = (bf16*)(W + o);  o += 46080;
  int* gidx = (int*)(W + o);   o += 784;

  hipMemsetAsync(xct, 0, (size_t)BB * GP * CK * 2, stream);
  k_prep2<<<dim3(196, BB), dim3(256), 0, stream>>>(ex0, ex, img, pre, xct, maskr);
  k_wt2<<<dim3(360), dim3(256), 0, stream>>>(c0w, wTb);
  k_conv0m<<<dim3(98, BB), dim3(256), 0, stream>>>(xct, wTb, c0b, x_t);
  for (int i = 0; i < 4; i++) {
    k_qkvr<<<dim3(RR, BB), dim3(256), 0, stream>>>(x_t, ln1g + i * 64, ln1b + i * 64,
        qkvw + (size_t)i * 192 * 64, qkvb + i * 192, qR, kR, v_t, vT, qd, kd);
    k_topk<<<dim3(RR, BB), dim3(64), 0, stream>>>(qd, kd, gidx);
    k_attn<<<dim3(BB * RR * 2), dim3(512), 0, stream>>>(qR, kR, vT, maskr, gidx, attnRb);
    k_lepe3<<<dim3(RR, BB), dim3(256), 0, stream>>>(v_t, attnRb, lw + (size_t)i * 64 * 25, lb + i * 64,
        pw + (size_t)i * 64 * 64, pb + i * 64, x_t);
    k_mlp<<<dim3(196, BB), dim3(256), 0, stream>>>(x_t, ln2g + i * 64, ln2b + i * 64,
        f1w + (size_t)i * 256 * 64, f1b + i * 256, f2w + (size_t)i * 64 * 256, f2b + i * 64, x_t);
  }
  k_untr<<<dim3(196, BB), dim3(256), 0, stream>>>(x_t, (float*)d_out);
}